// Round 2
// baseline (2684.163 us; speedup 1.0000x reference)
//
#include <hip/hip_runtime.h>
#include <math.h>

// HebbianBlock: B=4, T=4096, D=1024, H=8, d=128, C=64, N=64
// Round 2: same 5-kernel pipeline as R1, but all large intermediates in bf16
// (ws = 144.5 MB; R1's 302.5 MB f32 request likely exceeded ws_size and the
// guard silently returned -> output identical to empty stub).
//   K1 prep: rk (normalized heads, bf16 (BH,T,128)), beta (f32 BH,T)
//   K2 gemm<0>: vb = (x@W_write^T)*beta -> bf16 (BH,T,128)
//   K3 chunk: A0 -> UT transform -> wkcum(bf16), vb <- (A+I)vb, attn(bf16)
//   K4 scan: S columns independent -> 512 blocks; og bf16 (B,T,D)
//   K5 gemm<1>: out = x + og@W_read^T (f32 out)

#define T_LEN 4096
typedef unsigned short ushort;
typedef __attribute__((ext_vector_type(4))) unsigned short us4;
typedef __attribute__((ext_vector_type(8))) unsigned short us8;

__device__ __forceinline__ float bf2f(ushort u) {
  union { unsigned int u; float f; } c; c.u = ((unsigned int)u) << 16; return c.f;
}
__device__ __forceinline__ ushort f2bf(float x) {
  union { float f; unsigned int u; } c; c.f = x;
  unsigned int u = c.u + 0x7FFFu + ((c.u >> 16) & 1u);
  return (ushort)(u >> 16);
}

// ---------------- K1: rk + beta ----------------
__global__ __launch_bounds__(128) void k_prep(
    const float* __restrict__ x, const float* __restrict__ Wb,
    ushort* __restrict__ rk, float* __restrict__ beta)
{
  int bt = blockIdx.x;
  int b = bt >> 12, t = bt & 4095;
  int tid = threadIdx.x;
  __shared__ float xs[1024];
  __shared__ float red[16];
  {
    const float4* x4 = (const float4*)(x + (size_t)bt * 1024);
    float4* xs4 = (float4*)xs;
    xs4[tid] = x4[tid];
    xs4[tid + 128] = x4[tid + 128];
  }
  __syncthreads();
  int h = tid >> 4;
  int e0 = h * 128 + (tid & 15) * 8;
  float ss = 0.f;
  #pragma unroll
  for (int s = 0; s < 8; ++s) { float v = xs[e0 + s]; ss += v * v; }
  #pragma unroll
  for (int m = 1; m < 16; m <<= 1) ss += __shfl_xor(ss, m, 64);
  float inv = 1.f / fmaxf(sqrtf(ss), 1e-12f);
  {
    int bh = b * 8 + h;
    us8 o;
    #pragma unroll
    for (int s = 0; s < 8; ++s) o[s] = f2bf(xs[e0 + s] * inv);
    *(us8*)(rk + ((size_t)bh * T_LEN + t) * 128 + (tid & 15) * 8) = o;
  }
  const float* xk = xs + tid * 8;
  #pragma unroll
  for (int h2 = 0; h2 < 8; ++h2) {
    const float* wb = Wb + (size_t)h2 * 1024 + tid * 8;
    float p = 0.f;
    #pragma unroll
    for (int s = 0; s < 8; ++s) p += xk[s] * wb[s];
    #pragma unroll
    for (int m = 1; m < 64; m <<= 1) p += __shfl_xor(p, m, 64);
    if ((tid & 63) == 0) red[(tid >> 6) * 8 + h2] = p;
  }
  __syncthreads();
  if (tid < 8) {
    float s = red[tid] + red[8 + tid];
    beta[((size_t)(b * 8 + tid)) * T_LEN + t] = 1.f / (1.f + expf(-s));
  }
}

// ---------------- K2/K5: GEMM 64x64 tile, BK=16 ----------------
// MODE 0: A=f32 x, out=bf16 vb (scaled by beta); MODE 1: A=bf16 og, out=f32 (+xadd)
template<int MODE>
__global__ __launch_bounds__(256) void k_gemm(
    const void* __restrict__ Am_, const float* __restrict__ W,
    const float* __restrict__ beta, const float* __restrict__ xadd,
    void* __restrict__ out_)
{
  __shared__ float As[16][68];
  __shared__ float Bs[16][68];
  int n0 = blockIdx.x * 64;
  int m0 = blockIdx.y * 64;
  int tid = threadIdx.x;
  int tx = tid & 15, ty = tid >> 4;
  int lr = tid >> 2, lk = (tid & 3) * 4;
  float acc[4][4] = {};
  const float* Wp = W + (size_t)(n0 + lr) * 1024 + lk;
  for (int k0 = 0; k0 < 1024; k0 += 16) {
    float a0, a1, a2, a3;
    if (MODE == 0) {
      float4 a4 = *(const float4*)((const float*)Am_ + (size_t)(m0 + lr) * 1024 + k0 + lk);
      a0 = a4.x; a1 = a4.y; a2 = a4.z; a3 = a4.w;
    } else {
      us4 a4 = *(const us4*)((const ushort*)Am_ + (size_t)(m0 + lr) * 1024 + k0 + lk);
      a0 = bf2f(a4[0]); a1 = bf2f(a4[1]); a2 = bf2f(a4[2]); a3 = bf2f(a4[3]);
    }
    float4 b4 = *(const float4*)(Wp + k0);
    As[lk + 0][lr] = a0; As[lk + 1][lr] = a1;
    As[lk + 2][lr] = a2; As[lk + 3][lr] = a3;
    Bs[lk + 0][lr] = b4.x; Bs[lk + 1][lr] = b4.y;
    Bs[lk + 2][lr] = b4.z; Bs[lk + 3][lr] = b4.w;
    __syncthreads();
    #pragma unroll
    for (int kk = 0; kk < 16; ++kk) {
      float4 av = *(const float4*)&As[kk][ty * 4];
      float4 bv = *(const float4*)&Bs[kk][tx * 4];
      float aa[4] = {av.x, av.y, av.z, av.w};
      float bb[4] = {bv.x, bv.y, bv.z, bv.w};
      #pragma unroll
      for (int r = 0; r < 4; ++r)
        #pragma unroll
        for (int c = 0; c < 4; ++c) acc[r][c] += aa[r] * bb[c];
    }
    __syncthreads();
  }
  if (MODE == 0) {
    ushort* out = (ushort*)out_;
    int hh = n0 >> 7;
    int j0 = n0 & 127;
    #pragma unroll
    for (int r = 0; r < 4; ++r) {
      int bt = m0 + ty * 4 + r;
      int b = bt >> 12, t = bt & 4095;
      int bh = b * 8 + hh;
      float bv = beta[(size_t)bh * T_LEN + t];
      us4 o;
      #pragma unroll
      for (int c = 0; c < 4; ++c) o[c] = f2bf(acc[r][c] * bv);
      *(us4*)(out + ((size_t)bh * T_LEN + t) * 128 + j0 + tx * 4) = o;
    }
  } else {
    float* out = (float*)out_;
    #pragma unroll
    for (int r = 0; r < 4; ++r) {
      int bt = m0 + ty * 4 + r;
      const float* xr = xadd + (size_t)bt * 1024 + n0 + tx * 4;
      float* op = out + (size_t)bt * 1024 + n0 + tx * 4;
      #pragma unroll
      for (int c = 0; c < 4; ++c) op[c] = xr[c] + acc[r][c];
    }
  }
}

// ---------------- K3: per-chunk UT transform ----------------
__global__ __launch_bounds__(256) void k_chunk(
    const ushort* __restrict__ rk, ushort* __restrict__ vb,
    ushort* __restrict__ wkcum, ushort* __restrict__ attn,
    const float* __restrict__ beta, const float* __restrict__ decay)
{
  int bh = blockIdx.x >> 6;
  int n = blockIdx.x & 63;
  int h = bh & 7;
  int tid = threadIdx.x;
  __shared__ float rkx[65][132];   // rows t0-1..t0+63 of rk (wk[i]=rkx[i], rk[i]=rkx[i+1])
  __shared__ float A[64][66];
  __shared__ float red[4][64];
  __shared__ float betaS[64], bd[64], gpow[65];
  float lg = logf(1.f / (1.f + expf(-decay[h])));
  if (tid < 65) gpow[tid] = expf(lg * (float)tid);
  if (tid < 64) betaS[tid] = beta[(size_t)bh * T_LEN + n * 64 + tid];
  __syncthreads();
  if (tid < 64) bd[tid] = betaS[tid] * gpow[tid + 1];
  const size_t rbase = ((size_t)bh * T_LEN + n * 64) * 128;
  for (int idx = tid; idx < 65 * 32; idx += 256) {
    int row = idx >> 5, c = idx & 31;
    int t = n * 64 + row - 1;
    float4 v = make_float4(0.f, 0.f, 0.f, 0.f);
    if (t >= 0) {
      us4 u = *(const us4*)(rk + ((size_t)bh * T_LEN + t) * 128 + c * 4);
      v.x = bf2f(u[0]); v.y = bf2f(u[1]); v.z = bf2f(u[2]); v.w = bf2f(u[3]);
    }
    *(float4*)&rkx[row][c * 4] = v;
  }
  __syncthreads();
  // G[a][j] = rkx[a].rkx[j]
  int tx = tid & 15, ty = tid >> 4;
  float accg[4][4] = {};
  for (int pq = 0; pq < 32; ++pq) {
    float4 av[4], bv[4];
    #pragma unroll
    for (int r = 0; r < 4; ++r) av[r] = *(const float4*)&rkx[ty * 4 + r][pq * 4];
    #pragma unroll
    for (int c = 0; c < 4; ++c) bv[c] = *(const float4*)&rkx[tx + 16 * c][pq * 4];
    #pragma unroll
    for (int r = 0; r < 4; ++r) {
      #pragma unroll
      for (int c = 0; c < 4; ++c) {
        accg[r][c] += av[r].x * bv[c].x + av[r].y * bv[c].y
                    + av[r].z * bv[c].z + av[r].w * bv[c].w;
      }
    }
  }
  const size_t abase = ((size_t)bh * 64 + n) * 64 * 64;
  #pragma unroll
  for (int r = 0; r < 4; ++r) {
    #pragma unroll
    for (int c = 0; c < 4; ++c) {
      int a = ty * 4 + r, j = tx + 16 * c;
      if (a > j) {
        A[a][j] = -betaS[a] * accg[r][c] * gpow[a - j];
        attn[abase + (size_t)(a - 1) * 64 + j] = f2bf(accg[r][c] * gpow[a - 1 - j]);
      } else {
        A[a][j] = 0.f;
        if (a >= 1) attn[abase + (size_t)(a - 1) * 64 + j] = 0;
      }
    }
  }
  if (tid < 64) {
    int j = tid;
    float g = 0.f;
    for (int pq = 0; pq < 32; ++pq) {
      float4 u = *(const float4*)&rkx[64][pq * 4];
      float4 w = *(const float4*)&rkx[j][pq * 4];
      g += u.x * w.x + u.y * w.y + u.z * w.z + u.w * w.w;
    }
    attn[abase + (size_t)63 * 64 + j] = f2bf(g * gpow[63 - j]);
  }
  __syncthreads();
  // UT transform: for i=1..63: A[i,:] += A[i,:] @ A
  {
    int k = tid & 63, sp = tid >> 6;
    for (int i = 1; i < 64; ++i) {
      float part = 0.f;
      #pragma unroll
      for (int jj = 0; jj < 16; ++jj) {
        int j = sp * 16 + jj;
        part += A[i][j] * A[j][k];
      }
      red[sp][k] = part;
      __syncthreads();
      if (tid < 64) A[i][tid] += red[0][tid] + red[1][tid] + red[2][tid] + red[3][tid];
      __syncthreads();
    }
  }
  // 4a: wk_cum = (A+I) @ (beta*gamma^(j+1)*wk)
  int pq = tid & 31, ig = tid >> 5;
  for (int it = 0; it < 8; ++it) {
    int i = ig * 8 + it;
    float4 acc = make_float4(0.f, 0.f, 0.f, 0.f);
    for (int j = 0; j < 64; ++j) {
      float coef = (A[i][j] + (i == j ? 1.f : 0.f)) * bd[j];
      float4 rv = *(const float4*)&rkx[j][pq * 4];
      acc.x += coef * rv.x; acc.y += coef * rv.y;
      acc.z += coef * rv.z; acc.w += coef * rv.w;
    }
    us4 o; o[0] = f2bf(acc.x); o[1] = f2bf(acc.y); o[2] = f2bf(acc.z); o[3] = f2bf(acc.w);
    *(us4*)(wkcum + rbase + (size_t)i * 128 + pq * 4) = o;
  }
  __syncthreads();
  // 4b: v <- (A+I) @ v
  for (int idx = tid; idx < 64 * 32; idx += 256) {
    int row = idx >> 5, c = idx & 31;
    us4 u = *(const us4*)(vb + rbase + (size_t)row * 128 + c * 4);
    float4 v; v.x = bf2f(u[0]); v.y = bf2f(u[1]); v.z = bf2f(u[2]); v.w = bf2f(u[3]);
    *(float4*)&rkx[row][c * 4] = v;
  }
  __syncthreads();
  for (int it = 0; it < 8; ++it) {
    int i = ig * 8 + it;
    float4 acc = make_float4(0.f, 0.f, 0.f, 0.f);
    for (int j = 0; j < 64; ++j) {
      float coef = A[i][j] + (i == j ? 1.f : 0.f);
      float4 rv = *(const float4*)&rkx[j][pq * 4];
      acc.x += coef * rv.x; acc.y += coef * rv.y;
      acc.z += coef * rv.z; acc.w += coef * rv.w;
    }
    us4 o; o[0] = f2bf(acc.x); o[1] = f2bf(acc.y); o[2] = f2bf(acc.z); o[3] = f2bf(acc.w);
    *(us4*)(vb + rbase + (size_t)i * 128 + pq * 4) = o;
  }
}

// ---------------- K4: chunk scan (S columns independent) ----------------
__global__ __launch_bounds__(256) void k_scan(
    const ushort* __restrict__ rk, const ushort* __restrict__ vb,
    const ushort* __restrict__ wkcum, const ushort* __restrict__ attn,
    const float* __restrict__ decay, ushort* __restrict__ og)
{
  int bh = blockIdx.x >> 4;
  int qg = blockIdx.x & 15;
  int q0 = qg * 8;
  int b = bh >> 3, h = bh & 7;
  int tid = threadIdx.x;
  int q = tid & 7, g = tid >> 3;  // g in [0,32)
  __shared__ float S_T[8][132];   // S_T[q][p] = S[p][q0+q]
  __shared__ float vnew[64][9];
  __shared__ float gpow[65];
  float lg = logf(1.f / (1.f + expf(-decay[h])));
  if (tid < 65) gpow[tid] = expf(lg * (float)tid);
  for (int idx = tid; idx < 8 * 132; idx += 256) ((float*)S_T)[idx] = 0.f;
  __syncthreads();
  float ct = gpow[64];
  const size_t rowbase = (size_t)bh * T_LEN * 128;
  for (int n = 0; n < 64; ++n) {
    int t0 = n * 64;
    // Phase A: vnew[i][q] = v[i][q0+q] - sum_p wkcum[i][p]*S[p][q0+q]
    #pragma unroll
    for (int ii = 0; ii < 2; ++ii) {
      int i = g * 2 + ii;
      const ushort* wr = wkcum + rowbase + (size_t)(t0 + i) * 128;
      const float* sr = &S_T[q][0];
      float acc = 0.f;
      #pragma unroll 4
      for (int pq = 0; pq < 16; ++pq) {
        us8 w8 = *(const us8*)(wr + pq * 8);
        #pragma unroll
        for (int s = 0; s < 8; ++s) acc += bf2f(w8[s]) * sr[pq * 8 + s];
      }
      vnew[i][q] = bf2f(vb[rowbase + (size_t)(t0 + i) * 128 + q0 + q]) - acc;
    }
    __syncthreads();
    // Phase B: o[i] = gamma^(i+1)*rk[i]@S + attn[i,:]@vnew
    #pragma unroll
    for (int ii = 0; ii < 2; ++ii) {
      int i = g * 2 + ii;
      const ushort* rr = rk + rowbase + (size_t)(t0 + i) * 128;
      const float* sr = &S_T[q][0];
      float acc = 0.f;
      #pragma unroll 4
      for (int pq = 0; pq < 16; ++pq) {
        us8 w8 = *(const us8*)(rr + pq * 8);
        #pragma unroll
        for (int s = 0; s < 8; ++s) acc += bf2f(w8[s]) * sr[pq * 8 + s];
      }
      acc *= gpow[i + 1];
      const ushort* ar = attn + (((size_t)bh * 64 + n) * 64 + i) * 64;
      #pragma unroll 2
      for (int kb = 0; kb < 8; ++kb) {
        us8 a8 = *(const us8*)(ar + kb * 8);
        #pragma unroll
        for (int s = 0; s < 8; ++s) acc += bf2f(a8[s]) * vnew[kb * 8 + s][q];
      }
      og[((size_t)b * T_LEN + t0 + i) * 1024 + h * 128 + q0 + q] = f2bf(acc);
    }
    __syncthreads();
    // Phase C: S[p][q] = ct*S[p][q] + sum_i wk[i][p]*gamma^(63-i)*vnew[i][q]
    {
      int p = g * 4;
      float4 sv = *(float4*)&S_T[q][p];
      sv.x *= ct; sv.y *= ct; sv.z *= ct; sv.w *= ct;
      for (int i = 0; i < 64; ++i) {
        int t = t0 + i - 1;
        if (t >= 0) {
          float coef = gpow[63 - i] * vnew[i][q];
          us4 u = *(const us4*)(rk + rowbase + (size_t)t * 128 + p);
          sv.x += bf2f(u[0]) * coef; sv.y += bf2f(u[1]) * coef;
          sv.z += bf2f(u[2]) * coef; sv.w += bf2f(u[3]) * coef;
        }
      }
      *(float4*)&S_T[q][p] = sv;
    }
    __syncthreads();
  }
}

extern "C" void kernel_launch(void* const* d_in, const int* in_sizes, int n_in,
                              void* d_out, int out_size, void* d_ws, size_t ws_size,
                              hipStream_t stream) {
  const float* x   = (const float*)d_in[0];
  const float* Ww  = (const float*)d_in[1];
  const float* Wr  = (const float*)d_in[2];
  const float* Wb  = (const float*)d_in[3];
  const float* dec = (const float*)d_in[4];
  float* out = (float*)d_out;
  ushort* ws = (ushort*)d_ws;
  const size_t SZ = 32ull * 4096 * 128;              // 16,777,216 elems
  ushort* rk    = ws;                                // bf16, 32 MB
  ushort* vb    = ws + SZ;                           // bf16, 32 MB
  ushort* wkcum = ws + 2 * SZ;                       // bf16, 32 MB
  ushort* og    = ws + 3 * SZ;                       // bf16, 32 MB
  ushort* attn  = ws + 4 * SZ;                       // bf16, 16 MB (32*64*64*64)
  float*  beta  = (float*)(ws + 4 * SZ + 8388608ull);// f32, 0.5 MB
  const size_t NEED = (4 * SZ + 8388608ull) * 2ull + 131072ull * 4ull; // 151,519,232 B
  if (ws_size < NEED) {
    // diagnostic fallback: out = x (err would be max|o@Wr^T| ~ 3-4, NOT 5.5)
    hipMemcpyAsync(d_out, (const void*)x, (size_t)out_size * 4, hipMemcpyDeviceToDevice, stream);
    return;
  }

  k_prep<<<dim3(16384), dim3(128), 0, stream>>>(x, Wb, rk, beta);
  k_gemm<0><<<dim3(16, 256), dim3(256), 0, stream>>>((const void*)x, Ww, beta, nullptr, (void*)vb);
  k_chunk<<<dim3(2048), dim3(256), 0, stream>>>(rk, vb, wkcum, attn, beta, dec);
  k_scan<<<dim3(512), dim3(256), 0, stream>>>(rk, vb, wkcum, attn, dec, og);
  k_gemm<1><<<dim3(16, 256), dim3(256), 0, stream>>>((const void*)og, Wr, nullptr, (const float*)x, (void*)out);
}

// Round 3
// 2008.358 us; speedup vs baseline: 1.3365x; 1.3365x over previous
//
#include <hip/hip_runtime.h>
#include <hip/hip_bf16.h>
#include <math.h>

// HebbianBlock: B=4, T=4096, D=1024, H=8, d=128, C=64, N=64
// Round 3: K2/K5 GEMMs -> bf16 MFMA (16x16x32), in-kernel f32->bf16 staging.
// k_prep/k_chunk/k_scan identical to passing Round-2 version. ws unchanged.

#define T_LEN 4096
typedef unsigned short ushort;
typedef __attribute__((ext_vector_type(4))) unsigned short us4;
typedef __attribute__((ext_vector_type(8))) unsigned short us8;
typedef __attribute__((ext_vector_type(8))) short short8v;
typedef __attribute__((ext_vector_type(4))) float f32x4;

__device__ __forceinline__ float bf2f(ushort u) {
  union { unsigned int u; float f; } c; c.u = ((unsigned int)u) << 16; return c.f;
}
__device__ __forceinline__ ushort f2bf(float x) {
  union { float f; unsigned int u; } c; c.f = x;
  unsigned int u = c.u + 0x7FFFu + ((c.u >> 16) & 1u);
  return (ushort)(u >> 16);
}
__device__ __forceinline__ ushort f2bf_fast(float x) {
  __hip_bfloat16 h = __float2bfloat16(x);
  return *reinterpret_cast<ushort*>(&h);
}

// ---------------- K1: rk + beta ----------------
__global__ __launch_bounds__(128) void k_prep(
    const float* __restrict__ x, const float* __restrict__ Wb,
    ushort* __restrict__ rk, float* __restrict__ beta)
{
  int bt = blockIdx.x;
  int b = bt >> 12, t = bt & 4095;
  int tid = threadIdx.x;
  __shared__ float xs[1024];
  __shared__ float red[16];
  {
    const float4* x4 = (const float4*)(x + (size_t)bt * 1024);
    float4* xs4 = (float4*)xs;
    xs4[tid] = x4[tid];
    xs4[tid + 128] = x4[tid + 128];
  }
  __syncthreads();
  int h = tid >> 4;
  int e0 = h * 128 + (tid & 15) * 8;
  float ss = 0.f;
  #pragma unroll
  for (int s = 0; s < 8; ++s) { float v = xs[e0 + s]; ss += v * v; }
  #pragma unroll
  for (int m = 1; m < 16; m <<= 1) ss += __shfl_xor(ss, m, 64);
  float inv = 1.f / fmaxf(sqrtf(ss), 1e-12f);
  {
    int bh = b * 8 + h;
    us8 o;
    #pragma unroll
    for (int s = 0; s < 8; ++s) o[s] = f2bf(xs[e0 + s] * inv);
    *(us8*)(rk + ((size_t)bh * T_LEN + t) * 128 + (tid & 15) * 8) = o;
  }
  const float* xk = xs + tid * 8;
  #pragma unroll
  for (int h2 = 0; h2 < 8; ++h2) {
    const float* wb = Wb + (size_t)h2 * 1024 + tid * 8;
    float p = 0.f;
    #pragma unroll
    for (int s = 0; s < 8; ++s) p += xk[s] * wb[s];
    #pragma unroll
    for (int m = 1; m < 64; m <<= 1) p += __shfl_xor(p, m, 64);
    if ((tid & 63) == 0) red[(tid >> 6) * 8 + h2] = p;
  }
  __syncthreads();
  if (tid < 8) {
    float s = red[tid] + red[8 + tid];
    beta[((size_t)(b * 8 + tid)) * T_LEN + t] = 1.f / (1.f + expf(-s));
  }
}

// ---------------- K2/K5: bf16 MFMA GEMM, 128x128 tile, BK=32 ----------------
// C(16384x1024) = A(16384x1024) @ W^T(1024x1024)
// MODE 0: A = f32 x (cvt in staging), out = bf16 vb scaled by beta
// MODE 1: A = bf16 og,                out = f32 (x + C)
#define LDK 40  // 32 + 8 pad (80B row stride: balanced bank pattern for b128)
template<int MODE>
__global__ __launch_bounds__(256) void k_gemm(
    const void* __restrict__ Am_, const float* __restrict__ W,
    const float* __restrict__ beta, const float* __restrict__ xadd,
    void* __restrict__ out_)
{
  __shared__ ushort As[128 * LDK];
  __shared__ ushort Bs[128 * LDK];
  const int n0 = blockIdx.x * 128;
  const int m0 = blockIdx.y * 128;
  const int tid = threadIdx.x;
  const int lane = tid & 63;
  const int wid = tid >> 6;
  const int wr = wid >> 1, wc = wid & 1;
  const int c = lane & 15, g = lane >> 4;
  const int srow = tid >> 2;      // 0..63 (staging row)
  const int seg = tid & 3;        // 16B segment within BK=32

  f32x4 acc[4][4] = {};

  for (int k0 = 0; k0 < 1024; k0 += 32) {
    // ---- stage A (rows srow, srow+64) ----
    if (MODE == 0) {
      const float* a0 = (const float*)Am_ + (size_t)(m0 + srow) * 1024 + k0 + seg * 8;
      const float* a1 = (const float*)Am_ + (size_t)(m0 + srow + 64) * 1024 + k0 + seg * 8;
      float4 p0 = *(const float4*)a0, p1 = *(const float4*)(a0 + 4);
      float4 q0 = *(const float4*)a1, q1 = *(const float4*)(a1 + 4);
      us8 o0, o1;
      o0[0]=f2bf_fast(p0.x); o0[1]=f2bf_fast(p0.y); o0[2]=f2bf_fast(p0.z); o0[3]=f2bf_fast(p0.w);
      o0[4]=f2bf_fast(p1.x); o0[5]=f2bf_fast(p1.y); o0[6]=f2bf_fast(p1.z); o0[7]=f2bf_fast(p1.w);
      o1[0]=f2bf_fast(q0.x); o1[1]=f2bf_fast(q0.y); o1[2]=f2bf_fast(q0.z); o1[3]=f2bf_fast(q0.w);
      o1[4]=f2bf_fast(q1.x); o1[5]=f2bf_fast(q1.y); o1[6]=f2bf_fast(q1.z); o1[7]=f2bf_fast(q1.w);
      *(us8*)&As[srow * LDK + seg * 8] = o0;
      *(us8*)&As[(srow + 64) * LDK + seg * 8] = o1;
    } else {
      us8 o0 = *(const us8*)((const ushort*)Am_ + (size_t)(m0 + srow) * 1024 + k0 + seg * 8);
      us8 o1 = *(const us8*)((const ushort*)Am_ + (size_t)(m0 + srow + 64) * 1024 + k0 + seg * 8);
      *(us8*)&As[srow * LDK + seg * 8] = o0;
      *(us8*)&As[(srow + 64) * LDK + seg * 8] = o1;
    }
    // ---- stage B = W rows n0..n0+127 (f32 -> bf16) ----
    {
      const float* b0 = W + (size_t)(n0 + srow) * 1024 + k0 + seg * 8;
      const float* b1 = W + (size_t)(n0 + srow + 64) * 1024 + k0 + seg * 8;
      float4 p0 = *(const float4*)b0, p1 = *(const float4*)(b0 + 4);
      float4 q0 = *(const float4*)b1, q1 = *(const float4*)(b1 + 4);
      us8 o0, o1;
      o0[0]=f2bf_fast(p0.x); o0[1]=f2bf_fast(p0.y); o0[2]=f2bf_fast(p0.z); o0[3]=f2bf_fast(p0.w);
      o0[4]=f2bf_fast(p1.x); o0[5]=f2bf_fast(p1.y); o0[6]=f2bf_fast(p1.z); o0[7]=f2bf_fast(p1.w);
      o1[0]=f2bf_fast(q0.x); o1[1]=f2bf_fast(q0.y); o1[2]=f2bf_fast(q0.z); o1[3]=f2bf_fast(q0.w);
      o1[4]=f2bf_fast(q1.x); o1[5]=f2bf_fast(q1.y); o1[6]=f2bf_fast(q1.z); o1[7]=f2bf_fast(q1.w);
      *(us8*)&Bs[srow * LDK + seg * 8] = o0;
      *(us8*)&Bs[(srow + 64) * LDK + seg * 8] = o1;
    }
    __syncthreads();
    // ---- fragments + 16 MFMA ----
    short8v af[4], bf[4];
    #pragma unroll
    for (int mi = 0; mi < 4; ++mi)
      af[mi] = *(const short8v*)&As[(wr * 64 + mi * 16 + c) * LDK + g * 8];
    #pragma unroll
    for (int ni = 0; ni < 4; ++ni)
      bf[ni] = *(const short8v*)&Bs[(wc * 64 + ni * 16 + c) * LDK + g * 8];
    #pragma unroll
    for (int mi = 0; mi < 4; ++mi)
      #pragma unroll
      for (int ni = 0; ni < 4; ++ni)
        acc[mi][ni] = __builtin_amdgcn_mfma_f32_16x16x32_bf16(af[mi], bf[ni], acc[mi][ni], 0, 0, 0);
    __syncthreads();
  }

  // ---- epilogue: D row = g*4+j (local), col = c ----
  if (MODE == 0) {
    ushort* vb = (ushort*)out_;
    const int hh = n0 >> 7;               // n0 is a multiple of 128
    #pragma unroll
    for (int mi = 0; mi < 4; ++mi) {
      #pragma unroll
      for (int ni = 0; ni < 4; ++ni) {
        int jc = wc * 64 + ni * 16 + c;
        #pragma unroll
        for (int j = 0; j < 4; ++j) {
          int m = m0 + wr * 64 + mi * 16 + g * 4 + j;
          int b = m >> 12, t = m & 4095;
          size_t base = (size_t)(b * 8 + hh) * T_LEN + t;
          float bv = beta[base];
          vb[base * 128 + jc] = f2bf(acc[mi][ni][j] * bv);
        }
      }
    }
  } else {
    float* out = (float*)out_;
    #pragma unroll
    for (int mi = 0; mi < 4; ++mi) {
      #pragma unroll
      for (int ni = 0; ni < 4; ++ni) {
        int n = n0 + wc * 64 + ni * 16 + c;
        #pragma unroll
        for (int j = 0; j < 4; ++j) {
          int m = m0 + wr * 64 + mi * 16 + g * 4 + j;
          size_t idx = (size_t)m * 1024 + n;
          out[idx] = xadd[idx] + acc[mi][ni][j];
        }
      }
    }
  }
}

// ---------------- K3: per-chunk UT transform ----------------
__global__ __launch_bounds__(256) void k_chunk(
    const ushort* __restrict__ rk, ushort* __restrict__ vb,
    ushort* __restrict__ wkcum, ushort* __restrict__ attn,
    const float* __restrict__ beta, const float* __restrict__ decay)
{
  int bh = blockIdx.x >> 6;
  int n = blockIdx.x & 63;
  int h = bh & 7;
  int tid = threadIdx.x;
  __shared__ float rkx[65][132];
  __shared__ float A[64][66];
  __shared__ float red[4][64];
  __shared__ float betaS[64], bd[64], gpow[65];
  float lg = logf(1.f / (1.f + expf(-decay[h])));
  if (tid < 65) gpow[tid] = expf(lg * (float)tid);
  if (tid < 64) betaS[tid] = beta[(size_t)bh * T_LEN + n * 64 + tid];
  __syncthreads();
  if (tid < 64) bd[tid] = betaS[tid] * gpow[tid + 1];
  const size_t rbase = ((size_t)bh * T_LEN + n * 64) * 128;
  for (int idx = tid; idx < 65 * 32; idx += 256) {
    int row = idx >> 5, cc = idx & 31;
    int t = n * 64 + row - 1;
    float4 v = make_float4(0.f, 0.f, 0.f, 0.f);
    if (t >= 0) {
      us4 u = *(const us4*)(rk + ((size_t)bh * T_LEN + t) * 128 + cc * 4);
      v.x = bf2f(u[0]); v.y = bf2f(u[1]); v.z = bf2f(u[2]); v.w = bf2f(u[3]);
    }
    *(float4*)&rkx[row][cc * 4] = v;
  }
  __syncthreads();
  int tx = tid & 15, ty = tid >> 4;
  float accg[4][4] = {};
  for (int pq = 0; pq < 32; ++pq) {
    float4 av[4], bv[4];
    #pragma unroll
    for (int r = 0; r < 4; ++r) av[r] = *(const float4*)&rkx[ty * 4 + r][pq * 4];
    #pragma unroll
    for (int cc = 0; cc < 4; ++cc) bv[cc] = *(const float4*)&rkx[tx + 16 * cc][pq * 4];
    #pragma unroll
    for (int r = 0; r < 4; ++r) {
      #pragma unroll
      for (int cc = 0; cc < 4; ++cc) {
        accg[r][cc] += av[r].x * bv[cc].x + av[r].y * bv[cc].y
                     + av[r].z * bv[cc].z + av[r].w * bv[cc].w;
      }
    }
  }
  const size_t abase = ((size_t)bh * 64 + n) * 64 * 64;
  #pragma unroll
  for (int r = 0; r < 4; ++r) {
    #pragma unroll
    for (int cc = 0; cc < 4; ++cc) {
      int a = ty * 4 + r, j = tx + 16 * cc;
      if (a > j) {
        A[a][j] = -betaS[a] * accg[r][cc] * gpow[a - j];
        attn[abase + (size_t)(a - 1) * 64 + j] = f2bf(accg[r][cc] * gpow[a - 1 - j]);
      } else {
        A[a][j] = 0.f;
        if (a >= 1) attn[abase + (size_t)(a - 1) * 64 + j] = 0;
      }
    }
  }
  if (tid < 64) {
    int j = tid;
    float gg = 0.f;
    for (int pq = 0; pq < 32; ++pq) {
      float4 u = *(const float4*)&rkx[64][pq * 4];
      float4 w = *(const float4*)&rkx[j][pq * 4];
      gg += u.x * w.x + u.y * w.y + u.z * w.z + u.w * w.w;
    }
    attn[abase + (size_t)63 * 64 + j] = f2bf(gg * gpow[63 - j]);
  }
  __syncthreads();
  {
    int k = tid & 63, sp = tid >> 6;
    for (int i = 1; i < 64; ++i) {
      float part = 0.f;
      #pragma unroll
      for (int jj = 0; jj < 16; ++jj) {
        int j = sp * 16 + jj;
        part += A[i][j] * A[j][k];
      }
      red[sp][k] = part;
      __syncthreads();
      if (tid < 64) A[i][tid] += red[0][tid] + red[1][tid] + red[2][tid] + red[3][tid];
      __syncthreads();
    }
  }
  int pq = tid & 31, ig = tid >> 5;
  for (int it = 0; it < 8; ++it) {
    int i = ig * 8 + it;
    float4 acc = make_float4(0.f, 0.f, 0.f, 0.f);
    for (int j = 0; j < 64; ++j) {
      float coef = (A[i][j] + (i == j ? 1.f : 0.f)) * bd[j];
      float4 rv = *(const float4*)&rkx[j][pq * 4];
      acc.x += coef * rv.x; acc.y += coef * rv.y;
      acc.z += coef * rv.z; acc.w += coef * rv.w;
    }
    us4 o; o[0] = f2bf(acc.x); o[1] = f2bf(acc.y); o[2] = f2bf(acc.z); o[3] = f2bf(acc.w);
    *(us4*)(wkcum + rbase + (size_t)i * 128 + pq * 4) = o;
  }
  __syncthreads();
  for (int idx = tid; idx < 64 * 32; idx += 256) {
    int row = idx >> 5, cc = idx & 31;
    us4 u = *(const us4*)(vb + rbase + (size_t)row * 128 + cc * 4);
    float4 v; v.x = bf2f(u[0]); v.y = bf2f(u[1]); v.z = bf2f(u[2]); v.w = bf2f(u[3]);
    *(float4*)&rkx[row][cc * 4] = v;
  }
  __syncthreads();
  for (int it = 0; it < 8; ++it) {
    int i = ig * 8 + it;
    float4 acc = make_float4(0.f, 0.f, 0.f, 0.f);
    for (int j = 0; j < 64; ++j) {
      float coef = A[i][j] + (i == j ? 1.f : 0.f);
      float4 rv = *(const float4*)&rkx[j][pq * 4];
      acc.x += coef * rv.x; acc.y += coef * rv.y;
      acc.z += coef * rv.z; acc.w += coef * rv.w;
    }
    us4 o; o[0] = f2bf(acc.x); o[1] = f2bf(acc.y); o[2] = f2bf(acc.z); o[3] = f2bf(acc.w);
    *(us4*)(vb + rbase + (size_t)i * 128 + pq * 4) = o;
  }
}

// ---------------- K4: chunk scan ----------------
__global__ __launch_bounds__(256) void k_scan(
    const ushort* __restrict__ rk, const ushort* __restrict__ vb,
    const ushort* __restrict__ wkcum, const ushort* __restrict__ attn,
    const float* __restrict__ decay, ushort* __restrict__ og)
{
  int bh = blockIdx.x >> 4;
  int qg = blockIdx.x & 15;
  int q0 = qg * 8;
  int b = bh >> 3, h = bh & 7;
  int tid = threadIdx.x;
  int q = tid & 7, g = tid >> 3;
  __shared__ float S_T[8][132];
  __shared__ float vnew[64][9];
  __shared__ float gpow[65];
  float lg = logf(1.f / (1.f + expf(-decay[h])));
  if (tid < 65) gpow[tid] = expf(lg * (float)tid);
  for (int idx = tid; idx < 8 * 132; idx += 256) ((float*)S_T)[idx] = 0.f;
  __syncthreads();
  float ct = gpow[64];
  const size_t rowbase = (size_t)bh * T_LEN * 128;
  for (int n = 0; n < 64; ++n) {
    int t0 = n * 64;
    #pragma unroll
    for (int ii = 0; ii < 2; ++ii) {
      int i = g * 2 + ii;
      const ushort* wr = wkcum + rowbase + (size_t)(t0 + i) * 128;
      const float* sr = &S_T[q][0];
      float acc = 0.f;
      #pragma unroll 4
      for (int pq = 0; pq < 16; ++pq) {
        us8 w8 = *(const us8*)(wr + pq * 8);
        #pragma unroll
        for (int s = 0; s < 8; ++s) acc += bf2f(w8[s]) * sr[pq * 8 + s];
      }
      vnew[i][q] = bf2f(vb[rowbase + (size_t)(t0 + i) * 128 + q0 + q]) - acc;
    }
    __syncthreads();
    #pragma unroll
    for (int ii = 0; ii < 2; ++ii) {
      int i = g * 2 + ii;
      const ushort* rr = rk + rowbase + (size_t)(t0 + i) * 128;
      const float* sr = &S_T[q][0];
      float acc = 0.f;
      #pragma unroll 4
      for (int pq = 0; pq < 16; ++pq) {
        us8 w8 = *(const us8*)(rr + pq * 8);
        #pragma unroll
        for (int s = 0; s < 8; ++s) acc += bf2f(w8[s]) * sr[pq * 8 + s];
      }
      acc *= gpow[i + 1];
      const ushort* ar = attn + (((size_t)bh * 64 + n) * 64 + i) * 64;
      #pragma unroll 2
      for (int kb = 0; kb < 8; ++kb) {
        us8 a8 = *(const us8*)(ar + kb * 8);
        #pragma unroll
        for (int s = 0; s < 8; ++s) acc += bf2f(a8[s]) * vnew[kb * 8 + s][q];
      }
      og[((size_t)b * T_LEN + t0 + i) * 1024 + h * 128 + q0 + q] = f2bf(acc);
    }
    __syncthreads();
    {
      int p = g * 4;
      float4 sv = *(float4*)&S_T[q][p];
      sv.x *= ct; sv.y *= ct; sv.z *= ct; sv.w *= ct;
      for (int i = 0; i < 64; ++i) {
        int t = t0 + i - 1;
        if (t >= 0) {
          float coef = gpow[63 - i] * vnew[i][q];
          us4 u = *(const us4*)(rk + rowbase + (size_t)t * 128 + p);
          sv.x += bf2f(u[0]) * coef; sv.y += bf2f(u[1]) * coef;
          sv.z += bf2f(u[2]) * coef; sv.w += bf2f(u[3]) * coef;
        }
      }
      *(float4*)&S_T[q][p] = sv;
    }
    __syncthreads();
  }
}

extern "C" void kernel_launch(void* const* d_in, const int* in_sizes, int n_in,
                              void* d_out, int out_size, void* d_ws, size_t ws_size,
                              hipStream_t stream) {
  const float* x   = (const float*)d_in[0];
  const float* Ww  = (const float*)d_in[1];
  const float* Wr  = (const float*)d_in[2];
  const float* Wb  = (const float*)d_in[3];
  const float* dec = (const float*)d_in[4];
  float* out = (float*)d_out;
  ushort* ws = (ushort*)d_ws;
  const size_t SZ = 32ull * 4096 * 128;
  ushort* rk    = ws;
  ushort* vb    = ws + SZ;
  ushort* wkcum = ws + 2 * SZ;
  ushort* og    = ws + 3 * SZ;
  ushort* attn  = ws + 4 * SZ;
  float*  beta  = (float*)(ws + 4 * SZ + 8388608ull);
  const size_t NEED = (4 * SZ + 8388608ull) * 2ull + 131072ull * 4ull;
  if (ws_size < NEED) {
    hipMemcpyAsync(d_out, (const void*)x, (size_t)out_size * 4, hipMemcpyDeviceToDevice, stream);
    return;
  }

  k_prep<<<dim3(16384), dim3(128), 0, stream>>>(x, Wb, rk, beta);
  k_gemm<0><<<dim3(8, 128), dim3(256), 0, stream>>>((const void*)x, Ww, beta, nullptr, (void*)vb);
  k_chunk<<<dim3(2048), dim3(256), 0, stream>>>(rk, vb, wkcum, attn, beta, dec);
  k_scan<<<dim3(512), dim3(256), 0, stream>>>(rk, vb, wkcum, attn, dec, og);
  k_gemm<1><<<dim3(8, 128), dim3(256), 0, stream>>>((const void*)og, Wr, nullptr, (const float*)x, (void*)out);
}

// Round 4
// 1885.120 us; speedup vs baseline: 1.4239x; 1.0654x over previous
//
#include <hip/hip_runtime.h>
#include <hip/hip_bf16.h>
#include <math.h>

// HebbianBlock: B=4, T=4096, D=1024, H=8, d=128, C=64, N=64
// Round 4: k_scan split into
//   k_scan_state: serial S-scan (vnew -> vb in place, S^T checkpoints -> sck bf16)
//   k_scan_out:   fully-parallel MFMA o_n = gamma*rk@S_n + attn@vnew (2048 blocks)
// k_prep / k_gemm / k_chunk identical to passing Round-3 versions.

#define T_LEN 4096
typedef unsigned short ushort;
typedef __attribute__((ext_vector_type(2))) unsigned short us2;
typedef __attribute__((ext_vector_type(4))) unsigned short us4;
typedef __attribute__((ext_vector_type(8))) unsigned short us8;
typedef __attribute__((ext_vector_type(8))) short short8v;
typedef __attribute__((ext_vector_type(4))) float f32x4;

__device__ __forceinline__ float bf2f(ushort u) {
  union { unsigned int u; float f; } c; c.u = ((unsigned int)u) << 16; return c.f;
}
__device__ __forceinline__ ushort f2bf(float x) {
  union { float f; unsigned int u; } c; c.f = x;
  unsigned int u = c.u + 0x7FFFu + ((c.u >> 16) & 1u);
  return (ushort)(u >> 16);
}
__device__ __forceinline__ ushort f2bf_fast(float x) {
  __hip_bfloat16 h = __float2bfloat16(x);
  return *reinterpret_cast<ushort*>(&h);
}

// ---------------- K1: rk + beta ----------------
__global__ __launch_bounds__(128) void k_prep(
    const float* __restrict__ x, const float* __restrict__ Wb,
    ushort* __restrict__ rk, float* __restrict__ beta)
{
  int bt = blockIdx.x;
  int b = bt >> 12, t = bt & 4095;
  int tid = threadIdx.x;
  __shared__ float xs[1024];
  __shared__ float red[16];
  {
    const float4* x4 = (const float4*)(x + (size_t)bt * 1024);
    float4* xs4 = (float4*)xs;
    xs4[tid] = x4[tid];
    xs4[tid + 128] = x4[tid + 128];
  }
  __syncthreads();
  int h = tid >> 4;
  int e0 = h * 128 + (tid & 15) * 8;
  float ss = 0.f;
  #pragma unroll
  for (int s = 0; s < 8; ++s) { float v = xs[e0 + s]; ss += v * v; }
  #pragma unroll
  for (int m = 1; m < 16; m <<= 1) ss += __shfl_xor(ss, m, 64);
  float inv = 1.f / fmaxf(sqrtf(ss), 1e-12f);
  {
    int bh = b * 8 + h;
    us8 o;
    #pragma unroll
    for (int s = 0; s < 8; ++s) o[s] = f2bf(xs[e0 + s] * inv);
    *(us8*)(rk + ((size_t)bh * T_LEN + t) * 128 + (tid & 15) * 8) = o;
  }
  const float* xk = xs + tid * 8;
  #pragma unroll
  for (int h2 = 0; h2 < 8; ++h2) {
    const float* wb = Wb + (size_t)h2 * 1024 + tid * 8;
    float p = 0.f;
    #pragma unroll
    for (int s = 0; s < 8; ++s) p += xk[s] * wb[s];
    #pragma unroll
    for (int m = 1; m < 64; m <<= 1) p += __shfl_xor(p, m, 64);
    if ((tid & 63) == 0) red[(tid >> 6) * 8 + h2] = p;
  }
  __syncthreads();
  if (tid < 8) {
    float s = red[tid] + red[8 + tid];
    beta[((size_t)(b * 8 + tid)) * T_LEN + t] = 1.f / (1.f + expf(-s));
  }
}

// ---------------- K2/K5: bf16 MFMA GEMM, 128x128 tile, BK=32 ----------------
#define LDK 40
template<int MODE>
__global__ __launch_bounds__(256) void k_gemm(
    const void* __restrict__ Am_, const float* __restrict__ W,
    const float* __restrict__ beta, const float* __restrict__ xadd,
    void* __restrict__ out_)
{
  __shared__ ushort As[128 * LDK];
  __shared__ ushort Bs[128 * LDK];
  const int n0 = blockIdx.x * 128;
  const int m0 = blockIdx.y * 128;
  const int tid = threadIdx.x;
  const int lane = tid & 63;
  const int wid = tid >> 6;
  const int wr = wid >> 1, wc = wid & 1;
  const int c = lane & 15, g = lane >> 4;
  const int srow = tid >> 2;
  const int seg = tid & 3;

  f32x4 acc[4][4] = {};

  for (int k0 = 0; k0 < 1024; k0 += 32) {
    if (MODE == 0) {
      const float* a0 = (const float*)Am_ + (size_t)(m0 + srow) * 1024 + k0 + seg * 8;
      const float* a1 = (const float*)Am_ + (size_t)(m0 + srow + 64) * 1024 + k0 + seg * 8;
      float4 p0 = *(const float4*)a0, p1 = *(const float4*)(a0 + 4);
      float4 q0 = *(const float4*)a1, q1 = *(const float4*)(a1 + 4);
      us8 o0, o1;
      o0[0]=f2bf_fast(p0.x); o0[1]=f2bf_fast(p0.y); o0[2]=f2bf_fast(p0.z); o0[3]=f2bf_fast(p0.w);
      o0[4]=f2bf_fast(p1.x); o0[5]=f2bf_fast(p1.y); o0[6]=f2bf_fast(p1.z); o0[7]=f2bf_fast(p1.w);
      o1[0]=f2bf_fast(q0.x); o1[1]=f2bf_fast(q0.y); o1[2]=f2bf_fast(q0.z); o1[3]=f2bf_fast(q0.w);
      o1[4]=f2bf_fast(q1.x); o1[5]=f2bf_fast(q1.y); o1[6]=f2bf_fast(q1.z); o1[7]=f2bf_fast(q1.w);
      *(us8*)&As[srow * LDK + seg * 8] = o0;
      *(us8*)&As[(srow + 64) * LDK + seg * 8] = o1;
    } else {
      us8 o0 = *(const us8*)((const ushort*)Am_ + (size_t)(m0 + srow) * 1024 + k0 + seg * 8);
      us8 o1 = *(const us8*)((const ushort*)Am_ + (size_t)(m0 + srow + 64) * 1024 + k0 + seg * 8);
      *(us8*)&As[srow * LDK + seg * 8] = o0;
      *(us8*)&As[(srow + 64) * LDK + seg * 8] = o1;
    }
    {
      const float* b0 = W + (size_t)(n0 + srow) * 1024 + k0 + seg * 8;
      const float* b1 = W + (size_t)(n0 + srow + 64) * 1024 + k0 + seg * 8;
      float4 p0 = *(const float4*)b0, p1 = *(const float4*)(b0 + 4);
      float4 q0 = *(const float4*)b1, q1 = *(const float4*)(b1 + 4);
      us8 o0, o1;
      o0[0]=f2bf_fast(p0.x); o0[1]=f2bf_fast(p0.y); o0[2]=f2bf_fast(p0.z); o0[3]=f2bf_fast(p0.w);
      o0[4]=f2bf_fast(p1.x); o0[5]=f2bf_fast(p1.y); o0[6]=f2bf_fast(p1.z); o0[7]=f2bf_fast(p1.w);
      o1[0]=f2bf_fast(q0.x); o1[1]=f2bf_fast(q0.y); o1[2]=f2bf_fast(q0.z); o1[3]=f2bf_fast(q0.w);
      o1[4]=f2bf_fast(q1.x); o1[5]=f2bf_fast(q1.y); o1[6]=f2bf_fast(q1.z); o1[7]=f2bf_fast(q1.w);
      *(us8*)&Bs[srow * LDK + seg * 8] = o0;
      *(us8*)&Bs[(srow + 64) * LDK + seg * 8] = o1;
    }
    __syncthreads();
    short8v af[4], bf[4];
    #pragma unroll
    for (int mi = 0; mi < 4; ++mi)
      af[mi] = *(const short8v*)&As[(wr * 64 + mi * 16 + c) * LDK + g * 8];
    #pragma unroll
    for (int ni = 0; ni < 4; ++ni)
      bf[ni] = *(const short8v*)&Bs[(wc * 64 + ni * 16 + c) * LDK + g * 8];
    #pragma unroll
    for (int mi = 0; mi < 4; ++mi)
      #pragma unroll
      for (int ni = 0; ni < 4; ++ni)
        acc[mi][ni] = __builtin_amdgcn_mfma_f32_16x16x32_bf16(af[mi], bf[ni], acc[mi][ni], 0, 0, 0);
    __syncthreads();
  }

  if (MODE == 0) {
    ushort* vb = (ushort*)out_;
    const int hh = n0 >> 7;
    #pragma unroll
    for (int mi = 0; mi < 4; ++mi) {
      #pragma unroll
      for (int ni = 0; ni < 4; ++ni) {
        int jc = wc * 64 + ni * 16 + c;
        #pragma unroll
        for (int j = 0; j < 4; ++j) {
          int m = m0 + wr * 64 + mi * 16 + g * 4 + j;
          int b = m >> 12, t = m & 4095;
          size_t base = (size_t)(b * 8 + hh) * T_LEN + t;
          float bv = beta[base];
          vb[base * 128 + jc] = f2bf(acc[mi][ni][j] * bv);
        }
      }
    }
  } else {
    float* out = (float*)out_;
    #pragma unroll
    for (int mi = 0; mi < 4; ++mi) {
      #pragma unroll
      for (int ni = 0; ni < 4; ++ni) {
        int n = n0 + wc * 64 + ni * 16 + c;
        #pragma unroll
        for (int j = 0; j < 4; ++j) {
          int m = m0 + wr * 64 + mi * 16 + g * 4 + j;
          size_t idx = (size_t)m * 1024 + n;
          out[idx] = xadd[idx] + acc[mi][ni][j];
        }
      }
    }
  }
}

// ---------------- K3: per-chunk UT transform ----------------
__global__ __launch_bounds__(256) void k_chunk(
    const ushort* __restrict__ rk, ushort* __restrict__ vb,
    ushort* __restrict__ wkcum, ushort* __restrict__ attn,
    const float* __restrict__ beta, const float* __restrict__ decay)
{
  int bh = blockIdx.x >> 6;
  int n = blockIdx.x & 63;
  int h = bh & 7;
  int tid = threadIdx.x;
  __shared__ float rkx[65][132];
  __shared__ float A[64][66];
  __shared__ float red[4][64];
  __shared__ float betaS[64], bd[64], gpow[65];
  float lg = logf(1.f / (1.f + expf(-decay[h])));
  if (tid < 65) gpow[tid] = expf(lg * (float)tid);
  if (tid < 64) betaS[tid] = beta[(size_t)bh * T_LEN + n * 64 + tid];
  __syncthreads();
  if (tid < 64) bd[tid] = betaS[tid] * gpow[tid + 1];
  const size_t rbase = ((size_t)bh * T_LEN + n * 64) * 128;
  for (int idx = tid; idx < 65 * 32; idx += 256) {
    int row = idx >> 5, cc = idx & 31;
    int t = n * 64 + row - 1;
    float4 v = make_float4(0.f, 0.f, 0.f, 0.f);
    if (t >= 0) {
      us4 u = *(const us4*)(rk + ((size_t)bh * T_LEN + t) * 128 + cc * 4);
      v.x = bf2f(u[0]); v.y = bf2f(u[1]); v.z = bf2f(u[2]); v.w = bf2f(u[3]);
    }
    *(float4*)&rkx[row][cc * 4] = v;
  }
  __syncthreads();
  int tx = tid & 15, ty = tid >> 4;
  float accg[4][4] = {};
  for (int pq = 0; pq < 32; ++pq) {
    float4 av[4], bv[4];
    #pragma unroll
    for (int r = 0; r < 4; ++r) av[r] = *(const float4*)&rkx[ty * 4 + r][pq * 4];
    #pragma unroll
    for (int cc = 0; cc < 4; ++cc) bv[cc] = *(const float4*)&rkx[tx + 16 * cc][pq * 4];
    #pragma unroll
    for (int r = 0; r < 4; ++r) {
      #pragma unroll
      for (int cc = 0; cc < 4; ++cc) {
        accg[r][cc] += av[r].x * bv[cc].x + av[r].y * bv[cc].y
                     + av[r].z * bv[cc].z + av[r].w * bv[cc].w;
      }
    }
  }
  const size_t abase = ((size_t)bh * 64 + n) * 64 * 64;
  #pragma unroll
  for (int r = 0; r < 4; ++r) {
    #pragma unroll
    for (int cc = 0; cc < 4; ++cc) {
      int a = ty * 4 + r, j = tx + 16 * cc;
      if (a > j) {
        A[a][j] = -betaS[a] * accg[r][cc] * gpow[a - j];
        attn[abase + (size_t)(a - 1) * 64 + j] = f2bf(accg[r][cc] * gpow[a - 1 - j]);
      } else {
        A[a][j] = 0.f;
        if (a >= 1) attn[abase + (size_t)(a - 1) * 64 + j] = 0;
      }
    }
  }
  if (tid < 64) {
    int j = tid;
    float gg = 0.f;
    for (int pq = 0; pq < 32; ++pq) {
      float4 u = *(const float4*)&rkx[64][pq * 4];
      float4 w = *(const float4*)&rkx[j][pq * 4];
      gg += u.x * w.x + u.y * w.y + u.z * w.z + u.w * w.w;
    }
    attn[abase + (size_t)63 * 64 + j] = f2bf(gg * gpow[63 - j]);
  }
  __syncthreads();
  {
    int k = tid & 63, sp = tid >> 6;
    for (int i = 1; i < 64; ++i) {
      float part = 0.f;
      #pragma unroll
      for (int jj = 0; jj < 16; ++jj) {
        int j = sp * 16 + jj;
        part += A[i][j] * A[j][k];
      }
      red[sp][k] = part;
      __syncthreads();
      if (tid < 64) A[i][tid] += red[0][tid] + red[1][tid] + red[2][tid] + red[3][tid];
      __syncthreads();
    }
  }
  int pq = tid & 31, ig = tid >> 5;
  for (int it = 0; it < 8; ++it) {
    int i = ig * 8 + it;
    float4 acc = make_float4(0.f, 0.f, 0.f, 0.f);
    for (int j = 0; j < 64; ++j) {
      float coef = (A[i][j] + (i == j ? 1.f : 0.f)) * bd[j];
      float4 rv = *(const float4*)&rkx[j][pq * 4];
      acc.x += coef * rv.x; acc.y += coef * rv.y;
      acc.z += coef * rv.z; acc.w += coef * rv.w;
    }
    us4 o; o[0] = f2bf(acc.x); o[1] = f2bf(acc.y); o[2] = f2bf(acc.z); o[3] = f2bf(acc.w);
    *(us4*)(wkcum + rbase + (size_t)i * 128 + pq * 4) = o;
  }
  __syncthreads();
  for (int idx = tid; idx < 64 * 32; idx += 256) {
    int row = idx >> 5, cc = idx & 31;
    us4 u = *(const us4*)(vb + rbase + (size_t)row * 128 + cc * 4);
    float4 v; v.x = bf2f(u[0]); v.y = bf2f(u[1]); v.z = bf2f(u[2]); v.w = bf2f(u[3]);
    *(float4*)&rkx[row][cc * 4] = v;
  }
  __syncthreads();
  for (int it = 0; it < 8; ++it) {
    int i = ig * 8 + it;
    float4 acc = make_float4(0.f, 0.f, 0.f, 0.f);
    for (int j = 0; j < 64; ++j) {
      float coef = A[i][j] + (i == j ? 1.f : 0.f);
      float4 rv = *(const float4*)&rkx[j][pq * 4];
      acc.x += coef * rv.x; acc.y += coef * rv.y;
      acc.z += coef * rv.z; acc.w += coef * rv.w;
    }
    us4 o; o[0] = f2bf(acc.x); o[1] = f2bf(acc.y); o[2] = f2bf(acc.z); o[3] = f2bf(acc.w);
    *(us4*)(vb + rbase + (size_t)i * 128 + pq * 4) = o;
  }
}

// ---------------- K4a: serial state scan ----------------
// blocks = 32 bh x 32 colgroups (4 cols each). Per chunk:
//  - checkpoint S^T rows (bf16) -> sck
//  - vnew = v - wkcum @ S  (overwrites vb in place, also kept in LDS)
//  - S = ct*S + sum_i wk[i]*gamma^(63-i)*vnew[i]
__global__ __launch_bounds__(256) void k_scan_state(
    const ushort* __restrict__ rk, ushort* __restrict__ vb,
    const ushort* __restrict__ wkcum, const float* __restrict__ decay,
    ushort* __restrict__ sck)
{
  int bh = blockIdx.x >> 5;
  int qg = blockIdx.x & 31;
  int q0 = qg * 4;
  int h = bh & 7;
  int tid = threadIdx.x;
  int q = tid & 3, g = tid >> 2;   // g: 0..63
  __shared__ float S_T[4][132];    // S_T[q][p] = S[p][q0+q]
  __shared__ float vnew[64][5];
  __shared__ float gpow[65];
  float lg = logf(1.f / (1.f + expf(-decay[h])));
  if (tid < 65) gpow[tid] = expf(lg * (float)tid);
  for (int idx = tid; idx < 4 * 132; idx += 256) ((float*)S_T)[idx] = 0.f;
  __syncthreads();
  float ct = gpow[64];
  const size_t rowbase = (size_t)bh * T_LEN * 128;
  const size_t ckbh = (size_t)bh * 64;
  for (int n = 0; n < 64; ++n) {
    int t0 = n * 64;
    // checkpoint S^T (pre-update state) -> sck, rows q0..q0+3 (coalesced us2)
    {
      int e = tid * 2;
      int row = e >> 7, p = e & 127;
      us2 o; o[0] = f2bf(S_T[row][p]); o[1] = f2bf(S_T[row][p + 1]);
      *(us2*)(sck + ((ckbh + n) * 128 + (q0 + row)) * 128 + p) = o;
    }
    // phase A: vnew[g][q] = v - wkcum[g,:] . S_T[q,:]
    {
      const ushort* wr = wkcum + rowbase + (size_t)(t0 + g) * 128;
      const float* sr = &S_T[q][0];
      float acc = 0.f;
      #pragma unroll 4
      for (int pc = 0; pc < 16; ++pc) {
        us8 w8 = *(const us8*)(wr + pc * 8);
        #pragma unroll
        for (int s = 0; s < 8; ++s) acc += bf2f(w8[s]) * sr[pc * 8 + s];
      }
      size_t vidx = rowbase + (size_t)(t0 + g) * 128 + q0 + q;
      float v = bf2f(vb[vidx]) - acc;
      vnew[g][q] = v;
      vb[vidx] = f2bf(v);
    }
    __syncthreads();
    // phase C: S update (2 p-values per thread)
    {
      int p = g * 2;
      float s0 = S_T[q][p] * ct, s1 = S_T[q][p + 1] * ct;
      for (int i = 0; i < 64; ++i) {
        int t = t0 + i - 1;
        if (t >= 0) {
          float coef = gpow[63 - i] * vnew[i][q];
          us2 u = *(const us2*)(rk + rowbase + (size_t)t * 128 + p);
          s0 += bf2f(u[0]) * coef;
          s1 += bf2f(u[1]) * coef;
        }
      }
      S_T[q][p] = s0; S_T[q][p + 1] = s1;
    }
    __syncthreads();
  }
}

// ---------------- K4b: parallel MFMA output ----------------
// blocks = 32 bh x 64 chunks; 4 waves; per wave: 16-row band of
// o = gamma^(i+1) * rk @ S_n + attn @ vnew   (vnew read from vb)
__global__ __launch_bounds__(256) void k_scan_out(
    const ushort* __restrict__ rk, const ushort* __restrict__ vb,
    const ushort* __restrict__ attn, const ushort* __restrict__ sck,
    const float* __restrict__ decay, ushort* __restrict__ og)
{
  int bh = blockIdx.x >> 6;
  int n = blockIdx.x & 63;
  int b = bh >> 3, h = bh & 7;
  int t0 = n * 64;
  int tid = threadIdx.x;
  int lane = tid & 63, w = tid >> 6;
  int c = lane & 15, g = lane >> 4;
  __shared__ ushort vnT[128][72];   // vnew^T: [d][i], pad 72 (2-way conflicts = free)
  __shared__ float gpow[65];
  float lg = logf(1.f / (1.f + expf(-decay[h])));
  if (tid < 65) gpow[tid] = expf(lg * (float)tid);
  const size_t rowbase = (size_t)bh * T_LEN * 128;
  // stage vnew^T
  #pragma unroll
  for (int u = 0; u < 4; ++u) {
    int idx = tid * 4 + u;
    int i = idx >> 4, d0 = (idx & 15) * 8;
    us8 vv = *(const us8*)(vb + rowbase + (size_t)(t0 + i) * 128 + d0);
    #pragma unroll
    for (int j = 0; j < 8; ++j) vnT[d0 + j][i] = vv[j];
  }
  __syncthreads();

  f32x4 acc[8] = {};
  const size_t sbase = ((size_t)bh * 64 + n) * 128 * 128;
  // o += rk @ S : A=rk rows (band 16w), B=S^T rows (sck)
  #pragma unroll
  for (int ks = 0; ks < 4; ++ks) {
    short8v a = *(const short8v*)(rk + rowbase + (size_t)(t0 + 16 * w + c) * 128 + ks * 32 + g * 8);
    #pragma unroll
    for (int ctile = 0; ctile < 8; ++ctile) {
      short8v bfr = *(const short8v*)(sck + sbase + (size_t)(ctile * 16 + c) * 128 + ks * 32 + g * 8);
      acc[ctile] = __builtin_amdgcn_mfma_f32_16x16x32_bf16(a, bfr, acc[ctile], 0, 0, 0);
    }
  }
  // scale rows by gamma^(i+1), i = 16w + 4g + r
  #pragma unroll
  for (int ctile = 0; ctile < 8; ++ctile) {
    #pragma unroll
    for (int r = 0; r < 4; ++r) acc[ctile][r] *= gpow[16 * w + 4 * g + r + 1];
  }
  // o += attn @ vnew : A=attn rows, B=vnew^T rows (LDS)
  const size_t abase = ((size_t)bh * 64 + n) * 64 * 64;
  #pragma unroll
  for (int ks = 0; ks < 2; ++ks) {
    short8v a = *(const short8v*)(attn + abase + (size_t)(16 * w + c) * 64 + ks * 32 + g * 8);
    #pragma unroll
    for (int ctile = 0; ctile < 8; ++ctile) {
      short8v bfr = *(const short8v*)&vnT[ctile * 16 + c][ks * 32 + g * 8];
      acc[ctile] = __builtin_amdgcn_mfma_f32_16x16x32_bf16(a, bfr, acc[ctile], 0, 0, 0);
    }
  }
  // write og
  #pragma unroll
  for (int ctile = 0; ctile < 8; ++ctile) {
    #pragma unroll
    for (int r = 0; r < 4; ++r) {
      int i = 16 * w + 4 * g + r;
      og[((size_t)b * T_LEN + t0 + i) * 1024 + h * 128 + ctile * 16 + c] = f2bf(acc[ctile][r]);
    }
  }
}

extern "C" void kernel_launch(void* const* d_in, const int* in_sizes, int n_in,
                              void* d_out, int out_size, void* d_ws, size_t ws_size,
                              hipStream_t stream) {
  const float* x   = (const float*)d_in[0];
  const float* Ww  = (const float*)d_in[1];
  const float* Wr  = (const float*)d_in[2];
  const float* Wb  = (const float*)d_in[3];
  const float* dec = (const float*)d_in[4];
  float* out = (float*)d_out;
  ushort* ws = (ushort*)d_ws;
  const size_t SZ = 16777216ull;                 // 32*4096*128
  ushort* rk    = ws;                            // 32 MB
  ushort* vb    = ws + SZ;                       // 32 MB (becomes vnew in-place)
  ushort* wkcum = ws + 2 * SZ;                   // 32 MB
  ushort* og    = ws + 3 * SZ;                   // 32 MB
  ushort* attn  = ws + 4 * SZ;                   // 16 MB
  float*  beta  = (float*)(ws + 4 * SZ + 8388608ull);  // 0.5 MB
  ushort* sck   = ws + 4 * SZ + 8388608ull + 262144ull; // 64 MB (32*64*128*128 bf16)
  const size_t NEED = 218628096ull;
  if (ws_size < NEED) {
    // diagnostic fallback: out = x (err ~3-4 => ws too small; 5.5 => not launched)
    hipMemcpyAsync(d_out, (const void*)x, (size_t)out_size * 4, hipMemcpyDeviceToDevice, stream);
    return;
  }

  k_prep<<<dim3(16384), dim3(128), 0, stream>>>(x, Wb, rk, beta);
  k_gemm<0><<<dim3(8, 128), dim3(256), 0, stream>>>((const void*)x, Ww, beta, nullptr, (void*)vb);
  k_chunk<<<dim3(2048), dim3(256), 0, stream>>>(rk, vb, wkcum, attn, beta, dec);
  k_scan_state<<<dim3(1024), dim3(256), 0, stream>>>(rk, vb, wkcum, dec, sck);
  k_scan_out<<<dim3(2048), dim3(256), 0, stream>>>(rk, vb, attn, sck, dec, og);
  k_gemm<1><<<dim3(8, 128), dim3(256), 0, stream>>>((const void*)og, Wr, nullptr, (const float*)x, (void*)out);
}

// Round 5
// 1167.230 us; speedup vs baseline: 2.2996x; 1.6150x over previous
//
#include <hip/hip_runtime.h>
#include <hip/hip_bf16.h>
#include <math.h>

// HebbianBlock: B=4, T=4096, D=1024, H=8, d=128, C=64, N=64
// Round 5: k_chunk rewritten with MFMA (G, 4a, 4b) — was LDS-BW-bound VALU.
// k_prep / k_gemm / k_scan_state / k_scan_out verbatim from passing Round 4.

#define T_LEN 4096
typedef unsigned short ushort;
typedef __attribute__((ext_vector_type(2))) unsigned short us2;
typedef __attribute__((ext_vector_type(4))) unsigned short us4;
typedef __attribute__((ext_vector_type(8))) unsigned short us8;
typedef __attribute__((ext_vector_type(8))) short short8v;
typedef __attribute__((ext_vector_type(4))) float f32x4;

__device__ __forceinline__ float bf2f(ushort u) {
  union { unsigned int u; float f; } c; c.u = ((unsigned int)u) << 16; return c.f;
}
__device__ __forceinline__ ushort f2bf(float x) {
  union { float f; unsigned int u; } c; c.f = x;
  unsigned int u = c.u + 0x7FFFu + ((c.u >> 16) & 1u);
  return (ushort)(u >> 16);
}
__device__ __forceinline__ ushort f2bf_fast(float x) {
  __hip_bfloat16 h = __float2bfloat16(x);
  return *reinterpret_cast<ushort*>(&h);
}

// ---------------- K1: rk + beta ----------------
__global__ __launch_bounds__(128) void k_prep(
    const float* __restrict__ x, const float* __restrict__ Wb,
    ushort* __restrict__ rk, float* __restrict__ beta)
{
  int bt = blockIdx.x;
  int b = bt >> 12, t = bt & 4095;
  int tid = threadIdx.x;
  __shared__ float xs[1024];
  __shared__ float red[16];
  {
    const float4* x4 = (const float4*)(x + (size_t)bt * 1024);
    float4* xs4 = (float4*)xs;
    xs4[tid] = x4[tid];
    xs4[tid + 128] = x4[tid + 128];
  }
  __syncthreads();
  int h = tid >> 4;
  int e0 = h * 128 + (tid & 15) * 8;
  float ss = 0.f;
  #pragma unroll
  for (int s = 0; s < 8; ++s) { float v = xs[e0 + s]; ss += v * v; }
  #pragma unroll
  for (int m = 1; m < 16; m <<= 1) ss += __shfl_xor(ss, m, 64);
  float inv = 1.f / fmaxf(sqrtf(ss), 1e-12f);
  {
    int bh = b * 8 + h;
    us8 o;
    #pragma unroll
    for (int s = 0; s < 8; ++s) o[s] = f2bf(xs[e0 + s] * inv);
    *(us8*)(rk + ((size_t)bh * T_LEN + t) * 128 + (tid & 15) * 8) = o;
  }
  const float* xk = xs + tid * 8;
  #pragma unroll
  for (int h2 = 0; h2 < 8; ++h2) {
    const float* wb = Wb + (size_t)h2 * 1024 + tid * 8;
    float p = 0.f;
    #pragma unroll
    for (int s = 0; s < 8; ++s) p += xk[s] * wb[s];
    #pragma unroll
    for (int m = 1; m < 64; m <<= 1) p += __shfl_xor(p, m, 64);
    if ((tid & 63) == 0) red[(tid >> 6) * 8 + h2] = p;
  }
  __syncthreads();
  if (tid < 8) {
    float s = red[tid] + red[8 + tid];
    beta[((size_t)(b * 8 + tid)) * T_LEN + t] = 1.f / (1.f + expf(-s));
  }
}

// ---------------- K2/K5: bf16 MFMA GEMM, 128x128 tile, BK=32 ----------------
#define LDK 40
template<int MODE>
__global__ __launch_bounds__(256) void k_gemm(
    const void* __restrict__ Am_, const float* __restrict__ W,
    const float* __restrict__ beta, const float* __restrict__ xadd,
    void* __restrict__ out_)
{
  __shared__ ushort As[128 * LDK];
  __shared__ ushort Bs[128 * LDK];
  const int n0 = blockIdx.x * 128;
  const int m0 = blockIdx.y * 128;
  const int tid = threadIdx.x;
  const int lane = tid & 63;
  const int wid = tid >> 6;
  const int wr = wid >> 1, wc = wid & 1;
  const int c = lane & 15, g = lane >> 4;
  const int srow = tid >> 2;
  const int seg = tid & 3;

  f32x4 acc[4][4] = {};

  for (int k0 = 0; k0 < 1024; k0 += 32) {
    if (MODE == 0) {
      const float* a0 = (const float*)Am_ + (size_t)(m0 + srow) * 1024 + k0 + seg * 8;
      const float* a1 = (const float*)Am_ + (size_t)(m0 + srow + 64) * 1024 + k0 + seg * 8;
      float4 p0 = *(const float4*)a0, p1 = *(const float4*)(a0 + 4);
      float4 q0 = *(const float4*)a1, q1 = *(const float4*)(a1 + 4);
      us8 o0, o1;
      o0[0]=f2bf_fast(p0.x); o0[1]=f2bf_fast(p0.y); o0[2]=f2bf_fast(p0.z); o0[3]=f2bf_fast(p0.w);
      o0[4]=f2bf_fast(p1.x); o0[5]=f2bf_fast(p1.y); o0[6]=f2bf_fast(p1.z); o0[7]=f2bf_fast(p1.w);
      o1[0]=f2bf_fast(q0.x); o1[1]=f2bf_fast(q0.y); o1[2]=f2bf_fast(q0.z); o1[3]=f2bf_fast(q0.w);
      o1[4]=f2bf_fast(q1.x); o1[5]=f2bf_fast(q1.y); o1[6]=f2bf_fast(q1.z); o1[7]=f2bf_fast(q1.w);
      *(us8*)&As[srow * LDK + seg * 8] = o0;
      *(us8*)&As[(srow + 64) * LDK + seg * 8] = o1;
    } else {
      us8 o0 = *(const us8*)((const ushort*)Am_ + (size_t)(m0 + srow) * 1024 + k0 + seg * 8);
      us8 o1 = *(const us8*)((const ushort*)Am_ + (size_t)(m0 + srow + 64) * 1024 + k0 + seg * 8);
      *(us8*)&As[srow * LDK + seg * 8] = o0;
      *(us8*)&As[(srow + 64) * LDK + seg * 8] = o1;
    }
    {
      const float* b0 = W + (size_t)(n0 + srow) * 1024 + k0 + seg * 8;
      const float* b1 = W + (size_t)(n0 + srow + 64) * 1024 + k0 + seg * 8;
      float4 p0 = *(const float4*)b0, p1 = *(const float4*)(b0 + 4);
      float4 q0 = *(const float4*)b1, q1 = *(const float4*)(b1 + 4);
      us8 o0, o1;
      o0[0]=f2bf_fast(p0.x); o0[1]=f2bf_fast(p0.y); o0[2]=f2bf_fast(p0.z); o0[3]=f2bf_fast(p0.w);
      o0[4]=f2bf_fast(p1.x); o0[5]=f2bf_fast(p1.y); o0[6]=f2bf_fast(p1.z); o0[7]=f2bf_fast(p1.w);
      o1[0]=f2bf_fast(q0.x); o1[1]=f2bf_fast(q0.y); o1[2]=f2bf_fast(q0.z); o1[3]=f2bf_fast(q0.w);
      o1[4]=f2bf_fast(q1.x); o1[5]=f2bf_fast(q1.y); o1[6]=f2bf_fast(q1.z); o1[7]=f2bf_fast(q1.w);
      *(us8*)&Bs[srow * LDK + seg * 8] = o0;
      *(us8*)&Bs[(srow + 64) * LDK + seg * 8] = o1;
    }
    __syncthreads();
    short8v af[4], bf[4];
    #pragma unroll
    for (int mi = 0; mi < 4; ++mi)
      af[mi] = *(const short8v*)&As[(wr * 64 + mi * 16 + c) * LDK + g * 8];
    #pragma unroll
    for (int ni = 0; ni < 4; ++ni)
      bf[ni] = *(const short8v*)&Bs[(wc * 64 + ni * 16 + c) * LDK + g * 8];
    #pragma unroll
    for (int mi = 0; mi < 4; ++mi)
      #pragma unroll
      for (int ni = 0; ni < 4; ++ni)
        acc[mi][ni] = __builtin_amdgcn_mfma_f32_16x16x32_bf16(af[mi], bf[ni], acc[mi][ni], 0, 0, 0);
    __syncthreads();
  }

  if (MODE == 0) {
    ushort* vb = (ushort*)out_;
    const int hh = n0 >> 7;
    #pragma unroll
    for (int mi = 0; mi < 4; ++mi) {
      #pragma unroll
      for (int ni = 0; ni < 4; ++ni) {
        int jc = wc * 64 + ni * 16 + c;
        #pragma unroll
        for (int j = 0; j < 4; ++j) {
          int m = m0 + wr * 64 + mi * 16 + g * 4 + j;
          int b = m >> 12, t = m & 4095;
          size_t base = (size_t)(b * 8 + hh) * T_LEN + t;
          float bv = beta[base];
          vb[base * 128 + jc] = f2bf(acc[mi][ni][j] * bv);
        }
      }
    }
  } else {
    float* out = (float*)out_;
    #pragma unroll
    for (int mi = 0; mi < 4; ++mi) {
      #pragma unroll
      for (int ni = 0; ni < 4; ++ni) {
        int n = n0 + wc * 64 + ni * 16 + c;
        #pragma unroll
        for (int j = 0; j < 4; ++j) {
          int m = m0 + wr * 64 + mi * 16 + g * 4 + j;
          size_t idx = (size_t)m * 1024 + n;
          out[idx] = xadd[idx] + acc[mi][ni][j];
        }
      }
    }
  }
}

// ---------------- K3: per-chunk UT transform (MFMA version) ----------------
// G via MFMA from rkb (bf16 LDS); UT serial (f32 LDS); 4a/4b via MFMA with
// transposed B-operands staged in xT (reused wk^T then v^T).
__global__ __launch_bounds__(256) void k_chunk(
    const ushort* __restrict__ rk, ushort* __restrict__ vb,
    ushort* __restrict__ wkcum, ushort* __restrict__ attn,
    const float* __restrict__ beta, const float* __restrict__ decay)
{
  int bh = blockIdx.x >> 6;
  int n = blockIdx.x & 63;
  int h = bh & 7;
  int tid = threadIdx.x;
  int lane = tid & 63, w = tid >> 6;
  int c = lane & 15, g = lane >> 4;

  __shared__ ushort rkb[80 * 136];   // wkext rows 0..64 bf16 (65..79 zero)
  __shared__ float  Af[64 * 68];     // A matrix f32 (UT workspace)
  __shared__ ushort Ab1[64 * 72];    // (A+I)*diag(bd) bf16
  __shared__ ushort Ab2[64 * 72];    // (A+I) bf16
  __shared__ ushort xT[128 * 72];    // wk^T, then v^T (B-operand)
  __shared__ float  red[4][64];
  __shared__ float  betaS[64], bd[64], gpow[65];

  float lg = logf(1.f / (1.f + expf(-decay[h])));
  if (tid < 65) gpow[tid] = expf(lg * (float)tid);
  if (tid < 64) betaS[tid] = beta[(size_t)bh * T_LEN + n * 64 + tid];
  const int t0 = n * 64;
  const size_t bhbase = (size_t)bh * T_LEN;

  // stage rkb rows 0..64 (row r = rk[t0+r-1], zero if t<0); zero rows 65..79
  #pragma unroll
  for (int u = 0; u < 5; ++u) {
    int idx = tid + u * 256;
    int row = idx >> 4, cb = idx & 15;
    us8 v = {0, 0, 0, 0, 0, 0, 0, 0};
    int t = t0 + row - 1;
    if (row <= 64 && t >= 0) v = *(const us8*)(rk + (bhbase + t) * 128 + cb * 8);
    *(us8*)&rkb[row * 136 + cb * 8] = v;
  }
  // zero Af (upper tiles never written by G epilogue)
  for (int idx = tid; idx < 64 * 68; idx += 256) Af[idx] = 0.f;
  __syncthreads();
  if (tid < 64) bd[tid] = betaS[tid] * gpow[tid + 1];

  // ---- G via MFMA: tiles (tr,tc), tr>=tc plus tr=4 row (a=64) ----
  const size_t abase = ((size_t)bh * 64 + n) * 4096;
  {
    const int TR[14] = {0,1,1,2,2,2,3,3,3,3,4,4,4,4};
    const int TC[14] = {0,0,1,0,1,2,0,1,2,3,0,1,2,3};
    #pragma unroll
    for (int ti = 0; ti < 14; ++ti) {
      if ((ti & 3) != w) continue;            // wave-uniform branch
      const int tr = TR[ti], tc = TC[ti];     // compile-time (unrolled)
      f32x4 acc = {0.f, 0.f, 0.f, 0.f};
      #pragma unroll
      for (int ks = 0; ks < 4; ++ks) {
        short8v a = *(const short8v*)&rkb[(tr * 16 + c) * 136 + ks * 32 + g * 8];
        short8v b = *(const short8v*)&rkb[(tc * 16 + c) * 136 + ks * 32 + g * 8];
        acc = __builtin_amdgcn_mfma_f32_16x16x32_bf16(a, b, acc, 0, 0, 0);
      }
      #pragma unroll
      for (int r = 0; r < 4; ++r) {
        int a_ = tr * 16 + g * 4 + r;
        int j = tc * 16 + c;
        float val = acc[r];
        if (a_ <= 63) Af[a_ * 68 + j] = (a_ > j) ? (-betaS[a_] * val * gpow[a_ - j]) : 0.f;
        if (a_ >= 1 && a_ <= 64) {
          if (j <= a_ - 1)      attn[abase + (size_t)(a_ - 1) * 64 + j] = f2bf(val * gpow[a_ - 1 - j]);
          else if (a_ <= 63)    attn[abase + (size_t)(a_ - 1) * 64 + j] = 0;
        }
      }
    }
  }
  // zero strictly-upper attn tiles never touched above
  {
    const int ZR[6] = {0,0,0,1,1,2};
    const int ZC[6] = {1,2,3,2,3,3};
    int rr = tid >> 4, cc2 = tid & 15;
    #pragma unroll
    for (int z = 0; z < 6; ++z) {
      int r_att = ZR[z] * 16 - 1 + rr;
      if (r_att >= 0) attn[abase + (size_t)r_att * 64 + ZC[z] * 16 + cc2] = 0;
    }
  }
  // stage wk^T into xT (independent of UT; loads overlap)
  #pragma unroll
  for (int u = 0; u < 4; ++u) {
    int idx = tid + u * 256;
    int j = idx & 63, eb = idx >> 6;
    int t = t0 + j - 1;
    us8 v = {0, 0, 0, 0, 0, 0, 0, 0};
    if (t >= 0) v = *(const us8*)(rk + (bhbase + t) * 128 + eb * 8);
    #pragma unroll
    for (int s = 0; s < 8; ++s) xT[(eb * 8 + s) * 72 + j] = v[s];
  }
  __syncthreads();

  // ---- UT transform (serial, f32) ----
  {
    int k = tid & 63, sp = tid >> 6;
    for (int i = 1; i < 64; ++i) {
      float part = 0.f;
      #pragma unroll
      for (int jj = 0; jj < 16; ++jj) {
        int j = sp * 16 + jj;
        part += Af[i * 68 + j] * Af[j * 68 + k];
      }
      red[sp][k] = part;
      __syncthreads();
      if (tid < 64) Af[i * 68 + tid] += red[0][tid] + red[1][tid] + red[2][tid] + red[3][tid];
      __syncthreads();
    }
  }
  // build Ab1 = (A+I)*diag(bd), Ab2 = (A+I) in bf16
  {
    int i = tid >> 2, j0 = (tid & 3) * 16;
    #pragma unroll
    for (int jj = 0; jj < 16; ++jj) {
      int j = j0 + jj;
      float av = Af[i * 68 + j] + ((i == j) ? 1.f : 0.f);
      Ab1[i * 72 + j] = f2bf(av * bd[j]);
      Ab2[i * 72 + j] = f2bf(av);
    }
  }
  __syncthreads();

  // ---- 4a: wkcum = Ab1 @ wk  (B = xT = wk^T) ----
  {
    f32x4 acc[8] = {};
    #pragma unroll
    for (int ks = 0; ks < 2; ++ks) {
      short8v a = *(const short8v*)&Ab1[(w * 16 + c) * 72 + ks * 32 + g * 8];
      #pragma unroll
      for (int nt = 0; nt < 8; ++nt) {
        short8v b = *(const short8v*)&xT[(nt * 16 + c) * 72 + ks * 32 + g * 8];
        acc[nt] = __builtin_amdgcn_mfma_f32_16x16x32_bf16(a, b, acc[nt], 0, 0, 0);
      }
    }
    #pragma unroll
    for (int nt = 0; nt < 8; ++nt)
      #pragma unroll
      for (int r = 0; r < 4; ++r) {
        int i = w * 16 + g * 4 + r, e = nt * 16 + c;
        wkcum[(bhbase + t0 + i) * 128 + e] = f2bf(acc[nt][r]);
      }
  }
  __syncthreads();
  // stage v^T into xT (overwrite wk^T)
  #pragma unroll
  for (int u = 0; u < 4; ++u) {
    int idx = tid + u * 256;
    int j = idx & 63, eb = idx >> 6;
    us8 v = *(const us8*)(vb + (bhbase + t0 + j) * 128 + eb * 8);
    #pragma unroll
    for (int s = 0; s < 8; ++s) xT[(eb * 8 + s) * 72 + j] = v[s];
  }
  __syncthreads();
  // ---- 4b: vb = Ab2 @ v ----
  {
    f32x4 acc[8] = {};
    #pragma unroll
    for (int ks = 0; ks < 2; ++ks) {
      short8v a = *(const short8v*)&Ab2[(w * 16 + c) * 72 + ks * 32 + g * 8];
      #pragma unroll
      for (int nt = 0; nt < 8; ++nt) {
        short8v b = *(const short8v*)&xT[(nt * 16 + c) * 72 + ks * 32 + g * 8];
        acc[nt] = __builtin_amdgcn_mfma_f32_16x16x32_bf16(a, b, acc[nt], 0, 0, 0);
      }
    }
    #pragma unroll
    for (int nt = 0; nt < 8; ++nt)
      #pragma unroll
      for (int r = 0; r < 4; ++r) {
        int i = w * 16 + g * 4 + r, e = nt * 16 + c;
        vb[(bhbase + t0 + i) * 128 + e] = f2bf(acc[nt][r]);
      }
  }
}

// ---------------- K4a: serial state scan ----------------
__global__ __launch_bounds__(256) void k_scan_state(
    const ushort* __restrict__ rk, ushort* __restrict__ vb,
    const ushort* __restrict__ wkcum, const float* __restrict__ decay,
    ushort* __restrict__ sck)
{
  int bh = blockIdx.x >> 5;
  int qg = blockIdx.x & 31;
  int q0 = qg * 4;
  int h = bh & 7;
  int tid = threadIdx.x;
  int q = tid & 3, g = tid >> 2;   // g: 0..63
  __shared__ float S_T[4][132];
  __shared__ float vnew[64][5];
  __shared__ float gpow[65];
  float lg = logf(1.f / (1.f + expf(-decay[h])));
  if (tid < 65) gpow[tid] = expf(lg * (float)tid);
  for (int idx = tid; idx < 4 * 132; idx += 256) ((float*)S_T)[idx] = 0.f;
  __syncthreads();
  float ct = gpow[64];
  const size_t rowbase = (size_t)bh * T_LEN * 128;
  const size_t ckbh = (size_t)bh * 64;
  for (int n = 0; n < 64; ++n) {
    int t0 = n * 64;
    {
      int e = tid * 2;
      int row = e >> 7, p = e & 127;
      us2 o; o[0] = f2bf(S_T[row][p]); o[1] = f2bf(S_T[row][p + 1]);
      *(us2*)(sck + ((ckbh + n) * 128 + (q0 + row)) * 128 + p) = o;
    }
    {
      const ushort* wr = wkcum + rowbase + (size_t)(t0 + g) * 128;
      const float* sr = &S_T[q][0];
      float acc = 0.f;
      #pragma unroll 4
      for (int pc = 0; pc < 16; ++pc) {
        us8 w8 = *(const us8*)(wr + pc * 8);
        #pragma unroll
        for (int s = 0; s < 8; ++s) acc += bf2f(w8[s]) * sr[pc * 8 + s];
      }
      size_t vidx = rowbase + (size_t)(t0 + g) * 128 + q0 + q;
      float v = bf2f(vb[vidx]) - acc;
      vnew[g][q] = v;
      vb[vidx] = f2bf(v);
    }
    __syncthreads();
    {
      int p = g * 2;
      float s0 = S_T[q][p] * ct, s1 = S_T[q][p + 1] * ct;
      for (int i = 0; i < 64; ++i) {
        int t = t0 + i - 1;
        if (t >= 0) {
          float coef = gpow[63 - i] * vnew[i][q];
          us2 u = *(const us2*)(rk + rowbase + (size_t)t * 128 + p);
          s0 += bf2f(u[0]) * coef;
          s1 += bf2f(u[1]) * coef;
        }
      }
      S_T[q][p] = s0; S_T[q][p + 1] = s1;
    }
    __syncthreads();
  }
}

// ---------------- K4b: parallel MFMA output ----------------
__global__ __launch_bounds__(256) void k_scan_out(
    const ushort* __restrict__ rk, const ushort* __restrict__ vb,
    const ushort* __restrict__ attn, const ushort* __restrict__ sck,
    const float* __restrict__ decay, ushort* __restrict__ og)
{
  int bh = blockIdx.x >> 6;
  int n = blockIdx.x & 63;
  int b = bh >> 3, h = bh & 7;
  int t0 = n * 64;
  int tid = threadIdx.x;
  int lane = tid & 63, w = tid >> 6;
  int c = lane & 15, g = lane >> 4;
  __shared__ ushort vnT[128][72];
  __shared__ float gpow[65];
  float lg = logf(1.f / (1.f + expf(-decay[h])));
  if (tid < 65) gpow[tid] = expf(lg * (float)tid);
  const size_t rowbase = (size_t)bh * T_LEN * 128;
  #pragma unroll
  for (int u = 0; u < 4; ++u) {
    int idx = tid * 4 + u;
    int i = idx >> 4, d0 = (idx & 15) * 8;
    us8 vv = *(const us8*)(vb + rowbase + (size_t)(t0 + i) * 128 + d0);
    #pragma unroll
    for (int j = 0; j < 8; ++j) vnT[d0 + j][i] = vv[j];
  }
  __syncthreads();

  f32x4 acc[8] = {};
  const size_t sbase = ((size_t)bh * 64 + n) * 128 * 128;
  #pragma unroll
  for (int ks = 0; ks < 4; ++ks) {
    short8v a = *(const short8v*)(rk + rowbase + (size_t)(t0 + 16 * w + c) * 128 + ks * 32 + g * 8);
    #pragma unroll
    for (int ctile = 0; ctile < 8; ++ctile) {
      short8v bfr = *(const short8v*)(sck + sbase + (size_t)(ctile * 16 + c) * 128 + ks * 32 + g * 8);
      acc[ctile] = __builtin_amdgcn_mfma_f32_16x16x32_bf16(a, bfr, acc[ctile], 0, 0, 0);
    }
  }
  #pragma unroll
  for (int ctile = 0; ctile < 8; ++ctile) {
    #pragma unroll
    for (int r = 0; r < 4; ++r) acc[ctile][r] *= gpow[16 * w + 4 * g + r + 1];
  }
  const size_t abase = ((size_t)bh * 64 + n) * 64 * 64;
  #pragma unroll
  for (int ks = 0; ks < 2; ++ks) {
    short8v a = *(const short8v*)(attn + abase + (size_t)(16 * w + c) * 64 + ks * 32 + g * 8);
    #pragma unroll
    for (int ctile = 0; ctile < 8; ++ctile) {
      short8v bfr = *(const short8v*)&vnT[ctile * 16 + c][ks * 32 + g * 8];
      acc[ctile] = __builtin_amdgcn_mfma_f32_16x16x32_bf16(a, bfr, acc[ctile], 0, 0, 0);
    }
  }
  #pragma unroll
  for (int ctile = 0; ctile < 8; ++ctile) {
    #pragma unroll
    for (int r = 0; r < 4; ++r) {
      int i = 16 * w + 4 * g + r;
      og[((size_t)b * T_LEN + t0 + i) * 1024 + h * 128 + ctile * 16 + c] = f2bf(acc[ctile][r]);
    }
  }
}

extern "C" void kernel_launch(void* const* d_in, const int* in_sizes, int n_in,
                              void* d_out, int out_size, void* d_ws, size_t ws_size,
                              hipStream_t stream) {
  const float* x   = (const float*)d_in[0];
  const float* Ww  = (const float*)d_in[1];
  const float* Wr  = (const float*)d_in[2];
  const float* Wb  = (const float*)d_in[3];
  const float* dec = (const float*)d_in[4];
  float* out = (float*)d_out;
  ushort* ws = (ushort*)d_ws;
  const size_t SZ = 16777216ull;
  ushort* rk    = ws;
  ushort* vb    = ws + SZ;
  ushort* wkcum = ws + 2 * SZ;
  ushort* og    = ws + 3 * SZ;
  ushort* attn  = ws + 4 * SZ;
  float*  beta  = (float*)(ws + 4 * SZ + 8388608ull);
  ushort* sck   = ws + 4 * SZ + 8388608ull + 262144ull;
  const size_t NEED = 218628096ull;
  if (ws_size < NEED) {
    hipMemcpyAsync(d_out, (const void*)x, (size_t)out_size * 4, hipMemcpyDeviceToDevice, stream);
    return;
  }

  k_prep<<<dim3(16384), dim3(128), 0, stream>>>(x, Wb, rk, beta);
  k_gemm<0><<<dim3(8, 128), dim3(256), 0, stream>>>((const void*)x, Ww, beta, nullptr, (void*)vb);
  k_chunk<<<dim3(2048), dim3(256), 0, stream>>>(rk, vb, wkcum, attn, beta, dec);
  k_scan_state<<<dim3(1024), dim3(256), 0, stream>>>(rk, vb, wkcum, dec, sck);
  k_scan_out<<<dim3(2048), dim3(256), 0, stream>>>(rk, vb, attn, sck, dec, og);
  k_gemm<1><<<dim3(8, 128), dim3(256), 0, stream>>>((const void*)og, Wr, nullptr, (const float*)x, (void*)out);
}

// Round 6
// 542.637 us; speedup vs baseline: 4.9465x; 2.1510x over previous
//
#include <hip/hip_runtime.h>
#include <hip/hip_bf16.h>
#include <math.h>

// HebbianBlock: B=4, T=4096, D=1024, H=8, d=128, C=64, N=64
// Round 6: fused MFMA scan. One block per (bh, 32-col group) keeps S in f32
// MFMA accumulators across all 64 chunks (bf16 S^T mirror in LDS as the
// B-operand). Deletes sck checkpoints and k_scan_out entirely.
// k_prep / k_gemm / k_chunk verbatim from passing Round 5.

#define T_LEN 4096
typedef unsigned short ushort;
typedef __attribute__((ext_vector_type(2))) unsigned short us2;
typedef __attribute__((ext_vector_type(4))) unsigned short us4;
typedef __attribute__((ext_vector_type(8))) unsigned short us8;
typedef __attribute__((ext_vector_type(8))) short short8v;
typedef __attribute__((ext_vector_type(4))) float f32x4;

__device__ __forceinline__ float bf2f(ushort u) {
  union { unsigned int u; float f; } c; c.u = ((unsigned int)u) << 16; return c.f;
}
__device__ __forceinline__ ushort f2bf(float x) {
  union { float f; unsigned int u; } c; c.f = x;
  unsigned int u = c.u + 0x7FFFu + ((c.u >> 16) & 1u);
  return (ushort)(u >> 16);
}
__device__ __forceinline__ ushort f2bf_fast(float x) {
  __hip_bfloat16 h = __float2bfloat16(x);
  return *reinterpret_cast<ushort*>(&h);
}

// ---------------- K1: rk + beta ----------------
__global__ __launch_bounds__(128) void k_prep(
    const float* __restrict__ x, const float* __restrict__ Wb,
    ushort* __restrict__ rk, float* __restrict__ beta)
{
  int bt = blockIdx.x;
  int b = bt >> 12, t = bt & 4095;
  int tid = threadIdx.x;
  __shared__ float xs[1024];
  __shared__ float red[16];
  {
    const float4* x4 = (const float4*)(x + (size_t)bt * 1024);
    float4* xs4 = (float4*)xs;
    xs4[tid] = x4[tid];
    xs4[tid + 128] = x4[tid + 128];
  }
  __syncthreads();
  int h = tid >> 4;
  int e0 = h * 128 + (tid & 15) * 8;
  float ss = 0.f;
  #pragma unroll
  for (int s = 0; s < 8; ++s) { float v = xs[e0 + s]; ss += v * v; }
  #pragma unroll
  for (int m = 1; m < 16; m <<= 1) ss += __shfl_xor(ss, m, 64);
  float inv = 1.f / fmaxf(sqrtf(ss), 1e-12f);
  {
    int bh = b * 8 + h;
    us8 o;
    #pragma unroll
    for (int s = 0; s < 8; ++s) o[s] = f2bf(xs[e0 + s] * inv);
    *(us8*)(rk + ((size_t)bh * T_LEN + t) * 128 + (tid & 15) * 8) = o;
  }
  const float* xk = xs + tid * 8;
  #pragma unroll
  for (int h2 = 0; h2 < 8; ++h2) {
    const float* wb = Wb + (size_t)h2 * 1024 + tid * 8;
    float p = 0.f;
    #pragma unroll
    for (int s = 0; s < 8; ++s) p += xk[s] * wb[s];
    #pragma unroll
    for (int m = 1; m < 64; m <<= 1) p += __shfl_xor(p, m, 64);
    if ((tid & 63) == 0) red[(tid >> 6) * 8 + h2] = p;
  }
  __syncthreads();
  if (tid < 8) {
    float s = red[tid] + red[8 + tid];
    beta[((size_t)(b * 8 + tid)) * T_LEN + t] = 1.f / (1.f + expf(-s));
  }
}

// ---------------- K2/K5: bf16 MFMA GEMM, 128x128 tile, BK=32 ----------------
#define LDK 40
template<int MODE>
__global__ __launch_bounds__(256) void k_gemm(
    const void* __restrict__ Am_, const float* __restrict__ W,
    const float* __restrict__ beta, const float* __restrict__ xadd,
    void* __restrict__ out_)
{
  __shared__ ushort As[128 * LDK];
  __shared__ ushort Bs[128 * LDK];
  const int n0 = blockIdx.x * 128;
  const int m0 = blockIdx.y * 128;
  const int tid = threadIdx.x;
  const int lane = tid & 63;
  const int wid = tid >> 6;
  const int wr = wid >> 1, wc = wid & 1;
  const int c = lane & 15, g = lane >> 4;
  const int srow = tid >> 2;
  const int seg = tid & 3;

  f32x4 acc[4][4] = {};

  for (int k0 = 0; k0 < 1024; k0 += 32) {
    if (MODE == 0) {
      const float* a0 = (const float*)Am_ + (size_t)(m0 + srow) * 1024 + k0 + seg * 8;
      const float* a1 = (const float*)Am_ + (size_t)(m0 + srow + 64) * 1024 + k0 + seg * 8;
      float4 p0 = *(const float4*)a0, p1 = *(const float4*)(a0 + 4);
      float4 q0 = *(const float4*)a1, q1 = *(const float4*)(a1 + 4);
      us8 o0, o1;
      o0[0]=f2bf_fast(p0.x); o0[1]=f2bf_fast(p0.y); o0[2]=f2bf_fast(p0.z); o0[3]=f2bf_fast(p0.w);
      o0[4]=f2bf_fast(p1.x); o0[5]=f2bf_fast(p1.y); o0[6]=f2bf_fast(p1.z); o0[7]=f2bf_fast(p1.w);
      o1[0]=f2bf_fast(q0.x); o1[1]=f2bf_fast(q0.y); o1[2]=f2bf_fast(q0.z); o1[3]=f2bf_fast(q0.w);
      o1[4]=f2bf_fast(q1.x); o1[5]=f2bf_fast(q1.y); o1[6]=f2bf_fast(q1.z); o1[7]=f2bf_fast(q1.w);
      *(us8*)&As[srow * LDK + seg * 8] = o0;
      *(us8*)&As[(srow + 64) * LDK + seg * 8] = o1;
    } else {
      us8 o0 = *(const us8*)((const ushort*)Am_ + (size_t)(m0 + srow) * 1024 + k0 + seg * 8);
      us8 o1 = *(const us8*)((const ushort*)Am_ + (size_t)(m0 + srow + 64) * 1024 + k0 + seg * 8);
      *(us8*)&As[srow * LDK + seg * 8] = o0;
      *(us8*)&As[(srow + 64) * LDK + seg * 8] = o1;
    }
    {
      const float* b0 = W + (size_t)(n0 + srow) * 1024 + k0 + seg * 8;
      const float* b1 = W + (size_t)(n0 + srow + 64) * 1024 + k0 + seg * 8;
      float4 p0 = *(const float4*)b0, p1 = *(const float4*)(b0 + 4);
      float4 q0 = *(const float4*)b1, q1 = *(const float4*)(b1 + 4);
      us8 o0, o1;
      o0[0]=f2bf_fast(p0.x); o0[1]=f2bf_fast(p0.y); o0[2]=f2bf_fast(p0.z); o0[3]=f2bf_fast(p0.w);
      o0[4]=f2bf_fast(p1.x); o0[5]=f2bf_fast(p1.y); o0[6]=f2bf_fast(p1.z); o0[7]=f2bf_fast(p1.w);
      o1[0]=f2bf_fast(q0.x); o1[1]=f2bf_fast(q0.y); o1[2]=f2bf_fast(q0.z); o1[3]=f2bf_fast(q0.w);
      o1[4]=f2bf_fast(q1.x); o1[5]=f2bf_fast(q1.y); o1[6]=f2bf_fast(q1.z); o1[7]=f2bf_fast(q1.w);
      *(us8*)&Bs[srow * LDK + seg * 8] = o0;
      *(us8*)&Bs[(srow + 64) * LDK + seg * 8] = o1;
    }
    __syncthreads();
    short8v af[4], bf[4];
    #pragma unroll
    for (int mi = 0; mi < 4; ++mi)
      af[mi] = *(const short8v*)&As[(wr * 64 + mi * 16 + c) * LDK + g * 8];
    #pragma unroll
    for (int ni = 0; ni < 4; ++ni)
      bf[ni] = *(const short8v*)&Bs[(wc * 64 + ni * 16 + c) * LDK + g * 8];
    #pragma unroll
    for (int mi = 0; mi < 4; ++mi)
      #pragma unroll
      for (int ni = 0; ni < 4; ++ni)
        acc[mi][ni] = __builtin_amdgcn_mfma_f32_16x16x32_bf16(af[mi], bf[ni], acc[mi][ni], 0, 0, 0);
    __syncthreads();
  }

  if (MODE == 0) {
    ushort* vb = (ushort*)out_;
    const int hh = n0 >> 7;
    #pragma unroll
    for (int mi = 0; mi < 4; ++mi) {
      #pragma unroll
      for (int ni = 0; ni < 4; ++ni) {
        int jc = wc * 64 + ni * 16 + c;
        #pragma unroll
        for (int j = 0; j < 4; ++j) {
          int m = m0 + wr * 64 + mi * 16 + g * 4 + j;
          int b = m >> 12, t = m & 4095;
          size_t base = (size_t)(b * 8 + hh) * T_LEN + t;
          float bv = beta[base];
          vb[base * 128 + jc] = f2bf(acc[mi][ni][j] * bv);
        }
      }
    }
  } else {
    float* out = (float*)out_;
    #pragma unroll
    for (int mi = 0; mi < 4; ++mi) {
      #pragma unroll
      for (int ni = 0; ni < 4; ++ni) {
        int n = n0 + wc * 64 + ni * 16 + c;
        #pragma unroll
        for (int j = 0; j < 4; ++j) {
          int m = m0 + wr * 64 + mi * 16 + g * 4 + j;
          size_t idx = (size_t)m * 1024 + n;
          out[idx] = xadd[idx] + acc[mi][ni][j];
        }
      }
    }
  }
}

// ---------------- K3: per-chunk UT transform (MFMA version) ----------------
__global__ __launch_bounds__(256) void k_chunk(
    const ushort* __restrict__ rk, ushort* __restrict__ vb,
    ushort* __restrict__ wkcum, ushort* __restrict__ attn,
    const float* __restrict__ beta, const float* __restrict__ decay)
{
  int bh = blockIdx.x >> 6;
  int n = blockIdx.x & 63;
  int h = bh & 7;
  int tid = threadIdx.x;
  int lane = tid & 63, w = tid >> 6;
  int c = lane & 15, g = lane >> 4;

  __shared__ ushort rkb[80 * 136];
  __shared__ float  Af[64 * 68];
  __shared__ ushort Ab1[64 * 72];
  __shared__ ushort Ab2[64 * 72];
  __shared__ ushort xT[128 * 72];
  __shared__ float  red[4][64];
  __shared__ float  betaS[64], bd[64], gpow[65];

  float lg = logf(1.f / (1.f + expf(-decay[h])));
  if (tid < 65) gpow[tid] = expf(lg * (float)tid);
  if (tid < 64) betaS[tid] = beta[(size_t)bh * T_LEN + n * 64 + tid];
  const int t0 = n * 64;
  const size_t bhbase = (size_t)bh * T_LEN;

  #pragma unroll
  for (int u = 0; u < 5; ++u) {
    int idx = tid + u * 256;
    int row = idx >> 4, cb = idx & 15;
    us8 v = {0, 0, 0, 0, 0, 0, 0, 0};
    int t = t0 + row - 1;
    if (row <= 64 && t >= 0) v = *(const us8*)(rk + (bhbase + t) * 128 + cb * 8);
    *(us8*)&rkb[row * 136 + cb * 8] = v;
  }
  for (int idx = tid; idx < 64 * 68; idx += 256) Af[idx] = 0.f;
  __syncthreads();
  if (tid < 64) bd[tid] = betaS[tid] * gpow[tid + 1];

  const size_t abase = ((size_t)bh * 64 + n) * 4096;
  {
    const int TR[14] = {0,1,1,2,2,2,3,3,3,3,4,4,4,4};
    const int TC[14] = {0,0,1,0,1,2,0,1,2,3,0,1,2,3};
    #pragma unroll
    for (int ti = 0; ti < 14; ++ti) {
      if ((ti & 3) != w) continue;
      const int tr = TR[ti], tc = TC[ti];
      f32x4 acc = {0.f, 0.f, 0.f, 0.f};
      #pragma unroll
      for (int ks = 0; ks < 4; ++ks) {
        short8v a = *(const short8v*)&rkb[(tr * 16 + c) * 136 + ks * 32 + g * 8];
        short8v b = *(const short8v*)&rkb[(tc * 16 + c) * 136 + ks * 32 + g * 8];
        acc = __builtin_amdgcn_mfma_f32_16x16x32_bf16(a, b, acc, 0, 0, 0);
      }
      #pragma unroll
      for (int r = 0; r < 4; ++r) {
        int a_ = tr * 16 + g * 4 + r;
        int j = tc * 16 + c;
        float val = acc[r];
        if (a_ <= 63) Af[a_ * 68 + j] = (a_ > j) ? (-betaS[a_] * val * gpow[a_ - j]) : 0.f;
        if (a_ >= 1 && a_ <= 64) {
          if (j <= a_ - 1)      attn[abase + (size_t)(a_ - 1) * 64 + j] = f2bf(val * gpow[a_ - 1 - j]);
          else if (a_ <= 63)    attn[abase + (size_t)(a_ - 1) * 64 + j] = 0;
        }
      }
    }
  }
  {
    const int ZR[6] = {0,0,0,1,1,2};
    const int ZC[6] = {1,2,3,2,3,3};
    int rr = tid >> 4, cc2 = tid & 15;
    #pragma unroll
    for (int z = 0; z < 6; ++z) {
      int r_att = ZR[z] * 16 - 1 + rr;
      if (r_att >= 0) attn[abase + (size_t)r_att * 64 + ZC[z] * 16 + cc2] = 0;
    }
  }
  #pragma unroll
  for (int u = 0; u < 4; ++u) {
    int idx = tid + u * 256;
    int j = idx & 63, eb = idx >> 6;
    int t = t0 + j - 1;
    us8 v = {0, 0, 0, 0, 0, 0, 0, 0};
    if (t >= 0) v = *(const us8*)(rk + (bhbase + t) * 128 + eb * 8);
    #pragma unroll
    for (int s = 0; s < 8; ++s) xT[(eb * 8 + s) * 72 + j] = v[s];
  }
  __syncthreads();

  {
    int k = tid & 63, sp = tid >> 6;
    for (int i = 1; i < 64; ++i) {
      float part = 0.f;
      #pragma unroll
      for (int jj = 0; jj < 16; ++jj) {
        int j = sp * 16 + jj;
        part += Af[i * 68 + j] * Af[j * 68 + k];
      }
      red[sp][k] = part;
      __syncthreads();
      if (tid < 64) Af[i * 68 + tid] += red[0][tid] + red[1][tid] + red[2][tid] + red[3][tid];
      __syncthreads();
    }
  }
  {
    int i = tid >> 2, j0 = (tid & 3) * 16;
    #pragma unroll
    for (int jj = 0; jj < 16; ++jj) {
      int j = j0 + jj;
      float av = Af[i * 68 + j] + ((i == j) ? 1.f : 0.f);
      Ab1[i * 72 + j] = f2bf(av * bd[j]);
      Ab2[i * 72 + j] = f2bf(av);
    }
  }
  __syncthreads();

  {
    f32x4 acc[8] = {};
    #pragma unroll
    for (int ks = 0; ks < 2; ++ks) {
      short8v a = *(const short8v*)&Ab1[(w * 16 + c) * 72 + ks * 32 + g * 8];
      #pragma unroll
      for (int nt = 0; nt < 8; ++nt) {
        short8v b = *(const short8v*)&xT[(nt * 16 + c) * 72 + ks * 32 + g * 8];
        acc[nt] = __builtin_amdgcn_mfma_f32_16x16x32_bf16(a, b, acc[nt], 0, 0, 0);
      }
    }
    #pragma unroll
    for (int nt = 0; nt < 8; ++nt)
      #pragma unroll
      for (int r = 0; r < 4; ++r) {
        int i = w * 16 + g * 4 + r, e = nt * 16 + c;
        wkcum[(bhbase + t0 + i) * 128 + e] = f2bf(acc[nt][r]);
      }
  }
  __syncthreads();
  #pragma unroll
  for (int u = 0; u < 4; ++u) {
    int idx = tid + u * 256;
    int j = idx & 63, eb = idx >> 6;
    us8 v = *(const us8*)(vb + (bhbase + t0 + j) * 128 + eb * 8);
    #pragma unroll
    for (int s = 0; s < 8; ++s) xT[(eb * 8 + s) * 72 + j] = v[s];
  }
  __syncthreads();
  {
    f32x4 acc[8] = {};
    #pragma unroll
    for (int ks = 0; ks < 2; ++ks) {
      short8v a = *(const short8v*)&Ab2[(w * 16 + c) * 72 + ks * 32 + g * 8];
      #pragma unroll
      for (int nt = 0; nt < 8; ++nt) {
        short8v b = *(const short8v*)&xT[(nt * 16 + c) * 72 + ks * 32 + g * 8];
        acc[nt] = __builtin_amdgcn_mfma_f32_16x16x32_bf16(a, b, acc[nt], 0, 0, 0);
      }
    }
    #pragma unroll
    for (int nt = 0; nt < 8; ++nt)
      #pragma unroll
      for (int r = 0; r < 4; ++r) {
        int i = w * 16 + g * 4 + r, e = nt * 16 + c;
        vb[(bhbase + t0 + i) * 128 + e] = f2bf(acc[nt][r]);
      }
  }
}

// ---------------- K4: fused MFMA scan ----------------
// grid 128 = 32 bh x 4 colgroups(32). 4 waves. S kept in f32 accs (accS**),
// bf16 S^T mirror in LDS (ST). Per chunk: A) vnew=v-wkcum@S -> vnT;
// B) o = gamma*rk@S + attn@vnT -> og; C) accS = ct*accS + wkT@vnT -> ST.
__global__ __launch_bounds__(256) void k_scan_fused(
    const ushort* __restrict__ rk, const ushort* __restrict__ vb,
    const ushort* __restrict__ wkcum, const ushort* __restrict__ attn,
    const float* __restrict__ decay, ushort* __restrict__ og)
{
  const int bh = blockIdx.x >> 2;
  const int q0 = (blockIdx.x & 3) * 32;
  const int b_ = bh >> 3, h = bh & 7;
  const int tid = threadIdx.x;
  const int lane = tid & 63, w = tid >> 6;
  const int c = lane & 15, g = lane >> 4;

  __shared__ ushort ST[32 * 136];   // S^T: [q][p], bf16 mirror of accS
  __shared__ ushort vnT[32 * 72];   // vnew^T: [q][i]
  __shared__ ushort wkT[128 * 72];  // (wk*dw)^T: [p][i]
  __shared__ float gpow[65];

  float lg = logf(1.f / (1.f + expf(-decay[h])));
  if (tid < 65) gpow[tid] = expf(lg * (float)tid);
  for (int idx = tid; idx < 32 * 136; idx += 256) ST[idx] = 0;
  __syncthreads();
  const float ct = gpow[64];
  const size_t bhbase = (size_t)bh * T_LEN;

  f32x4 accS00 = {}, accS01 = {}, accS10 = {}, accS11 = {};

  for (int n = 0; n < 64; ++n) {
    const int t0 = n * 64;
    const size_t abase = ((size_t)bh * 64 + n) * 4096;

    // ---- issue all global loads for this chunk ----
    short8v aW[4], aR[4], aT[2];
    #pragma unroll
    for (int ks = 0; ks < 4; ++ks) {
      aW[ks] = *(const short8v*)(wkcum + (bhbase + t0 + 16 * w + c) * 128 + ks * 32 + g * 8);
      aR[ks] = *(const short8v*)(rk + (bhbase + t0 + 16 * w + c) * 128 + ks * 32 + g * 8);
    }
    #pragma unroll
    for (int ks = 0; ks < 2; ++ks)
      aT[ks] = *(const short8v*)(attn + abase + (size_t)(16 * w + c) * 64 + ks * 32 + g * 8);
    float vval0[4], vval1[4];
    #pragma unroll
    for (int r = 0; r < 4; ++r) {
      vval0[r] = bf2f(vb[(bhbase + t0 + 16 * w + 4 * g + r) * 128 + q0 + c]);
      vval1[r] = bf2f(vb[(bhbase + t0 + 16 * w + 4 * g + r) * 128 + q0 + 16 + c]);
    }
    // ---- stage wkT = (wk * dw)^T ----
    #pragma unroll
    for (int u = 0; u < 4; ++u) {
      int idx = tid + u * 256;
      int iL = idx & 63, eb = idx >> 6;
      int t = t0 + iL - 1;
      float dw = gpow[63 - iL];
      us8 vv = {0, 0, 0, 0, 0, 0, 0, 0};
      if (t >= 0) vv = *(const us8*)(rk + (bhbase + t) * 128 + eb * 8);
      #pragma unroll
      for (int s = 0; s < 8; ++s)
        wkT[(eb * 8 + s) * 72 + iL] = f2bf(bf2f(vv[s]) * dw);
    }

    // ---- phase A: accA = wkcum @ S; vnew = v - accA -> vnT ----
    f32x4 accA0 = {}, accA1 = {};
    #pragma unroll
    for (int ks = 0; ks < 4; ++ks) {
      short8v b0 = *(const short8v*)&ST[(c) * 136 + ks * 32 + g * 8];
      short8v b1 = *(const short8v*)&ST[(16 + c) * 136 + ks * 32 + g * 8];
      accA0 = __builtin_amdgcn_mfma_f32_16x16x32_bf16(aW[ks], b0, accA0, 0, 0, 0);
      accA1 = __builtin_amdgcn_mfma_f32_16x16x32_bf16(aW[ks], b1, accA1, 0, 0, 0);
    }
    #pragma unroll
    for (int r = 0; r < 4; ++r) {
      int i = 16 * w + 4 * g + r;
      vnT[(c) * 72 + i] = f2bf(vval0[r] - accA0[r]);
      vnT[(16 + c) * 72 + i] = f2bf(vval1[r] - accA1[r]);
    }
    __syncthreads();  // bar1: vnT + wkT ready

    // ---- phase B: o = gamma^(i+1)*rk@S + attn@vnew ----
    f32x4 accB0 = {}, accB1 = {};
    #pragma unroll
    for (int ks = 0; ks < 4; ++ks) {
      short8v b0 = *(const short8v*)&ST[(c) * 136 + ks * 32 + g * 8];
      short8v b1 = *(const short8v*)&ST[(16 + c) * 136 + ks * 32 + g * 8];
      accB0 = __builtin_amdgcn_mfma_f32_16x16x32_bf16(aR[ks], b0, accB0, 0, 0, 0);
      accB1 = __builtin_amdgcn_mfma_f32_16x16x32_bf16(aR[ks], b1, accB1, 0, 0, 0);
    }
    #pragma unroll
    for (int r = 0; r < 4; ++r) {
      float gsc = gpow[16 * w + 4 * g + r + 1];
      accB0[r] *= gsc; accB1[r] *= gsc;
    }
    #pragma unroll
    for (int ks = 0; ks < 2; ++ks) {
      short8v b0 = *(const short8v*)&vnT[(c) * 72 + ks * 32 + g * 8];
      short8v b1 = *(const short8v*)&vnT[(16 + c) * 72 + ks * 32 + g * 8];
      accB0 = __builtin_amdgcn_mfma_f32_16x16x32_bf16(aT[ks], b0, accB0, 0, 0, 0);
      accB1 = __builtin_amdgcn_mfma_f32_16x16x32_bf16(aT[ks], b1, accB1, 0, 0, 0);
    }
    #pragma unroll
    for (int r = 0; r < 4; ++r) {
      int i = 16 * w + 4 * g + r;
      size_t obase = ((size_t)b_ * T_LEN + t0 + i) * 1024 + h * 128 + q0;
      og[obase + c] = f2bf(accB0[r]);
      og[obase + 16 + c] = f2bf(accB1[r]);
    }
    __syncthreads();  // bar2: ST reads done before phase C rewrites it

    // ---- phase C: accS = ct*accS + wkT @ vnT; write ST ----
    #pragma unroll
    for (int r = 0; r < 4; ++r) {
      accS00[r] *= ct; accS01[r] *= ct; accS10[r] *= ct; accS11[r] *= ct;
    }
    #pragma unroll
    for (int ks = 0; ks < 2; ++ks) {
      short8v a0 = *(const short8v*)&wkT[(32 * w + c) * 72 + ks * 32 + g * 8];
      short8v a1 = *(const short8v*)&wkT[(32 * w + 16 + c) * 72 + ks * 32 + g * 8];
      short8v b0 = *(const short8v*)&vnT[(c) * 72 + ks * 32 + g * 8];
      short8v b1 = *(const short8v*)&vnT[(16 + c) * 72 + ks * 32 + g * 8];
      accS00 = __builtin_amdgcn_mfma_f32_16x16x32_bf16(a0, b0, accS00, 0, 0, 0);
      accS01 = __builtin_amdgcn_mfma_f32_16x16x32_bf16(a0, b1, accS01, 0, 0, 0);
      accS10 = __builtin_amdgcn_mfma_f32_16x16x32_bf16(a1, b0, accS10, 0, 0, 0);
      accS11 = __builtin_amdgcn_mfma_f32_16x16x32_bf16(a1, b1, accS11, 0, 0, 0);
    }
    #pragma unroll
    for (int r = 0; r < 4; ++r) {
      int p0r = 32 * w + 4 * g + r;
      ST[(c) * 136 + p0r] = f2bf(accS00[r]);
      ST[(c) * 136 + p0r + 16] = f2bf(accS10[r]);
      ST[(16 + c) * 136 + p0r] = f2bf(accS01[r]);
      ST[(16 + c) * 136 + p0r + 16] = f2bf(accS11[r]);
    }
    __syncthreads();  // bar3: ST ready for next chunk
  }
}

extern "C" void kernel_launch(void* const* d_in, const int* in_sizes, int n_in,
                              void* d_out, int out_size, void* d_ws, size_t ws_size,
                              hipStream_t stream) {
  const float* x   = (const float*)d_in[0];
  const float* Ww  = (const float*)d_in[1];
  const float* Wr  = (const float*)d_in[2];
  const float* Wb  = (const float*)d_in[3];
  const float* dec = (const float*)d_in[4];
  float* out = (float*)d_out;
  ushort* ws = (ushort*)d_ws;
  const size_t SZ = 16777216ull;
  ushort* rk    = ws;
  ushort* vb    = ws + SZ;
  ushort* wkcum = ws + 2 * SZ;
  ushort* og    = ws + 3 * SZ;
  ushort* attn  = ws + 4 * SZ;
  float*  beta  = (float*)(ws + 4 * SZ + 8388608ull);
  const size_t NEED = (4 * SZ + 8388608ull) * 2ull + 131072ull * 4ull;  // 151.5 MB
  if (ws_size < NEED) {
    hipMemcpyAsync(d_out, (const void*)x, (size_t)out_size * 4, hipMemcpyDeviceToDevice, stream);
    return;
  }

  k_prep<<<dim3(16384), dim3(128), 0, stream>>>(x, Wb, rk, beta);
  k_gemm<0><<<dim3(8, 128), dim3(256), 0, stream>>>((const void*)x, Ww, beta, nullptr, (void*)vb);
  k_chunk<<<dim3(2048), dim3(256), 0, stream>>>(rk, vb, wkcum, attn, beta, dec);
  k_scan_fused<<<dim3(128), dim3(256), 0, stream>>>(rk, vb, wkcum, attn, dec, og);
  k_gemm<1><<<dim3(8, 128), dim3(256), 0, stream>>>((const void*)og, Wr, nullptr, (const float*)x, (void*)out);
}

// Round 7
// 494.408 us; speedup vs baseline: 5.4290x; 1.0975x over previous
//
#include <hip/hip_runtime.h>
#include <hip/hip_bf16.h>
#include <math.h>

// HebbianBlock: B=4, T=4096, D=1024, H=8, d=128, C=64, N=64
// Round 7: scan latency attack. k_chunk pre-writes dw-scaled wk^T (wkdwT) so
// the scan's phase-C A-operand is a direct global load (no per-chunk LDS
// transpose); scan restructured to 2 raw barriers (lgkmcnt-only) per chunk
// with cross-chunk double-buffered prefetch of aW/aR fragments.
// k_prep / k_gemm verbatim from passing Round 6.

#define T_LEN 4096
typedef unsigned short ushort;
typedef __attribute__((ext_vector_type(2))) unsigned short us2;
typedef __attribute__((ext_vector_type(4))) unsigned short us4;
typedef __attribute__((ext_vector_type(8))) unsigned short us8;
typedef __attribute__((ext_vector_type(8))) short short8v;
typedef __attribute__((ext_vector_type(4))) float f32x4;

__device__ __forceinline__ float bf2f(ushort u) {
  union { unsigned int u; float f; } c; c.u = ((unsigned int)u) << 16; return c.f;
}
__device__ __forceinline__ ushort f2bf(float x) {
  union { float f; unsigned int u; } c; c.f = x;
  unsigned int u = c.u + 0x7FFFu + ((c.u >> 16) & 1u);
  return (ushort)(u >> 16);
}
__device__ __forceinline__ ushort f2bf_fast(float x) {
  __hip_bfloat16 h = __float2bfloat16(x);
  return *reinterpret_cast<ushort*>(&h);
}

// ---------------- K1: rk + beta ----------------
__global__ __launch_bounds__(128) void k_prep(
    const float* __restrict__ x, const float* __restrict__ Wb,
    ushort* __restrict__ rk, float* __restrict__ beta)
{
  int bt = blockIdx.x;
  int b = bt >> 12, t = bt & 4095;
  int tid = threadIdx.x;
  __shared__ float xs[1024];
  __shared__ float red[16];
  {
    const float4* x4 = (const float4*)(x + (size_t)bt * 1024);
    float4* xs4 = (float4*)xs;
    xs4[tid] = x4[tid];
    xs4[tid + 128] = x4[tid + 128];
  }
  __syncthreads();
  int h = tid >> 4;
  int e0 = h * 128 + (tid & 15) * 8;
  float ss = 0.f;
  #pragma unroll
  for (int s = 0; s < 8; ++s) { float v = xs[e0 + s]; ss += v * v; }
  #pragma unroll
  for (int m = 1; m < 16; m <<= 1) ss += __shfl_xor(ss, m, 64);
  float inv = 1.f / fmaxf(sqrtf(ss), 1e-12f);
  {
    int bh = b * 8 + h;
    us8 o;
    #pragma unroll
    for (int s = 0; s < 8; ++s) o[s] = f2bf(xs[e0 + s] * inv);
    *(us8*)(rk + ((size_t)bh * T_LEN + t) * 128 + (tid & 15) * 8) = o;
  }
  const float* xk = xs + tid * 8;
  #pragma unroll
  for (int h2 = 0; h2 < 8; ++h2) {
    const float* wb = Wb + (size_t)h2 * 1024 + tid * 8;
    float p = 0.f;
    #pragma unroll
    for (int s = 0; s < 8; ++s) p += xk[s] * wb[s];
    #pragma unroll
    for (int m = 1; m < 64; m <<= 1) p += __shfl_xor(p, m, 64);
    if ((tid & 63) == 0) red[(tid >> 6) * 8 + h2] = p;
  }
  __syncthreads();
  if (tid < 8) {
    float s = red[tid] + red[8 + tid];
    beta[((size_t)(b * 8 + tid)) * T_LEN + t] = 1.f / (1.f + expf(-s));
  }
}

// ---------------- K2/K5: bf16 MFMA GEMM, 128x128 tile, BK=32 ----------------
#define LDK 40
template<int MODE>
__global__ __launch_bounds__(256) void k_gemm(
    const void* __restrict__ Am_, const float* __restrict__ W,
    const float* __restrict__ beta, const float* __restrict__ xadd,
    void* __restrict__ out_)
{
  __shared__ ushort As[128 * LDK];
  __shared__ ushort Bs[128 * LDK];
  const int n0 = blockIdx.x * 128;
  const int m0 = blockIdx.y * 128;
  const int tid = threadIdx.x;
  const int lane = tid & 63;
  const int wid = tid >> 6;
  const int wr = wid >> 1, wc = wid & 1;
  const int c = lane & 15, g = lane >> 4;
  const int srow = tid >> 2;
  const int seg = tid & 3;

  f32x4 acc[4][4] = {};

  for (int k0 = 0; k0 < 1024; k0 += 32) {
    if (MODE == 0) {
      const float* a0 = (const float*)Am_ + (size_t)(m0 + srow) * 1024 + k0 + seg * 8;
      const float* a1 = (const float*)Am_ + (size_t)(m0 + srow + 64) * 1024 + k0 + seg * 8;
      float4 p0 = *(const float4*)a0, p1 = *(const float4*)(a0 + 4);
      float4 q0 = *(const float4*)a1, q1 = *(const float4*)(a1 + 4);
      us8 o0, o1;
      o0[0]=f2bf_fast(p0.x); o0[1]=f2bf_fast(p0.y); o0[2]=f2bf_fast(p0.z); o0[3]=f2bf_fast(p0.w);
      o0[4]=f2bf_fast(p1.x); o0[5]=f2bf_fast(p1.y); o0[6]=f2bf_fast(p1.z); o0[7]=f2bf_fast(p1.w);
      o1[0]=f2bf_fast(q0.x); o1[1]=f2bf_fast(q0.y); o1[2]=f2bf_fast(q0.z); o1[3]=f2bf_fast(q0.w);
      o1[4]=f2bf_fast(q1.x); o1[5]=f2bf_fast(q1.y); o1[6]=f2bf_fast(q1.z); o1[7]=f2bf_fast(q1.w);
      *(us8*)&As[srow * LDK + seg * 8] = o0;
      *(us8*)&As[(srow + 64) * LDK + seg * 8] = o1;
    } else {
      us8 o0 = *(const us8*)((const ushort*)Am_ + (size_t)(m0 + srow) * 1024 + k0 + seg * 8);
      us8 o1 = *(const us8*)((const ushort*)Am_ + (size_t)(m0 + srow + 64) * 1024 + k0 + seg * 8);
      *(us8*)&As[srow * LDK + seg * 8] = o0;
      *(us8*)&As[(srow + 64) * LDK + seg * 8] = o1;
    }
    {
      const float* b0 = W + (size_t)(n0 + srow) * 1024 + k0 + seg * 8;
      const float* b1 = W + (size_t)(n0 + srow + 64) * 1024 + k0 + seg * 8;
      float4 p0 = *(const float4*)b0, p1 = *(const float4*)(b0 + 4);
      float4 q0 = *(const float4*)b1, q1 = *(const float4*)(b1 + 4);
      us8 o0, o1;
      o0[0]=f2bf_fast(p0.x); o0[1]=f2bf_fast(p0.y); o0[2]=f2bf_fast(p0.z); o0[3]=f2bf_fast(p0.w);
      o0[4]=f2bf_fast(p1.x); o0[5]=f2bf_fast(p1.y); o0[6]=f2bf_fast(p1.z); o0[7]=f2bf_fast(p1.w);
      o1[0]=f2bf_fast(q0.x); o1[1]=f2bf_fast(q0.y); o1[2]=f2bf_fast(q0.z); o1[3]=f2bf_fast(q0.w);
      o1[4]=f2bf_fast(q1.x); o1[5]=f2bf_fast(q1.y); o1[6]=f2bf_fast(q1.z); o1[7]=f2bf_fast(q1.w);
      *(us8*)&Bs[srow * LDK + seg * 8] = o0;
      *(us8*)&Bs[(srow + 64) * LDK + seg * 8] = o1;
    }
    __syncthreads();
    short8v af[4], bf[4];
    #pragma unroll
    for (int mi = 0; mi < 4; ++mi)
      af[mi] = *(const short8v*)&As[(wr * 64 + mi * 16 + c) * LDK + g * 8];
    #pragma unroll
    for (int ni = 0; ni < 4; ++ni)
      bf[ni] = *(const short8v*)&Bs[(wc * 64 + ni * 16 + c) * LDK + g * 8];
    #pragma unroll
    for (int mi = 0; mi < 4; ++mi)
      #pragma unroll
      for (int ni = 0; ni < 4; ++ni)
        acc[mi][ni] = __builtin_amdgcn_mfma_f32_16x16x32_bf16(af[mi], bf[ni], acc[mi][ni], 0, 0, 0);
    __syncthreads();
  }

  if (MODE == 0) {
    ushort* vb = (ushort*)out_;
    const int hh = n0 >> 7;
    #pragma unroll
    for (int mi = 0; mi < 4; ++mi) {
      #pragma unroll
      for (int ni = 0; ni < 4; ++ni) {
        int jc = wc * 64 + ni * 16 + c;
        #pragma unroll
        for (int j = 0; j < 4; ++j) {
          int m = m0 + wr * 64 + mi * 16 + g * 4 + j;
          int b = m >> 12, t = m & 4095;
          size_t base = (size_t)(b * 8 + hh) * T_LEN + t;
          float bv = beta[base];
          vb[base * 128 + jc] = f2bf(acc[mi][ni][j] * bv);
        }
      }
    }
  } else {
    float* out = (float*)out_;
    #pragma unroll
    for (int mi = 0; mi < 4; ++mi) {
      #pragma unroll
      for (int ni = 0; ni < 4; ++ni) {
        int n = n0 + wc * 64 + ni * 16 + c;
        #pragma unroll
        for (int j = 0; j < 4; ++j) {
          int m = m0 + wr * 64 + mi * 16 + g * 4 + j;
          size_t idx = (size_t)m * 1024 + n;
          out[idx] = xadd[idx] + acc[mi][ni][j];
        }
      }
    }
  }
}

// ---------------- K3: per-chunk UT transform (MFMA) + wkdwT export ----------------
__global__ __launch_bounds__(256) void k_chunk(
    const ushort* __restrict__ rk, ushort* __restrict__ vb,
    ushort* __restrict__ wkcum, ushort* __restrict__ attn,
    const float* __restrict__ beta, const float* __restrict__ decay,
    ushort* __restrict__ wkdwT)
{
  int bh = blockIdx.x >> 6;
  int n = blockIdx.x & 63;
  int h = bh & 7;
  int tid = threadIdx.x;
  int lane = tid & 63, w = tid >> 6;
  int c = lane & 15, g = lane >> 4;

  __shared__ ushort rkb[80 * 136];
  __shared__ float  Af[64 * 68];
  __shared__ ushort Ab1[64 * 72];
  __shared__ ushort Ab2[64 * 72];
  __shared__ ushort xT[128 * 72];
  __shared__ float  red[4][64];
  __shared__ float  betaS[64], bd[64], gpow[65];

  float lg = logf(1.f / (1.f + expf(-decay[h])));
  if (tid < 65) gpow[tid] = expf(lg * (float)tid);
  if (tid < 64) betaS[tid] = beta[(size_t)bh * T_LEN + n * 64 + tid];
  const int t0 = n * 64;
  const size_t bhbase = (size_t)bh * T_LEN;

  #pragma unroll
  for (int u = 0; u < 5; ++u) {
    int idx = tid + u * 256;
    int row = idx >> 4, cb = idx & 15;
    us8 v = {0, 0, 0, 0, 0, 0, 0, 0};
    int t = t0 + row - 1;
    if (row <= 64 && t >= 0) v = *(const us8*)(rk + (bhbase + t) * 128 + cb * 8);
    *(us8*)&rkb[row * 136 + cb * 8] = v;
  }
  for (int idx = tid; idx < 64 * 68; idx += 256) Af[idx] = 0.f;
  __syncthreads();
  if (tid < 64) bd[tid] = betaS[tid] * gpow[tid + 1];

  const size_t abase = ((size_t)bh * 64 + n) * 4096;
  {
    const int TR[14] = {0,1,1,2,2,2,3,3,3,3,4,4,4,4};
    const int TC[14] = {0,0,1,0,1,2,0,1,2,3,0,1,2,3};
    #pragma unroll
    for (int ti = 0; ti < 14; ++ti) {
      if ((ti & 3) != w) continue;
      const int tr = TR[ti], tc = TC[ti];
      f32x4 acc = {0.f, 0.f, 0.f, 0.f};
      #pragma unroll
      for (int ks = 0; ks < 4; ++ks) {
        short8v a = *(const short8v*)&rkb[(tr * 16 + c) * 136 + ks * 32 + g * 8];
        short8v b = *(const short8v*)&rkb[(tc * 16 + c) * 136 + ks * 32 + g * 8];
        acc = __builtin_amdgcn_mfma_f32_16x16x32_bf16(a, b, acc, 0, 0, 0);
      }
      #pragma unroll
      for (int r = 0; r < 4; ++r) {
        int a_ = tr * 16 + g * 4 + r;
        int j = tc * 16 + c;
        float val = acc[r];
        if (a_ <= 63) Af[a_ * 68 + j] = (a_ > j) ? (-betaS[a_] * val * gpow[a_ - j]) : 0.f;
        if (a_ >= 1 && a_ <= 64) {
          if (j <= a_ - 1)      attn[abase + (size_t)(a_ - 1) * 64 + j] = f2bf(val * gpow[a_ - 1 - j]);
          else if (a_ <= 63)    attn[abase + (size_t)(a_ - 1) * 64 + j] = 0;
        }
      }
    }
  }
  {
    const int ZR[6] = {0,0,0,1,1,2};
    const int ZC[6] = {1,2,3,2,3,3};
    int rr = tid >> 4, cc2 = tid & 15;
    #pragma unroll
    for (int z = 0; z < 6; ++z) {
      int r_att = ZR[z] * 16 - 1 + rr;
      if (r_att >= 0) attn[abase + (size_t)r_att * 64 + ZC[z] * 16 + cc2] = 0;
    }
  }
  #pragma unroll
  for (int u = 0; u < 4; ++u) {
    int idx = tid + u * 256;
    int j = idx & 63, eb = idx >> 6;
    int t = t0 + j - 1;
    us8 v = {0, 0, 0, 0, 0, 0, 0, 0};
    if (t >= 0) v = *(const us8*)(rk + (bhbase + t) * 128 + eb * 8);
    #pragma unroll
    for (int s = 0; s < 8; ++s) xT[(eb * 8 + s) * 72 + j] = v[s];
  }
  __syncthreads();

  {
    int k = tid & 63, sp = tid >> 6;
    for (int i = 1; i < 64; ++i) {
      float part = 0.f;
      #pragma unroll
      for (int jj = 0; jj < 16; ++jj) {
        int j = sp * 16 + jj;
        part += Af[i * 68 + j] * Af[j * 68 + k];
      }
      red[sp][k] = part;
      __syncthreads();
      if (tid < 64) Af[i * 68 + tid] += red[0][tid] + red[1][tid] + red[2][tid] + red[3][tid];
      __syncthreads();
    }
  }
  {
    int i = tid >> 2, j0 = (tid & 3) * 16;
    #pragma unroll
    for (int jj = 0; jj < 16; ++jj) {
      int j = j0 + jj;
      float av = Af[i * 68 + j] + ((i == j) ? 1.f : 0.f);
      Ab1[i * 72 + j] = f2bf(av * bd[j]);
      Ab2[i * 72 + j] = f2bf(av);
    }
  }
  __syncthreads();

  {
    f32x4 acc[8] = {};
    #pragma unroll
    for (int ks = 0; ks < 2; ++ks) {
      short8v a = *(const short8v*)&Ab1[(w * 16 + c) * 72 + ks * 32 + g * 8];
      #pragma unroll
      for (int nt = 0; nt < 8; ++nt) {
        short8v b = *(const short8v*)&xT[(nt * 16 + c) * 72 + ks * 32 + g * 8];
        acc[nt] = __builtin_amdgcn_mfma_f32_16x16x32_bf16(a, b, acc[nt], 0, 0, 0);
      }
    }
    #pragma unroll
    for (int nt = 0; nt < 8; ++nt)
      #pragma unroll
      for (int r = 0; r < 4; ++r) {
        int i = w * 16 + g * 4 + r, e = nt * 16 + c;
        wkcum[(bhbase + t0 + i) * 128 + e] = f2bf(acc[nt][r]);
      }
  }
  // export wkdwT[p][i] = wk[i][p] * gamma^(63-i)  (xT still holds wk^T)
  {
    const size_t kbase = ((size_t)bh * 64 + n) * 8192;
    #pragma unroll
    for (int u = 0; u < 4; ++u) {
      int idx = tid + u * 256;
      int e = idx >> 3, seg = idx & 7;
      us8 v = *(const us8*)&xT[e * 72 + seg * 8];
      us8 o;
      #pragma unroll
      for (int s = 0; s < 8; ++s) o[s] = f2bf(bf2f(v[s]) * gpow[63 - (seg * 8 + s)]);
      *(us8*)(wkdwT + kbase + (size_t)e * 64 + seg * 8) = o;
    }
  }
  __syncthreads();
  #pragma unroll
  for (int u = 0; u < 4; ++u) {
    int idx = tid + u * 256;
    int j = idx & 63, eb = idx >> 6;
    us8 v = *(const us8*)(vb + (bhbase + t0 + j) * 128 + eb * 8);
    #pragma unroll
    for (int s = 0; s < 8; ++s) xT[(eb * 8 + s) * 72 + j] = v[s];
  }
  __syncthreads();
  {
    f32x4 acc[8] = {};
    #pragma unroll
    for (int ks = 0; ks < 2; ++ks) {
      short8v a = *(const short8v*)&Ab2[(w * 16 + c) * 72 + ks * 32 + g * 8];
      #pragma unroll
      for (int nt = 0; nt < 8; ++nt) {
        short8v b = *(const short8v*)&xT[(nt * 16 + c) * 72 + ks * 32 + g * 8];
        acc[nt] = __builtin_amdgcn_mfma_f32_16x16x32_bf16(a, b, acc[nt], 0, 0, 0);
      }
    }
    #pragma unroll
    for (int nt = 0; nt < 8; ++nt)
      #pragma unroll
      for (int r = 0; r < 4; ++r) {
        int i = w * 16 + g * 4 + r, e = nt * 16 + c;
        vb[(bhbase + t0 + i) * 128 + e] = f2bf(acc[nt][r]);
      }
  }
}

// ---------------- K4: fused MFMA scan, 2 raw barriers, prefetched ----------------
// grid 128 = 32 bh x 4 colgroups(32). Per chunk:
//  region1: [read ST] accA=wkcum@S, accB=rk@S (*gamma); vnT writes | bar
//  region2: [read vnT] accB+=attn@vn -> og; accS=ct*accS+wkdw@vn -> ST | bar
#define SCAN_STEP(CURW, CURR, NXTW, NXTR, n_) {                                  \
  const int t0s = (n_) * 64;                                                    \
  short8v aT0, aT1, aK0, aK1, aK2, aK3;                                          \
  { const size_t ab = ((size_t)bh * 64 + (n_)) * 4096 + (size_t)(16 * w + c) * 64; \
    aT0 = *(const short8v*)(attn + ab + g * 8);                                  \
    aT1 = *(const short8v*)(attn + ab + 32 + g * 8); }                           \
  { const size_t kb = ((size_t)bh * 64 + (n_)) * 8192;                           \
    aK0 = *(const short8v*)(wkdwT + kb + (size_t)(32 * w + c) * 64 + g * 8);     \
    aK1 = *(const short8v*)(wkdwT + kb + (size_t)(32 * w + c) * 64 + 32 + g * 8);\
    aK2 = *(const short8v*)(wkdwT + kb + (size_t)(32 * w + 16 + c) * 64 + g * 8);\
    aK3 = *(const short8v*)(wkdwT + kb + (size_t)(32 * w + 16 + c) * 64 + 32 + g * 8); } \
  float vv[8];                                                                   \
  _Pragma("unroll")                                                              \
  for (int r = 0; r < 4; ++r) {                                                  \
    size_t vbase = (bhbase + t0s + 16 * w + 4 * g + r) * 128 + q0;               \
    vv[r]     = bf2f(vb[vbase + c]);                                             \
    vv[4 + r] = bf2f(vb[vbase + 16 + c]); }                                      \
  { const int np = ((n_) < 63) ? (n_) + 1 : 63;                                  \
    const size_t rb = (bhbase + np * 64 + 16 * w + c) * 128;                     \
    _Pragma("unroll")                                                            \
    for (int ks = 0; ks < 4; ++ks) {                                             \
      NXTW[ks] = *(const short8v*)(wkcum + rb + ks * 32 + g * 8);                \
      NXTR[ks] = *(const short8v*)(rk    + rb + ks * 32 + g * 8); } }            \
  f32x4 accA0 = {}, accA1 = {}, accB0 = {}, accB1 = {};                          \
  _Pragma("unroll")                                                              \
  for (int ks = 0; ks < 4; ++ks) {                                               \
    short8v b0 = *(const short8v*)&ST[c * 136 + ks * 32 + g * 8];                \
    short8v b1 = *(const short8v*)&ST[(16 + c) * 136 + ks * 32 + g * 8];         \
    accA0 = __builtin_amdgcn_mfma_f32_16x16x32_bf16(CURW[ks], b0, accA0, 0, 0, 0); \
    accA1 = __builtin_amdgcn_mfma_f32_16x16x32_bf16(CURW[ks], b1, accA1, 0, 0, 0); \
    accB0 = __builtin_amdgcn_mfma_f32_16x16x32_bf16(CURR[ks], b0, accB0, 0, 0, 0); \
    accB1 = __builtin_amdgcn_mfma_f32_16x16x32_bf16(CURR[ks], b1, accB1, 0, 0, 0); } \
  _Pragma("unroll")                                                              \
  for (int r = 0; r < 4; ++r) {                                                  \
    int i = 16 * w + 4 * g + r;                                                  \
    accB0[r] *= gB[r]; accB1[r] *= gB[r];                                        \
    vnL[c * 72 + i]        = f2bf(vv[r] - accA0[r]);                             \
    vnL[(16 + c) * 72 + i] = f2bf(vv[4 + r] - accA1[r]); }                       \
  asm volatile("s_waitcnt lgkmcnt(0)" ::: "memory");                             \
  __builtin_amdgcn_s_barrier();                                                  \
  short8v vf00 = *(const short8v*)&vnL[c * 72 + g * 8];                          \
  short8v vf01 = *(const short8v*)&vnL[c * 72 + 32 + g * 8];                     \
  short8v vf10 = *(const short8v*)&vnL[(16 + c) * 72 + g * 8];                   \
  short8v vf11 = *(const short8v*)&vnL[(16 + c) * 72 + 32 + g * 8];              \
  accB0 = __builtin_amdgcn_mfma_f32_16x16x32_bf16(aT0, vf00, accB0, 0, 0, 0);    \
  accB0 = __builtin_amdgcn_mfma_f32_16x16x32_bf16(aT1, vf01, accB0, 0, 0, 0);    \
  accB1 = __builtin_amdgcn_mfma_f32_16x16x32_bf16(aT0, vf10, accB1, 0, 0, 0);    \
  accB1 = __builtin_amdgcn_mfma_f32_16x16x32_bf16(aT1, vf11, accB1, 0, 0, 0);    \
  _Pragma("unroll")                                                              \
  for (int r = 0; r < 4; ++r) {                                                  \
    int i = 16 * w + 4 * g + r;                                                  \
    size_t obase = ((size_t)b_ * T_LEN + t0s + i) * 1024 + h * 128 + q0;         \
    og[obase + c] = f2bf(accB0[r]);                                              \
    og[obase + 16 + c] = f2bf(accB1[r]); }                                       \
  _Pragma("unroll")                                                              \
  for (int r = 0; r < 4; ++r) {                                                  \
    accS00[r] *= ct; accS01[r] *= ct; accS10[r] *= ct; accS11[r] *= ct; }        \
  accS00 = __builtin_amdgcn_mfma_f32_16x16x32_bf16(aK0, vf00, accS00, 0, 0, 0);  \
  accS00 = __builtin_amdgcn_mfma_f32_16x16x32_bf16(aK1, vf01, accS00, 0, 0, 0);  \
  accS01 = __builtin_amdgcn_mfma_f32_16x16x32_bf16(aK0, vf10, accS01, 0, 0, 0);  \
  accS01 = __builtin_amdgcn_mfma_f32_16x16x32_bf16(aK1, vf11, accS01, 0, 0, 0);  \
  accS10 = __builtin_amdgcn_mfma_f32_16x16x32_bf16(aK2, vf00, accS10, 0, 0, 0);  \
  accS10 = __builtin_amdgcn_mfma_f32_16x16x32_bf16(aK3, vf01, accS10, 0, 0, 0);  \
  accS11 = __builtin_amdgcn_mfma_f32_16x16x32_bf16(aK2, vf10, accS11, 0, 0, 0);  \
  accS11 = __builtin_amdgcn_mfma_f32_16x16x32_bf16(aK3, vf11, accS11, 0, 0, 0);  \
  _Pragma("unroll")                                                              \
  for (int r = 0; r < 4; ++r) {                                                  \
    int p0r = 32 * w + 4 * g + r;                                                \
    ST[c * 136 + p0r]             = f2bf(accS00[r]);                             \
    ST[c * 136 + p0r + 16]        = f2bf(accS10[r]);                             \
    ST[(16 + c) * 136 + p0r]      = f2bf(accS01[r]);                             \
    ST[(16 + c) * 136 + p0r + 16] = f2bf(accS11[r]); }                           \
  asm volatile("s_waitcnt lgkmcnt(0)" ::: "memory");                             \
  __builtin_amdgcn_s_barrier();                                                  \
}

__global__ __launch_bounds__(256) void k_scan_fused(
    const ushort* __restrict__ rk, const ushort* __restrict__ vb,
    const ushort* __restrict__ wkcum, const ushort* __restrict__ attn,
    const ushort* __restrict__ wkdwT, const float* __restrict__ decay,
    ushort* __restrict__ og)
{
  const int bh = blockIdx.x >> 2;
  const int q0 = (blockIdx.x & 3) * 32;
  const int b_ = bh >> 3, h = bh & 7;
  const int tid = threadIdx.x;
  const int lane = tid & 63, w = tid >> 6;
  const int c = lane & 15, g = lane >> 4;

  __shared__ ushort ST[32 * 136];
  __shared__ ushort vnL[32 * 72];
  __shared__ float gpow[65];

  float lg = logf(1.f / (1.f + expf(-decay[h])));
  if (tid < 65) gpow[tid] = expf(lg * (float)tid);
  for (int idx = tid; idx < 32 * 136; idx += 256) ST[idx] = 0;
  __syncthreads();
  const float ct = gpow[64];
  float gB[4];
  #pragma unroll
  for (int r = 0; r < 4; ++r) gB[r] = gpow[16 * w + 4 * g + r + 1];
  const size_t bhbase = (size_t)bh * T_LEN;

  f32x4 accS00 = {}, accS01 = {}, accS10 = {}, accS11 = {};
  short8v bAW[4], bAR[4], bBW[4], bBR[4];
  // prologue: load chunk 0 fragments
  {
    const size_t rb = (bhbase + 16 * w + c) * 128;
    #pragma unroll
    for (int ks = 0; ks < 4; ++ks) {
      bAW[ks] = *(const short8v*)(wkcum + rb + ks * 32 + g * 8);
      bAR[ks] = *(const short8v*)(rk + rb + ks * 32 + g * 8);
    }
  }
  for (int n = 0; n < 64; n += 2) {
    SCAN_STEP(bAW, bAR, bBW, bBR, n);
    SCAN_STEP(bBW, bBR, bAW, bAR, n + 1);
  }
}

extern "C" void kernel_launch(void* const* d_in, const int* in_sizes, int n_in,
                              void* d_out, int out_size, void* d_ws, size_t ws_size,
                              hipStream_t stream) {
  const float* x   = (const float*)d_in[0];
  const float* Ww  = (const float*)d_in[1];
  const float* Wr  = (const float*)d_in[2];
  const float* Wb  = (const float*)d_in[3];
  const float* dec = (const float*)d_in[4];
  float* out = (float*)d_out;
  ushort* ws = (ushort*)d_ws;
  const size_t SZ = 16777216ull;
  ushort* rk    = ws;                                   // 32 MB
  ushort* vb    = ws + SZ;                              // 32 MB
  ushort* wkcum = ws + 2 * SZ;                          // 32 MB
  ushort* og    = ws + 3 * SZ;                          // 32 MB
  ushort* attn  = ws + 4 * SZ;                          // 16 MB
  float*  beta  = (float*)(ws + 4 * SZ + 8388608ull);   // 0.5 MB
  ushort* wkdwT = ws + 4 * SZ + 8388608ull + 262144ull; // 32 MB
  const size_t NEED = (4 * SZ + 8388608ull + 262144ull + SZ) * 2ull; // 185,073,664 B
  if (ws_size < NEED) {
    hipMemcpyAsync(d_out, (const void*)x, (size_t)out_size * 4, hipMemcpyDeviceToDevice, stream);
    return;
  }

  k_prep<<<dim3(16384), dim3(128), 0, stream>>>(x, Wb, rk, beta);
  k_gemm<0><<<dim3(8, 128), dim3(256), 0, stream>>>((const void*)x, Ww, beta, nullptr, (void*)vb);
  k_chunk<<<dim3(2048), dim3(256), 0, stream>>>(rk, vb, wkcum, attn, beta, dec, wkdwT);
  k_scan_fused<<<dim3(128), dim3(256), 0, stream>>>(rk, vb, wkcum, attn, wkdwT, dec, og);
  k_gemm<1><<<dim3(8, 128), dim3(256), 0, stream>>>((const void*)og, Wr, nullptr, (const float*)x, (void*)out);
}

// Round 8
// 461.154 us; speedup vs baseline: 5.8205x; 1.0721x over previous
//
#include <hip/hip_runtime.h>
#include <hip/hip_bf16.h>
#include <math.h>

// HebbianBlock: B=4, T=4096, D=1024, H=8, d=128, C=64, N=64
// Round 8: scan latency attack #2.
//  - col-groups 32 -> 16 (grid 256 = 1 block/CU, halves per-chunk MFMA chain)
//  - FULL one-chunk-ahead prefetch (wkcum/rk/attn/wkdwT/vb) in double-buffered
//    named register sets
//  - XCD-aligned block mapping: bh = bid & 31 so all 8 col-groups of a bh
//    share an XCD's L2 (A-operand streams are identical across groups)
// k_prep / k_gemm / k_chunk verbatim from passing Round 7.

#define T_LEN 4096
typedef unsigned short ushort;
typedef __attribute__((ext_vector_type(2))) unsigned short us2;
typedef __attribute__((ext_vector_type(4))) unsigned short us4;
typedef __attribute__((ext_vector_type(8))) unsigned short us8;
typedef __attribute__((ext_vector_type(8))) short short8v;
typedef __attribute__((ext_vector_type(4))) float f32x4;

__device__ __forceinline__ float bf2f(ushort u) {
  union { unsigned int u; float f; } c; c.u = ((unsigned int)u) << 16; return c.f;
}
__device__ __forceinline__ ushort f2bf(float x) {
  union { float f; unsigned int u; } c; c.f = x;
  unsigned int u = c.u + 0x7FFFu + ((c.u >> 16) & 1u);
  return (ushort)(u >> 16);
}
__device__ __forceinline__ ushort f2bf_fast(float x) {
  __hip_bfloat16 h = __float2bfloat16(x);
  return *reinterpret_cast<ushort*>(&h);
}

// ---------------- K1: rk + beta ----------------
__global__ __launch_bounds__(128) void k_prep(
    const float* __restrict__ x, const float* __restrict__ Wb,
    ushort* __restrict__ rk, float* __restrict__ beta)
{
  int bt = blockIdx.x;
  int b = bt >> 12, t = bt & 4095;
  int tid = threadIdx.x;
  __shared__ float xs[1024];
  __shared__ float red[16];
  {
    const float4* x4 = (const float4*)(x + (size_t)bt * 1024);
    float4* xs4 = (float4*)xs;
    xs4[tid] = x4[tid];
    xs4[tid + 128] = x4[tid + 128];
  }
  __syncthreads();
  int h = tid >> 4;
  int e0 = h * 128 + (tid & 15) * 8;
  float ss = 0.f;
  #pragma unroll
  for (int s = 0; s < 8; ++s) { float v = xs[e0 + s]; ss += v * v; }
  #pragma unroll
  for (int m = 1; m < 16; m <<= 1) ss += __shfl_xor(ss, m, 64);
  float inv = 1.f / fmaxf(sqrtf(ss), 1e-12f);
  {
    int bh = b * 8 + h;
    us8 o;
    #pragma unroll
    for (int s = 0; s < 8; ++s) o[s] = f2bf(xs[e0 + s] * inv);
    *(us8*)(rk + ((size_t)bh * T_LEN + t) * 128 + (tid & 15) * 8) = o;
  }
  const float* xk = xs + tid * 8;
  #pragma unroll
  for (int h2 = 0; h2 < 8; ++h2) {
    const float* wb = Wb + (size_t)h2 * 1024 + tid * 8;
    float p = 0.f;
    #pragma unroll
    for (int s = 0; s < 8; ++s) p += xk[s] * wb[s];
    #pragma unroll
    for (int m = 1; m < 64; m <<= 1) p += __shfl_xor(p, m, 64);
    if ((tid & 63) == 0) red[(tid >> 6) * 8 + h2] = p;
  }
  __syncthreads();
  if (tid < 8) {
    float s = red[tid] + red[8 + tid];
    beta[((size_t)(b * 8 + tid)) * T_LEN + t] = 1.f / (1.f + expf(-s));
  }
}

// ---------------- K2/K5: bf16 MFMA GEMM, 128x128 tile, BK=32 ----------------
#define LDK 40
template<int MODE>
__global__ __launch_bounds__(256) void k_gemm(
    const void* __restrict__ Am_, const float* __restrict__ W,
    const float* __restrict__ beta, const float* __restrict__ xadd,
    void* __restrict__ out_)
{
  __shared__ ushort As[128 * LDK];
  __shared__ ushort Bs[128 * LDK];
  const int n0 = blockIdx.x * 128;
  const int m0 = blockIdx.y * 128;
  const int tid = threadIdx.x;
  const int lane = tid & 63;
  const int wid = tid >> 6;
  const int wr = wid >> 1, wc = wid & 1;
  const int c = lane & 15, g = lane >> 4;
  const int srow = tid >> 2;
  const int seg = tid & 3;

  f32x4 acc[4][4] = {};

  for (int k0 = 0; k0 < 1024; k0 += 32) {
    if (MODE == 0) {
      const float* a0 = (const float*)Am_ + (size_t)(m0 + srow) * 1024 + k0 + seg * 8;
      const float* a1 = (const float*)Am_ + (size_t)(m0 + srow + 64) * 1024 + k0 + seg * 8;
      float4 p0 = *(const float4*)a0, p1 = *(const float4*)(a0 + 4);
      float4 q0 = *(const float4*)a1, q1 = *(const float4*)(a1 + 4);
      us8 o0, o1;
      o0[0]=f2bf_fast(p0.x); o0[1]=f2bf_fast(p0.y); o0[2]=f2bf_fast(p0.z); o0[3]=f2bf_fast(p0.w);
      o0[4]=f2bf_fast(p1.x); o0[5]=f2bf_fast(p1.y); o0[6]=f2bf_fast(p1.z); o0[7]=f2bf_fast(p1.w);
      o1[0]=f2bf_fast(q0.x); o1[1]=f2bf_fast(q0.y); o1[2]=f2bf_fast(q0.z); o1[3]=f2bf_fast(q0.w);
      o1[4]=f2bf_fast(q1.x); o1[5]=f2bf_fast(q1.y); o1[6]=f2bf_fast(q1.z); o1[7]=f2bf_fast(q1.w);
      *(us8*)&As[srow * LDK + seg * 8] = o0;
      *(us8*)&As[(srow + 64) * LDK + seg * 8] = o1;
    } else {
      us8 o0 = *(const us8*)((const ushort*)Am_ + (size_t)(m0 + srow) * 1024 + k0 + seg * 8);
      us8 o1 = *(const us8*)((const ushort*)Am_ + (size_t)(m0 + srow + 64) * 1024 + k0 + seg * 8);
      *(us8*)&As[srow * LDK + seg * 8] = o0;
      *(us8*)&As[(srow + 64) * LDK + seg * 8] = o1;
    }
    {
      const float* b0 = W + (size_t)(n0 + srow) * 1024 + k0 + seg * 8;
      const float* b1 = W + (size_t)(n0 + srow + 64) * 1024 + k0 + seg * 8;
      float4 p0 = *(const float4*)b0, p1 = *(const float4*)(b0 + 4);
      float4 q0 = *(const float4*)b1, q1 = *(const float4*)(b1 + 4);
      us8 o0, o1;
      o0[0]=f2bf_fast(p0.x); o0[1]=f2bf_fast(p0.y); o0[2]=f2bf_fast(p0.z); o0[3]=f2bf_fast(p0.w);
      o0[4]=f2bf_fast(p1.x); o0[5]=f2bf_fast(p1.y); o0[6]=f2bf_fast(p1.z); o0[7]=f2bf_fast(p1.w);
      o1[0]=f2bf_fast(q0.x); o1[1]=f2bf_fast(q0.y); o1[2]=f2bf_fast(q0.z); o1[3]=f2bf_fast(q0.w);
      o1[4]=f2bf_fast(q1.x); o1[5]=f2bf_fast(q1.y); o1[6]=f2bf_fast(q1.z); o1[7]=f2bf_fast(q1.w);
      *(us8*)&Bs[srow * LDK + seg * 8] = o0;
      *(us8*)&Bs[(srow + 64) * LDK + seg * 8] = o1;
    }
    __syncthreads();
    short8v af[4], bf[4];
    #pragma unroll
    for (int mi = 0; mi < 4; ++mi)
      af[mi] = *(const short8v*)&As[(wr * 64 + mi * 16 + c) * LDK + g * 8];
    #pragma unroll
    for (int ni = 0; ni < 4; ++ni)
      bf[ni] = *(const short8v*)&Bs[(wc * 64 + ni * 16 + c) * LDK + g * 8];
    #pragma unroll
    for (int mi = 0; mi < 4; ++mi)
      #pragma unroll
      for (int ni = 0; ni < 4; ++ni)
        acc[mi][ni] = __builtin_amdgcn_mfma_f32_16x16x32_bf16(af[mi], bf[ni], acc[mi][ni], 0, 0, 0);
    __syncthreads();
  }

  if (MODE == 0) {
    ushort* vb = (ushort*)out_;
    const int hh = n0 >> 7;
    #pragma unroll
    for (int mi = 0; mi < 4; ++mi) {
      #pragma unroll
      for (int ni = 0; ni < 4; ++ni) {
        int jc = wc * 64 + ni * 16 + c;
        #pragma unroll
        for (int j = 0; j < 4; ++j) {
          int m = m0 + wr * 64 + mi * 16 + g * 4 + j;
          int b = m >> 12, t = m & 4095;
          size_t base = (size_t)(b * 8 + hh) * T_LEN + t;
          float bv = beta[base];
          vb[base * 128 + jc] = f2bf(acc[mi][ni][j] * bv);
        }
      }
    }
  } else {
    float* out = (float*)out_;
    #pragma unroll
    for (int mi = 0; mi < 4; ++mi) {
      #pragma unroll
      for (int ni = 0; ni < 4; ++ni) {
        int n = n0 + wc * 64 + ni * 16 + c;
        #pragma unroll
        for (int j = 0; j < 4; ++j) {
          int m = m0 + wr * 64 + mi * 16 + g * 4 + j;
          size_t idx = (size_t)m * 1024 + n;
          out[idx] = xadd[idx] + acc[mi][ni][j];
        }
      }
    }
  }
}

// ---------------- K3: per-chunk UT transform (MFMA) + wkdwT export ----------------
__global__ __launch_bounds__(256) void k_chunk(
    const ushort* __restrict__ rk, ushort* __restrict__ vb,
    ushort* __restrict__ wkcum, ushort* __restrict__ attn,
    const float* __restrict__ beta, const float* __restrict__ decay,
    ushort* __restrict__ wkdwT)
{
  int bh = blockIdx.x >> 6;
  int n = blockIdx.x & 63;
  int h = bh & 7;
  int tid = threadIdx.x;
  int lane = tid & 63, w = tid >> 6;
  int c = lane & 15, g = lane >> 4;

  __shared__ ushort rkb[80 * 136];
  __shared__ float  Af[64 * 68];
  __shared__ ushort Ab1[64 * 72];
  __shared__ ushort Ab2[64 * 72];
  __shared__ ushort xT[128 * 72];
  __shared__ float  red[4][64];
  __shared__ float  betaS[64], bd[64], gpow[65];

  float lg = logf(1.f / (1.f + expf(-decay[h])));
  if (tid < 65) gpow[tid] = expf(lg * (float)tid);
  if (tid < 64) betaS[tid] = beta[(size_t)bh * T_LEN + n * 64 + tid];
  const int t0 = n * 64;
  const size_t bhbase = (size_t)bh * T_LEN;

  #pragma unroll
  for (int u = 0; u < 5; ++u) {
    int idx = tid + u * 256;
    int row = idx >> 4, cb = idx & 15;
    us8 v = {0, 0, 0, 0, 0, 0, 0, 0};
    int t = t0 + row - 1;
    if (row <= 64 && t >= 0) v = *(const us8*)(rk + (bhbase + t) * 128 + cb * 8);
    *(us8*)&rkb[row * 136 + cb * 8] = v;
  }
  for (int idx = tid; idx < 64 * 68; idx += 256) Af[idx] = 0.f;
  __syncthreads();
  if (tid < 64) bd[tid] = betaS[tid] * gpow[tid + 1];

  const size_t abase = ((size_t)bh * 64 + n) * 4096;
  {
    const int TR[14] = {0,1,1,2,2,2,3,3,3,3,4,4,4,4};
    const int TC[14] = {0,0,1,0,1,2,0,1,2,3,0,1,2,3};
    #pragma unroll
    for (int ti = 0; ti < 14; ++ti) {
      if ((ti & 3) != w) continue;
      const int tr = TR[ti], tc = TC[ti];
      f32x4 acc = {0.f, 0.f, 0.f, 0.f};
      #pragma unroll
      for (int ks = 0; ks < 4; ++ks) {
        short8v a = *(const short8v*)&rkb[(tr * 16 + c) * 136 + ks * 32 + g * 8];
        short8v b = *(const short8v*)&rkb[(tc * 16 + c) * 136 + ks * 32 + g * 8];
        acc = __builtin_amdgcn_mfma_f32_16x16x32_bf16(a, b, acc, 0, 0, 0);
      }
      #pragma unroll
      for (int r = 0; r < 4; ++r) {
        int a_ = tr * 16 + g * 4 + r;
        int j = tc * 16 + c;
        float val = acc[r];
        if (a_ <= 63) Af[a_ * 68 + j] = (a_ > j) ? (-betaS[a_] * val * gpow[a_ - j]) : 0.f;
        if (a_ >= 1 && a_ <= 64) {
          if (j <= a_ - 1)      attn[abase + (size_t)(a_ - 1) * 64 + j] = f2bf(val * gpow[a_ - 1 - j]);
          else if (a_ <= 63)    attn[abase + (size_t)(a_ - 1) * 64 + j] = 0;
        }
      }
    }
  }
  {
    const int ZR[6] = {0,0,0,1,1,2};
    const int ZC[6] = {1,2,3,2,3,3};
    int rr = tid >> 4, cc2 = tid & 15;
    #pragma unroll
    for (int z = 0; z < 6; ++z) {
      int r_att = ZR[z] * 16 - 1 + rr;
      if (r_att >= 0) attn[abase + (size_t)r_att * 64 + ZC[z] * 16 + cc2] = 0;
    }
  }
  #pragma unroll
  for (int u = 0; u < 4; ++u) {
    int idx = tid + u * 256;
    int j = idx & 63, eb = idx >> 6;
    int t = t0 + j - 1;
    us8 v = {0, 0, 0, 0, 0, 0, 0, 0};
    if (t >= 0) v = *(const us8*)(rk + (bhbase + t) * 128 + eb * 8);
    #pragma unroll
    for (int s = 0; s < 8; ++s) xT[(eb * 8 + s) * 72 + j] = v[s];
  }
  __syncthreads();

  {
    int k = tid & 63, sp = tid >> 6;
    for (int i = 1; i < 64; ++i) {
      float part = 0.f;
      #pragma unroll
      for (int jj = 0; jj < 16; ++jj) {
        int j = sp * 16 + jj;
        part += Af[i * 68 + j] * Af[j * 68 + k];
      }
      red[sp][k] = part;
      __syncthreads();
      if (tid < 64) Af[i * 68 + tid] += red[0][tid] + red[1][tid] + red[2][tid] + red[3][tid];
      __syncthreads();
    }
  }
  {
    int i = tid >> 2, j0 = (tid & 3) * 16;
    #pragma unroll
    for (int jj = 0; jj < 16; ++jj) {
      int j = j0 + jj;
      float av = Af[i * 68 + j] + ((i == j) ? 1.f : 0.f);
      Ab1[i * 72 + j] = f2bf(av * bd[j]);
      Ab2[i * 72 + j] = f2bf(av);
    }
  }
  __syncthreads();

  {
    f32x4 acc[8] = {};
    #pragma unroll
    for (int ks = 0; ks < 2; ++ks) {
      short8v a = *(const short8v*)&Ab1[(w * 16 + c) * 72 + ks * 32 + g * 8];
      #pragma unroll
      for (int nt = 0; nt < 8; ++nt) {
        short8v b = *(const short8v*)&xT[(nt * 16 + c) * 72 + ks * 32 + g * 8];
        acc[nt] = __builtin_amdgcn_mfma_f32_16x16x32_bf16(a, b, acc[nt], 0, 0, 0);
      }
    }
    #pragma unroll
    for (int nt = 0; nt < 8; ++nt)
      #pragma unroll
      for (int r = 0; r < 4; ++r) {
        int i = w * 16 + g * 4 + r, e = nt * 16 + c;
        wkcum[(bhbase + t0 + i) * 128 + e] = f2bf(acc[nt][r]);
      }
  }
  // export wkdwT[p][i] = wk[i][p] * gamma^(63-i)  (xT still holds wk^T)
  {
    const size_t kbase = ((size_t)bh * 64 + n) * 8192;
    #pragma unroll
    for (int u = 0; u < 4; ++u) {
      int idx = tid + u * 256;
      int e = idx >> 3, seg = idx & 7;
      us8 v = *(const us8*)&xT[e * 72 + seg * 8];
      us8 o;
      #pragma unroll
      for (int s = 0; s < 8; ++s) o[s] = f2bf(bf2f(v[s]) * gpow[63 - (seg * 8 + s)]);
      *(us8*)(wkdwT + kbase + (size_t)e * 64 + seg * 8) = o;
    }
  }
  __syncthreads();
  #pragma unroll
  for (int u = 0; u < 4; ++u) {
    int idx = tid + u * 256;
    int j = idx & 63, eb = idx >> 6;
    us8 v = *(const us8*)(vb + (bhbase + t0 + j) * 128 + eb * 8);
    #pragma unroll
    for (int s = 0; s < 8; ++s) xT[(eb * 8 + s) * 72 + j] = v[s];
  }
  __syncthreads();
  {
    f32x4 acc[8] = {};
    #pragma unroll
    for (int ks = 0; ks < 2; ++ks) {
      short8v a = *(const short8v*)&Ab2[(w * 16 + c) * 72 + ks * 32 + g * 8];
      #pragma unroll
      for (int nt = 0; nt < 8; ++nt) {
        short8v b = *(const short8v*)&xT[(nt * 16 + c) * 72 + ks * 32 + g * 8];
        acc[nt] = __builtin_amdgcn_mfma_f32_16x16x32_bf16(a, b, acc[nt], 0, 0, 0);
      }
    }
    #pragma unroll
    for (int nt = 0; nt < 8; ++nt)
      #pragma unroll
      for (int r = 0; r < 4; ++r) {
        int i = w * 16 + g * 4 + r, e = nt * 16 + c;
        vb[(bhbase + t0 + i) * 128 + e] = f2bf(acc[nt][r]);
      }
  }
}

// ---------------- K4: fused MFMA scan, 16-col groups, full prefetch ----------------
// grid 256 = 8 colgroups x 32 bh (bh = bid & 31 -> same-bh groups share an XCD).
// Per chunk: region1 [read ST] accA=wkcum@S, accB=rk@S(*gamma), vnL write | bar
//            region2 [read vnL] accB+=attn@vn -> og; accS=ct*accS+wkdw@vn -> ST | bar
// ALL global operands for chunk n+1 issue at the top of chunk n (reg sets A/B).
#define SCAN_STEP(W_, R_, T_, K_, V_, nW, nR, nT, nK, nV, n_) {                 \
  const int t0s = (n_) * 64;                                                    \
  { const int np = ((n_) < 63) ? (n_) + 1 : 63;                                 \
    const size_t rb = (bhbase + (size_t)(np * 64 + 16 * w + c)) * 128;          \
    _Pragma("unroll")                                                           \
    for (int ks = 0; ks < 4; ++ks) {                                            \
      nW[ks] = *(const short8v*)(wkcum + rb + ks * 32 + g * 8);                 \
      nR[ks] = *(const short8v*)(rk    + rb + ks * 32 + g * 8); }               \
    const size_t ab = ((size_t)bh * 64 + np) * 4096 + (size_t)(16 * w + c) * 64;\
    nT[0] = *(const short8v*)(attn + ab + g * 8);                               \
    nT[1] = *(const short8v*)(attn + ab + 32 + g * 8);                          \
    const size_t kb = ((size_t)bh * 64 + np) * 8192;                            \
    nK[0] = *(const short8v*)(wkdwT + kb + (size_t)(32 * w + c) * 64 + g * 8);  \
    nK[1] = *(const short8v*)(wkdwT + kb + (size_t)(32 * w + c) * 64 + 32 + g * 8); \
    nK[2] = *(const short8v*)(wkdwT + kb + (size_t)(32 * w + 16 + c) * 64 + g * 8); \
    nK[3] = *(const short8v*)(wkdwT + kb + (size_t)(32 * w + 16 + c) * 64 + 32 + g * 8); \
    _Pragma("unroll")                                                           \
    for (int r = 0; r < 4; ++r)                                                 \
      nV[r] = vb[(bhbase + (size_t)(np * 64 + 16 * w + 4 * g + r)) * 128 + q0 + c]; } \
  f32x4 accA = {}, accB = {};                                                   \
  _Pragma("unroll")                                                             \
  for (int ks = 0; ks < 4; ++ks) {                                              \
    short8v b0 = *(const short8v*)&ST[c * 136 + ks * 32 + g * 8];               \
    accA = __builtin_amdgcn_mfma_f32_16x16x32_bf16(W_[ks], b0, accA, 0, 0, 0);  \
    accB = __builtin_amdgcn_mfma_f32_16x16x32_bf16(R_[ks], b0, accB, 0, 0, 0); }\
  _Pragma("unroll")                                                             \
  for (int r = 0; r < 4; ++r) {                                                 \
    int i = 16 * w + 4 * g + r;                                                 \
    accB[r] *= gB[r];                                                           \
    vnL[c * 72 + i] = f2bf(bf2f(V_[r]) - accA[r]); }                            \
  asm volatile("s_waitcnt lgkmcnt(0)" ::: "memory");                            \
  __builtin_amdgcn_s_barrier();                                                 \
  short8v vf0 = *(const short8v*)&vnL[c * 72 + g * 8];                          \
  short8v vf1 = *(const short8v*)&vnL[c * 72 + 32 + g * 8];                     \
  accB = __builtin_amdgcn_mfma_f32_16x16x32_bf16(T_[0], vf0, accB, 0, 0, 0);    \
  accB = __builtin_amdgcn_mfma_f32_16x16x32_bf16(T_[1], vf1, accB, 0, 0, 0);    \
  _Pragma("unroll")                                                             \
  for (int r = 0; r < 4; ++r) {                                                 \
    int i = 16 * w + 4 * g + r;                                                 \
    og[((size_t)b_ * T_LEN + t0s + i) * 1024 + h * 128 + q0 + c] = f2bf(accB[r]); } \
  _Pragma("unroll")                                                             \
  for (int r = 0; r < 4; ++r) { accS0[r] *= ct; accS1[r] *= ct; }               \
  accS0 = __builtin_amdgcn_mfma_f32_16x16x32_bf16(K_[0], vf0, accS0, 0, 0, 0);  \
  accS0 = __builtin_amdgcn_mfma_f32_16x16x32_bf16(K_[1], vf1, accS0, 0, 0, 0);  \
  accS1 = __builtin_amdgcn_mfma_f32_16x16x32_bf16(K_[2], vf0, accS1, 0, 0, 0);  \
  accS1 = __builtin_amdgcn_mfma_f32_16x16x32_bf16(K_[3], vf1, accS1, 0, 0, 0);  \
  _Pragma("unroll")                                                             \
  for (int r = 0; r < 4; ++r) {                                                 \
    int p0r = 32 * w + 4 * g + r;                                               \
    ST[c * 136 + p0r]      = f2bf(accS0[r]);                                    \
    ST[c * 136 + p0r + 16] = f2bf(accS1[r]); }                                  \
  asm volatile("s_waitcnt lgkmcnt(0)" ::: "memory");                            \
  __builtin_amdgcn_s_barrier();                                                 \
}

__global__ __launch_bounds__(256) void k_scan_fused(
    const ushort* __restrict__ rk, const ushort* __restrict__ vb,
    const ushort* __restrict__ wkcum, const ushort* __restrict__ attn,
    const ushort* __restrict__ wkdwT, const float* __restrict__ decay,
    ushort* __restrict__ og)
{
  const int bh = blockIdx.x & 31;          // same-bh groups -> same XCD
  const int q0 = (blockIdx.x >> 5) * 16;
  const int b_ = bh >> 3, h = bh & 7;
  const int tid = threadIdx.x;
  const int lane = tid & 63, w = tid >> 6;
  const int c = lane & 15, g = lane >> 4;

  __shared__ ushort ST[16 * 136];
  __shared__ ushort vnL[16 * 72];
  __shared__ float gpow[65];

  float lg = logf(1.f / (1.f + expf(-decay[h])));
  if (tid < 65) gpow[tid] = expf(lg * (float)tid);
  for (int idx = tid; idx < 16 * 136; idx += 256) ST[idx] = 0;
  __syncthreads();
  const float ct = gpow[64];
  float gB[4];
  #pragma unroll
  for (int r = 0; r < 4; ++r) gB[r] = gpow[16 * w + 4 * g + r + 1];
  const size_t bhbase = (size_t)bh * T_LEN;

  f32x4 accS0 = {}, accS1 = {};
  short8v aW[4], aR[4], aT[2], aK[4];
  short8v bW[4], bR[4], bT[2], bK[4];
  ushort aV[4], bV[4];
  // prologue: chunk-0 operands into set A
  {
    const size_t rb = (bhbase + (size_t)(16 * w + c)) * 128;
    #pragma unroll
    for (int ks = 0; ks < 4; ++ks) {
      aW[ks] = *(const short8v*)(wkcum + rb + ks * 32 + g * 8);
      aR[ks] = *(const short8v*)(rk + rb + ks * 32 + g * 8);
    }
    const size_t ab = (size_t)bh * 64 * 4096 + (size_t)(16 * w + c) * 64;
    aT[0] = *(const short8v*)(attn + ab + g * 8);
    aT[1] = *(const short8v*)(attn + ab + 32 + g * 8);
    const size_t kb = (size_t)bh * 64 * 8192;
    aK[0] = *(const short8v*)(wkdwT + kb + (size_t)(32 * w + c) * 64 + g * 8);
    aK[1] = *(const short8v*)(wkdwT + kb + (size_t)(32 * w + c) * 64 + 32 + g * 8);
    aK[2] = *(const short8v*)(wkdwT + kb + (size_t)(32 * w + 16 + c) * 64 + g * 8);
    aK[3] = *(const short8v*)(wkdwT + kb + (size_t)(32 * w + 16 + c) * 64 + 32 + g * 8);
    #pragma unroll
    for (int r = 0; r < 4; ++r)
      aV[r] = vb[(bhbase + (size_t)(16 * w + 4 * g + r)) * 128 + q0 + c];
  }
  for (int n = 0; n < 64; n += 2) {
    SCAN_STEP(aW, aR, aT, aK, aV, bW, bR, bT, bK, bV, n);
    SCAN_STEP(bW, bR, bT, bK, bV, aW, aR, aT, aK, aV, n + 1);
  }
}

extern "C" void kernel_launch(void* const* d_in, const int* in_sizes, int n_in,
                              void* d_out, int out_size, void* d_ws, size_t ws_size,
                              hipStream_t stream) {
  const float* x   = (const float*)d_in[0];
  const float* Ww  = (const float*)d_in[1];
  const float* Wr  = (const float*)d_in[2];
  const float* Wb  = (const float*)d_in[3];
  const float* dec = (const float*)d_in[4];
  float* out = (float*)d_out;
  ushort* ws = (ushort*)d_ws;
  const size_t SZ = 16777216ull;
  ushort* rk    = ws;                                   // 32 MB
  ushort* vb    = ws + SZ;                              // 32 MB
  ushort* wkcum = ws + 2 * SZ;                          // 32 MB
  ushort* og    = ws + 3 * SZ;                          // 32 MB
  ushort* attn  = ws + 4 * SZ;                          // 16 MB
  float*  beta  = (float*)(ws + 4 * SZ + 8388608ull);   // 0.5 MB
  ushort* wkdwT = ws + 4 * SZ + 8388608ull + 262144ull; // 32 MB
  const size_t NEED = (4 * SZ + 8388608ull + 262144ull + SZ) * 2ull; // 185 MB
  if (ws_size < NEED) {
    hipMemcpyAsync(d_out, (const void*)x, (size_t)out_size * 4, hipMemcpyDeviceToDevice, stream);
    return;
  }

  k_prep<<<dim3(16384), dim3(128), 0, stream>>>(x, Wb, rk, beta);
  k_gemm<0><<<dim3(8, 128), dim3(256), 0, stream>>>((const void*)x, Ww, beta, nullptr, (void*)vb);
  k_chunk<<<dim3(2048), dim3(256), 0, stream>>>(rk, vb, wkcum, attn, beta, dec, wkdwT);
  k_scan_fused<<<dim3(256), dim3(256), 0, stream>>>(rk, vb, wkcum, attn, wkdwT, dec, og);
  k_gemm<1><<<dim3(8, 128), dim3(256), 0, stream>>>((const void*)og, Wr, nullptr, (const float*)x, (void*)out);
}

// Round 10
// 426.132 us; speedup vs baseline: 6.2989x; 1.0822x over previous
//
#include <hip/hip_runtime.h>
#include <hip/hip_bf16.h>
#include <math.h>

// HebbianBlock: B=4, T=4096, D=1024, H=8, d=128, C=64, N=64
// Round 10: revert k_chunk to R8's EXACT serial-f32 UT numerics (R9's bf16
// log-doubling compounded rounding -> 0.177 fail). Instead, cut k_chunk LDS
// 78.3KB -> ~40KB via live-range overlays (xT staged after UT; red/Ab1/Ab2
// overlay dead rkb; xT overlays dead Af) -> 4 blocks/CU, 2 generations.
// k_prep / k_gemm / k_scan_fused verbatim from passing Round 8.

#define T_LEN 4096
typedef unsigned short ushort;
typedef __attribute__((ext_vector_type(2))) unsigned short us2;
typedef __attribute__((ext_vector_type(4))) unsigned short us4;
typedef __attribute__((ext_vector_type(8))) unsigned short us8;
typedef __attribute__((ext_vector_type(8))) short short8v;
typedef __attribute__((ext_vector_type(4))) float f32x4;

__device__ __forceinline__ float bf2f(ushort u) {
  union { unsigned int u; float f; } c; c.u = ((unsigned int)u) << 16; return c.f;
}
__device__ __forceinline__ ushort f2bf(float x) {
  union { float f; unsigned int u; } c; c.f = x;
  unsigned int u = c.u + 0x7FFFu + ((c.u >> 16) & 1u);
  return (ushort)(u >> 16);
}
__device__ __forceinline__ ushort f2bf_fast(float x) {
  __hip_bfloat16 h = __float2bfloat16(x);
  return *reinterpret_cast<ushort*>(&h);
}

// ---------------- K1: rk + beta ----------------
__global__ __launch_bounds__(128) void k_prep(
    const float* __restrict__ x, const float* __restrict__ Wb,
    ushort* __restrict__ rk, float* __restrict__ beta)
{
  int bt = blockIdx.x;
  int b = bt >> 12, t = bt & 4095;
  int tid = threadIdx.x;
  __shared__ float xs[1024];
  __shared__ float red[16];
  {
    const float4* x4 = (const float4*)(x + (size_t)bt * 1024);
    float4* xs4 = (float4*)xs;
    xs4[tid] = x4[tid];
    xs4[tid + 128] = x4[tid + 128];
  }
  __syncthreads();
  int h = tid >> 4;
  int e0 = h * 128 + (tid & 15) * 8;
  float ss = 0.f;
  #pragma unroll
  for (int s = 0; s < 8; ++s) { float v = xs[e0 + s]; ss += v * v; }
  #pragma unroll
  for (int m = 1; m < 16; m <<= 1) ss += __shfl_xor(ss, m, 64);
  float inv = 1.f / fmaxf(sqrtf(ss), 1e-12f);
  {
    int bh = b * 8 + h;
    us8 o;
    #pragma unroll
    for (int s = 0; s < 8; ++s) o[s] = f2bf(xs[e0 + s] * inv);
    *(us8*)(rk + ((size_t)bh * T_LEN + t) * 128 + (tid & 15) * 8) = o;
  }
  const float* xk = xs + tid * 8;
  #pragma unroll
  for (int h2 = 0; h2 < 8; ++h2) {
    const float* wb = Wb + (size_t)h2 * 1024 + tid * 8;
    float p = 0.f;
    #pragma unroll
    for (int s = 0; s < 8; ++s) p += xk[s] * wb[s];
    #pragma unroll
    for (int m = 1; m < 64; m <<= 1) p += __shfl_xor(p, m, 64);
    if ((tid & 63) == 0) red[(tid >> 6) * 8 + h2] = p;
  }
  __syncthreads();
  if (tid < 8) {
    float s = red[tid] + red[8 + tid];
    beta[((size_t)(b * 8 + tid)) * T_LEN + t] = 1.f / (1.f + expf(-s));
  }
}

// ---------------- K2/K5: bf16 MFMA GEMM, 128x128 tile, BK=32 ----------------
#define LDK 40
template<int MODE>
__global__ __launch_bounds__(256) void k_gemm(
    const void* __restrict__ Am_, const float* __restrict__ W,
    const float* __restrict__ beta, const float* __restrict__ xadd,
    void* __restrict__ out_)
{
  __shared__ ushort As[128 * LDK];
  __shared__ ushort Bs[128 * LDK];
  const int n0 = blockIdx.x * 128;
  const int m0 = blockIdx.y * 128;
  const int tid = threadIdx.x;
  const int lane = tid & 63;
  const int wid = tid >> 6;
  const int wr = wid >> 1, wc = wid & 1;
  const int c = lane & 15, g = lane >> 4;
  const int srow = tid >> 2;
  const int seg = tid & 3;

  f32x4 acc[4][4] = {};

  for (int k0 = 0; k0 < 1024; k0 += 32) {
    if (MODE == 0) {
      const float* a0 = (const float*)Am_ + (size_t)(m0 + srow) * 1024 + k0 + seg * 8;
      const float* a1 = (const float*)Am_ + (size_t)(m0 + srow + 64) * 1024 + k0 + seg * 8;
      float4 p0 = *(const float4*)a0, p1 = *(const float4*)(a0 + 4);
      float4 q0 = *(const float4*)a1, q1 = *(const float4*)(a1 + 4);
      us8 o0, o1;
      o0[0]=f2bf_fast(p0.x); o0[1]=f2bf_fast(p0.y); o0[2]=f2bf_fast(p0.z); o0[3]=f2bf_fast(p0.w);
      o0[4]=f2bf_fast(p1.x); o0[5]=f2bf_fast(p1.y); o0[6]=f2bf_fast(p1.z); o0[7]=f2bf_fast(p1.w);
      o1[0]=f2bf_fast(q0.x); o1[1]=f2bf_fast(q0.y); o1[2]=f2bf_fast(q0.z); o1[3]=f2bf_fast(q0.w);
      o1[4]=f2bf_fast(q1.x); o1[5]=f2bf_fast(q1.y); o1[6]=f2bf_fast(q1.z); o1[7]=f2bf_fast(q1.w);
      *(us8*)&As[srow * LDK + seg * 8] = o0;
      *(us8*)&As[(srow + 64) * LDK + seg * 8] = o1;
    } else {
      us8 o0 = *(const us8*)((const ushort*)Am_ + (size_t)(m0 + srow) * 1024 + k0 + seg * 8);
      us8 o1 = *(const us8*)((const ushort*)Am_ + (size_t)(m0 + srow + 64) * 1024 + k0 + seg * 8);
      *(us8*)&As[srow * LDK + seg * 8] = o0;
      *(us8*)&As[(srow + 64) * LDK + seg * 8] = o1;
    }
    {
      const float* b0 = W + (size_t)(n0 + srow) * 1024 + k0 + seg * 8;
      const float* b1 = W + (size_t)(n0 + srow + 64) * 1024 + k0 + seg * 8;
      float4 p0 = *(const float4*)b0, p1 = *(const float4*)(b0 + 4);
      float4 q0 = *(const float4*)b1, q1 = *(const float4*)(b1 + 4);
      us8 o0, o1;
      o0[0]=f2bf_fast(p0.x); o0[1]=f2bf_fast(p0.y); o0[2]=f2bf_fast(p0.z); o0[3]=f2bf_fast(p0.w);
      o0[4]=f2bf_fast(p1.x); o0[5]=f2bf_fast(p1.y); o0[6]=f2bf_fast(p1.z); o0[7]=f2bf_fast(p1.w);
      o1[0]=f2bf_fast(q0.x); o1[1]=f2bf_fast(q0.y); o1[2]=f2bf_fast(q0.z); o1[3]=f2bf_fast(q0.w);
      o1[4]=f2bf_fast(q1.x); o1[5]=f2bf_fast(q1.y); o1[6]=f2bf_fast(q1.z); o1[7]=f2bf_fast(q1.w);
      *(us8*)&Bs[srow * LDK + seg * 8] = o0;
      *(us8*)&Bs[(srow + 64) * LDK + seg * 8] = o1;
    }
    __syncthreads();
    short8v af[4], bf[4];
    #pragma unroll
    for (int mi = 0; mi < 4; ++mi)
      af[mi] = *(const short8v*)&As[(wr * 64 + mi * 16 + c) * LDK + g * 8];
    #pragma unroll
    for (int ni = 0; ni < 4; ++ni)
      bf[ni] = *(const short8v*)&Bs[(wc * 64 + ni * 16 + c) * LDK + g * 8];
    #pragma unroll
    for (int mi = 0; mi < 4; ++mi)
      #pragma unroll
      for (int ni = 0; ni < 4; ++ni)
        acc[mi][ni] = __builtin_amdgcn_mfma_f32_16x16x32_bf16(af[mi], bf[ni], acc[mi][ni], 0, 0, 0);
    __syncthreads();
  }

  if (MODE == 0) {
    ushort* vb = (ushort*)out_;
    const int hh = n0 >> 7;
    #pragma unroll
    for (int mi = 0; mi < 4; ++mi) {
      #pragma unroll
      for (int ni = 0; ni < 4; ++ni) {
        int jc = wc * 64 + ni * 16 + c;
        #pragma unroll
        for (int j = 0; j < 4; ++j) {
          int m = m0 + wr * 64 + mi * 16 + g * 4 + j;
          int b = m >> 12, t = m & 4095;
          size_t base = (size_t)(b * 8 + hh) * T_LEN + t;
          float bv = beta[base];
          vb[base * 128 + jc] = f2bf(acc[mi][ni][j] * bv);
        }
      }
    }
  } else {
    float* out = (float*)out_;
    #pragma unroll
    for (int mi = 0; mi < 4; ++mi) {
      #pragma unroll
      for (int ni = 0; ni < 4; ++ni) {
        int n = n0 + wc * 64 + ni * 16 + c;
        #pragma unroll
        for (int j = 0; j < 4; ++j) {
          int m = m0 + wr * 64 + mi * 16 + g * 4 + j;
          size_t idx = (size_t)m * 1024 + n;
          out[idx] = xadd[idx] + acc[mi][ni][j];
        }
      }
    }
  }
}

// ---------------- K3: chunk kernel, serial-f32 UT (R8 numerics), 40KB LDS ----------------
// Overlay layout (bytes):
//  [0,21760)      rkb (G phase) -> red[256]f32 at [0,1024) during UT
//                 -> Ab1 [0,9216) + Ab2 [9216,18432) after UT
//  [21760,39168)  Af f32 64x68 (G..Ab-build) ; xT [18432,36864) after Ab-build
//  [39168,39944)  gpow(65f) betaS(64f) bd(64f)
__global__ __launch_bounds__(256) void k_chunk(
    const ushort* __restrict__ rk, ushort* __restrict__ vb,
    ushort* __restrict__ wkcum, ushort* __restrict__ attn,
    const float* __restrict__ beta, const float* __restrict__ decay,
    ushort* __restrict__ wkdwT)
{
  int bh = blockIdx.x >> 6;
  int n = blockIdx.x & 63;
  int h = bh & 7;
  int tid = threadIdx.x;
  int lane = tid & 63, w = tid >> 6;
  int c = lane & 15, g = lane >> 4;

  __shared__ __align__(16) char smem[39952];
  ushort* rkb  = (ushort*)smem;                 // [80*136]  (G phase)
  float*  redp = (float*)smem;                  // [4*64]    (UT phase)
  ushort* Ab1  = (ushort*)smem;                 // [64*72]   (post-UT)
  ushort* Ab2  = (ushort*)(smem + 9216);        // [64*72]
  float*  Af   = (float*)(smem + 21760);        // [64*68]
  ushort* xT   = (ushort*)(smem + 18432);       // [128*72]  (post-Ab)
  float*  gpow  = (float*)(smem + 39168);       // 65
  float*  betaS = (float*)(smem + 39432);       // 64
  float*  bd    = (float*)(smem + 39688);       // 64

  float lg = logf(1.f / (1.f + expf(-decay[h])));
  if (tid < 65) gpow[tid] = expf(lg * (float)tid);
  if (tid < 64) betaS[tid] = beta[(size_t)bh * T_LEN + n * 64 + tid];
  const int t0 = n * 64;
  const size_t bhbase = (size_t)bh * T_LEN;
  const us8 zero8 = {0, 0, 0, 0, 0, 0, 0, 0};

  // ---- P0: stage rkb (rows 0..64 = wkext; 65..79 zero); zero Af ----
  #pragma unroll
  for (int u = 0; u < 5; ++u) {
    int idx = tid + u * 256;
    int row = idx >> 4, cb = idx & 15;
    us8 v = zero8;
    int t = t0 + row - 1;
    if (row <= 64 && t >= 0) v = *(const us8*)(rk + (bhbase + t) * 128 + cb * 8);
    *(us8*)&rkb[row * 136 + cb * 8] = v;
  }
  for (int idx = tid; idx < 64 * 68; idx += 256) Af[idx] = 0.f;
  __syncthreads();
  if (tid < 64) bd[tid] = betaS[tid] * gpow[tid + 1];

  // ---- P1: G via MFMA -> Af (A0, f32) + attn ----
  const size_t abase = ((size_t)bh * 64 + n) * 4096;
  {
    const int TR[14] = {0,1,1,2,2,2,3,3,3,3,4,4,4,4};
    const int TC[14] = {0,0,1,0,1,2,0,1,2,3,0,1,2,3};
    #pragma unroll
    for (int ti = 0; ti < 14; ++ti) {
      if ((ti & 3) != w) continue;
      const int tr = TR[ti], tc = TC[ti];
      f32x4 acc = {0.f, 0.f, 0.f, 0.f};
      #pragma unroll
      for (int ks = 0; ks < 4; ++ks) {
        short8v a = *(const short8v*)&rkb[(tr * 16 + c) * 136 + ks * 32 + g * 8];
        short8v b = *(const short8v*)&rkb[(tc * 16 + c) * 136 + ks * 32 + g * 8];
        acc = __builtin_amdgcn_mfma_f32_16x16x32_bf16(a, b, acc, 0, 0, 0);
      }
      #pragma unroll
      for (int r = 0; r < 4; ++r) {
        int a_ = tr * 16 + g * 4 + r;
        int j = tc * 16 + c;
        float val = acc[r];
        if (a_ <= 63) Af[a_ * 68 + j] = (a_ > j) ? (-betaS[a_] * val * gpow[a_ - j]) : 0.f;
        if (a_ >= 1 && a_ <= 64) {
          if (j <= a_ - 1)      attn[abase + (size_t)(a_ - 1) * 64 + j] = f2bf(val * gpow[a_ - 1 - j]);
          else if (a_ <= 63)    attn[abase + (size_t)(a_ - 1) * 64 + j] = 0;
        }
      }
    }
  }
  {
    const int ZR[6] = {0,0,0,1,1,2};
    const int ZC[6] = {1,2,3,2,3,3};
    int rr = tid >> 4, cc2 = tid & 15;
    #pragma unroll
    for (int z = 0; z < 6; ++z) {
      int r_att = ZR[z] * 16 - 1 + rr;
      if (r_att >= 0) attn[abase + (size_t)r_att * 64 + ZC[z] * 16 + cc2] = 0;
    }
  }
  __syncthreads();   // rkb dead from here

  // ---- P2: serial UT transform (f32, exact R8) ; red overlays rkb ----
  {
    int k = tid & 63, sp = tid >> 6;
    for (int i = 1; i < 64; ++i) {
      float part = 0.f;
      #pragma unroll
      for (int jj = 0; jj < 16; ++jj) {
        int j = sp * 16 + jj;
        part += Af[i * 68 + j] * Af[j * 68 + k];
      }
      redp[sp * 64 + k] = part;
      __syncthreads();
      if (tid < 64) Af[i * 68 + tid] += redp[tid] + redp[64 + tid] + redp[128 + tid] + redp[192 + tid];
      __syncthreads();
    }
  }
  // ---- P3: build Ab1=(A+I)diag(bd), Ab2=(A+I) bf16 (overlay rkb; red dead) ----
  {
    int i = tid >> 2, j0 = (tid & 3) * 16;
    #pragma unroll
    for (int jj = 0; jj < 16; ++jj) {
      int j = j0 + jj;
      float av = Af[i * 68 + j] + ((i == j) ? 1.f : 0.f);
      Ab1[i * 72 + j] = f2bf(av * bd[j]);
      Ab2[i * 72 + j] = f2bf(av);
    }
  }
  __syncthreads();   // Af dead from here

  // ---- P4: stage xT = wk^T from global (overlays Af region) ----
  #pragma unroll
  for (int u = 0; u < 4; ++u) {
    int idx = tid + u * 256;
    int j = idx & 63, eb = idx >> 6;
    int t = t0 + j - 1;
    us8 v = zero8;
    if (t >= 0) v = *(const us8*)(rk + (bhbase + t) * 128 + eb * 8);
    #pragma unroll
    for (int s = 0; s < 8; ++s) xT[(eb * 8 + s) * 72 + j] = v[s];
  }
  __syncthreads();

  // ---- P5: 4a: wkcum = Ab1 @ wk ----
  {
    f32x4 acc[8] = {};
    #pragma unroll
    for (int ks = 0; ks < 2; ++ks) {
      short8v a = *(const short8v*)&Ab1[(w * 16 + c) * 72 + ks * 32 + g * 8];
      #pragma unroll
      for (int nt = 0; nt < 8; ++nt) {
        short8v b = *(const short8v*)&xT[(nt * 16 + c) * 72 + ks * 32 + g * 8];
        acc[nt] = __builtin_amdgcn_mfma_f32_16x16x32_bf16(a, b, acc[nt], 0, 0, 0);
      }
    }
    #pragma unroll
    for (int nt = 0; nt < 8; ++nt)
      #pragma unroll
      for (int r = 0; r < 4; ++r) {
        int i = w * 16 + g * 4 + r, e = nt * 16 + c;
        wkcum[(bhbase + t0 + i) * 128 + e] = f2bf(acc[nt][r]);
      }
  }
  // ---- export wkdwT[p][i] = wk[i][p] * gamma^(63-i) (xT still wk^T) ----
  {
    const size_t kbase = ((size_t)bh * 64 + n) * 8192;
    #pragma unroll
    for (int u = 0; u < 4; ++u) {
      int idx = tid + u * 256;
      int e = idx >> 3, seg = idx & 7;
      us8 v = *(const us8*)&xT[e * 72 + seg * 8];
      us8 o;
      #pragma unroll
      for (int s = 0; s < 8; ++s) o[s] = f2bf(bf2f(v[s]) * gpow[63 - (seg * 8 + s)]);
      *(us8*)(wkdwT + kbase + (size_t)e * 64 + seg * 8) = o;
    }
  }
  __syncthreads();
  // ---- P6: xT = v^T ----
  #pragma unroll
  for (int u = 0; u < 4; ++u) {
    int idx = tid + u * 256;
    int j = idx & 63, eb = idx >> 6;
    us8 v = *(const us8*)(vb + (bhbase + t0 + j) * 128 + eb * 8);
    #pragma unroll
    for (int s = 0; s < 8; ++s) xT[(eb * 8 + s) * 72 + j] = v[s];
  }
  __syncthreads();
  // ---- P7: 4b: vb = Ab2 @ v ----
  {
    f32x4 acc[8] = {};
    #pragma unroll
    for (int ks = 0; ks < 2; ++ks) {
      short8v a = *(const short8v*)&Ab2[(w * 16 + c) * 72 + ks * 32 + g * 8];
      #pragma unroll
      for (int nt = 0; nt < 8; ++nt) {
        short8v b = *(const short8v*)&xT[(nt * 16 + c) * 72 + ks * 32 + g * 8];
        acc[nt] = __builtin_amdgcn_mfma_f32_16x16x32_bf16(a, b, acc[nt], 0, 0, 0);
      }
    }
    #pragma unroll
    for (int nt = 0; nt < 8; ++nt)
      #pragma unroll
      for (int r = 0; r < 4; ++r) {
        int i = w * 16 + g * 4 + r, e = nt * 16 + c;
        vb[(bhbase + t0 + i) * 128 + e] = f2bf(acc[nt][r]);
      }
  }
}

// ---------------- K4: fused MFMA scan (unchanged from R8) ----------------
#define SCAN_STEP(W_, R_, T_, K_, V_, nW, nR, nT, nK, nV, n_) {                 \
  const int t0s = (n_) * 64;                                                    \
  { const int np = ((n_) < 63) ? (n_) + 1 : 63;                                 \
    const size_t rb = (bhbase + (size_t)(np * 64 + 16 * w + c)) * 128;          \
    _Pragma("unroll")                                                           \
    for (int ks = 0; ks < 4; ++ks) {                                            \
      nW[ks] = *(const short8v*)(wkcum + rb + ks * 32 + g * 8);                 \
      nR[ks] = *(const short8v*)(rk    + rb + ks * 32 + g * 8); }               \
    const size_t ab = ((size_t)bh * 64 + np) * 4096 + (size_t)(16 * w + c) * 64;\
    nT[0] = *(const short8v*)(attn + ab + g * 8);                               \
    nT[1] = *(const short8v*)(attn + ab + 32 + g * 8);                          \
    const size_t kb = ((size_t)bh * 64 + np) * 8192;                            \
    nK[0] = *(const short8v*)(wkdwT + kb + (size_t)(32 * w + c) * 64 + g * 8);  \
    nK[1] = *(const short8v*)(wkdwT + kb + (size_t)(32 * w + c) * 64 + 32 + g * 8); \
    nK[2] = *(const short8v*)(wkdwT + kb + (size_t)(32 * w + 16 + c) * 64 + g * 8); \
    nK[3] = *(const short8v*)(wkdwT + kb + (size_t)(32 * w + 16 + c) * 64 + 32 + g * 8); \
    _Pragma("unroll")                                                           \
    for (int r = 0; r < 4; ++r)                                                 \
      nV[r] = vb[(bhbase + (size_t)(np * 64 + 16 * w + 4 * g + r)) * 128 + q0 + c]; } \
  f32x4 accA = {}, accB = {};                                                   \
  _Pragma("unroll")                                                             \
  for (int ks = 0; ks < 4; ++ks) {                                              \
    short8v b0 = *(const short8v*)&ST[c * 136 + ks * 32 + g * 8];               \
    accA = __builtin_amdgcn_mfma_f32_16x16x32_bf16(W_[ks], b0, accA, 0, 0, 0);  \
    accB = __builtin_amdgcn_mfma_f32_16x16x32_bf16(R_[ks], b0, accB, 0, 0, 0); }\
  _Pragma("unroll")                                                             \
  for (int r = 0; r < 4; ++r) {                                                 \
    int i = 16 * w + 4 * g + r;                                                 \
    accB[r] *= gB[r];                                                           \
    vnL[c * 72 + i] = f2bf(bf2f(V_[r]) - accA[r]); }                            \
  asm volatile("s_waitcnt lgkmcnt(0)" ::: "memory");                            \
  __builtin_amdgcn_s_barrier();                                                 \
  short8v vf0 = *(const short8v*)&vnL[c * 72 + g * 8];                          \
  short8v vf1 = *(const short8v*)&vnL[c * 72 + 32 + g * 8];                     \
  accB = __builtin_amdgcn_mfma_f32_16x16x32_bf16(T_[0], vf0, accB, 0, 0, 0);    \
  accB = __builtin_amdgcn_mfma_f32_16x16x32_bf16(T_[1], vf1, accB, 0, 0, 0);    \
  _Pragma("unroll")                                                             \
  for (int r = 0; r < 4; ++r) {                                                 \
    int i = 16 * w + 4 * g + r;                                                 \
    og[((size_t)b_ * T_LEN + t0s + i) * 1024 + h * 128 + q0 + c] = f2bf(accB[r]); } \
  _Pragma("unroll")                                                             \
  for (int r = 0; r < 4; ++r) { accS0[r] *= ct; accS1[r] *= ct; }               \
  accS0 = __builtin_amdgcn_mfma_f32_16x16x32_bf16(K_[0], vf0, accS0, 0, 0, 0);  \
  accS0 = __builtin_amdgcn_mfma_f32_16x16x32_bf16(K_[1], vf1, accS0, 0, 0, 0);  \
  accS1 = __builtin_amdgcn_mfma_f32_16x16x32_bf16(K_[2], vf0, accS1, 0, 0, 0);  \
  accS1 = __builtin_amdgcn_mfma_f32_16x16x32_bf16(K_[3], vf1, accS1, 0, 0, 0);  \
  _Pragma("unroll")                                                             \
  for (int r = 0; r < 4; ++r) {                                                 \
    int p0r = 32 * w + 4 * g + r;                                               \
    ST[c * 136 + p0r]      = f2bf(accS0[r]);                                    \
    ST[c * 136 + p0r + 16] = f2bf(accS1[r]); }                                  \
  asm volatile("s_waitcnt lgkmcnt(0)" ::: "memory");                            \
  __builtin_amdgcn_s_barrier();                                                 \
}

__global__ __launch_bounds__(256) void k_scan_fused(
    const ushort* __restrict__ rk, const ushort* __restrict__ vb,
    const ushort* __restrict__ wkcum, const ushort* __restrict__ attn,
    const ushort* __restrict__ wkdwT, const float* __restrict__ decay,
    ushort* __restrict__ og)
{
  const int bh = blockIdx.x & 31;
  const int q0 = (blockIdx.x >> 5) * 16;
  const int b_ = bh >> 3, h = bh & 7;
  const int tid = threadIdx.x;
  const int lane = tid & 63, w = tid >> 6;
  const int c = lane & 15, g = lane >> 4;

  __shared__ ushort ST[16 * 136];
  __shared__ ushort vnL[16 * 72];
  __shared__ float gpow[65];

  float lg = logf(1.f / (1.f + expf(-decay[h])));
  if (tid < 65) gpow[tid] = expf(lg * (float)tid);
  for (int idx = tid; idx < 16 * 136; idx += 256) ST[idx] = 0;
  __syncthreads();
  const float ct = gpow[64];
  float gB[4];
  #pragma unroll
  for (int r = 0; r < 4; ++r) gB[r] = gpow[16 * w + 4 * g + r + 1];
  const size_t bhbase = (size_t)bh * T_LEN;

  f32x4 accS0 = {}, accS1 = {};
  short8v aW[4], aR[4], aT[2], aK[4];
  short8v bW[4], bR[4], bT[2], bK[4];
  ushort aV[4], bV[4];
  {
    const size_t rb = (bhbase + (size_t)(16 * w + c)) * 128;
    #pragma unroll
    for (int ks = 0; ks < 4; ++ks) {
      aW[ks] = *(const short8v*)(wkcum + rb + ks * 32 + g * 8);
      aR[ks] = *(const short8v*)(rk + rb + ks * 32 + g * 8);
    }
    const size_t ab = (size_t)bh * 64 * 4096 + (size_t)(16 * w + c) * 64;
    aT[0] = *(const short8v*)(attn + ab + g * 8);
    aT[1] = *(const short8v*)(attn + ab + 32 + g * 8);
    const size_t kb = (size_t)bh * 64 * 8192;
    aK[0] = *(const short8v*)(wkdwT + kb + (size_t)(32 * w + c) * 64 + g * 8);
    aK[1] = *(const short8v*)(wkdwT + kb + (size_t)(32 * w + c) * 64 + 32 + g * 8);
    aK[2] = *(const short8v*)(wkdwT + kb + (size_t)(32 * w + 16 + c) * 64 + g * 8);
    aK[3] = *(const short8v*)(wkdwT + kb + (size_t)(32 * w + 16 + c) * 64 + 32 + g * 8);
    #pragma unroll
    for (int r = 0; r < 4; ++r)
      aV[r] = vb[(bhbase + (size_t)(16 * w + 4 * g + r)) * 128 + q0 + c];
  }
  for (int n = 0; n < 64; n += 2) {
    SCAN_STEP(aW, aR, aT, aK, aV, bW, bR, bT, bK, bV, n);
    SCAN_STEP(bW, bR, bT, bK, bV, aW, aR, aT, aK, aV, n + 1);
  }
}

extern "C" void kernel_launch(void* const* d_in, const int* in_sizes, int n_in,
                              void* d_out, int out_size, void* d_ws, size_t ws_size,
                              hipStream_t stream) {
  const float* x   = (const float*)d_in[0];
  const float* Ww  = (const float*)d_in[1];
  const float* Wr  = (const float*)d_in[2];
  const float* Wb  = (const float*)d_in[3];
  const float* dec = (const float*)d_in[4];
  float* out = (float*)d_out;
  ushort* ws = (ushort*)d_ws;
  const size_t SZ = 16777216ull;
  ushort* rk    = ws;
  ushort* vb    = ws + SZ;
  ushort* wkcum = ws + 2 * SZ;
  ushort* og    = ws + 3 * SZ;
  ushort* attn  = ws + 4 * SZ;
  float*  beta  = (float*)(ws + 4 * SZ + 8388608ull);
  ushort* wkdwT = ws + 4 * SZ + 8388608ull + 262144ull;
  const size_t NEED = (4 * SZ + 8388608ull + 262144ull + SZ) * 2ull;
  if (ws_size < NEED) {
    hipMemcpyAsync(d_out, (const void*)x, (size_t)out_size * 4, hipMemcpyDeviceToDevice, stream);
    return;
  }

  k_prep<<<dim3(16384), dim3(128), 0, stream>>>(x, Wb, rk, beta);
  k_gemm<0><<<dim3(8, 128), dim3(256), 0, stream>>>((const void*)x, Ww, beta, nullptr, (void*)vb);
  k_chunk<<<dim3(2048), dim3(256), 0, stream>>>(rk, vb, wkcum, attn, beta, dec, wkdwT);
  k_scan_fused<<<dim3(256), dim3(256), 0, stream>>>(rk, vb, wkcum, attn, wkdwT, dec, og);
  k_gemm<1><<<dim3(8, 128), dim3(256), 0, stream>>>((const void*)og, Wr, nullptr, (const float*)x, (void*)out);
}